// Round 1
// baseline (5096.566 us; speedup 1.0000x reference)
//
#include <hip/hip_runtime.h>
#include <cstdint>
#include <cstddef>

#define NN 4096
#define EE 131072
#define TS 64

__device__ __forceinline__ unsigned fkey(float f) {
    unsigned u = __float_as_uint(f);
    return (u & 0x80000000u) ? ~u : (u | 0x80000000u);
}
__device__ __forceinline__ float funkey(unsigned k) {
    unsigned u = (k & 0x80000000u) ? (k & 0x7fffffffu) : ~k;
    return __uint_as_float(u);
}

__global__ void k_count(const int* __restrict__ src, const int* __restrict__ dst,
                        int* __restrict__ cs, int* __restrict__ cd) {
    int e = blockIdx.x * 256 + threadIdx.x;
    if (e < EE) {
        atomicAdd(&cs[src[e]], 1);
        atomicAdd(&cd[dst[e]], 1);
    }
}

__global__ void k_norm(const int* __restrict__ cs, const int* __restrict__ cd,
                       float* __restrict__ on, float* __restrict__ inn) {
    int i = blockIdx.x * 256 + threadIdx.x;
    if (i < NN) {
        int a = cs[i] > 1 ? cs[i] : 1;
        int b = cd[i] > 1 ? cd[i] : 1;
        on[i]  = 1.0f / sqrtf((float)a);
        inn[i] = 1.0f / sqrtf((float)b);
    }
}

// out[i][j] = (sum_k X[i][k] * W[k][j]) * scale[i]
template<int K, int ND>
__global__ void k_gemm_scale(const float* __restrict__ X, const float* __restrict__ W,
                             const float* __restrict__ scale, float* __restrict__ out) {
    __shared__ float xr[K];
    int i = blockIdx.x;
    for (int k = threadIdx.x; k < K; k += ND) xr[k] = X[(size_t)i * K + k];
    __syncthreads();
    int j = threadIdx.x;
    float acc = 0.0f;
    #pragma unroll 8
    for (int k = 0; k < K; ++k) acc = fmaf(xr[k], W[k * ND + j], acc);
    out[(size_t)i * ND + j] = acc * scale[i];
}

// out[i][j] = X@W + b1[j] (+ b2[j]) (optionally relu)
template<int K, int ND>
__global__ void k_gemm_ab(const float* __restrict__ X, const float* __restrict__ W,
                          const float* __restrict__ b1, const float* __restrict__ b2,
                          float* __restrict__ out, int do_relu) {
    __shared__ float xr[K];
    int i = blockIdx.x;
    for (int k = threadIdx.x; k < K; k += ND) xr[k] = X[(size_t)i * K + k];
    __syncthreads();
    int j = threadIdx.x;
    float acc = 0.0f;
    #pragma unroll 8
    for (int k = 0; k < K; ++k) acc = fmaf(xr[k], W[k * ND + j], acc);
    acc += b1[j];
    if (b2) acc += b2[j];
    if (do_relu) acc = fmaxf(acc, 0.0f);
    out[(size_t)i * ND + j] = acc;
}

__global__ void k_scatter(const float* __restrict__ t, const int* __restrict__ src,
                          const int* __restrict__ dst, float* __restrict__ agg) {
    int e = blockIdx.x;
    int j = threadIdx.x;   // 128 threads
    int s = src[e], d = dst[e];
    atomicAdd(&agg[(size_t)d * 128 + j], t[(size_t)s * 128 + j]);
}

__global__ void k_gcn_out(const float* __restrict__ agg, const float* __restrict__ inn,
                          const float* __restrict__ b, float* __restrict__ out, int do_relu) {
    int idx = blockIdx.x * 256 + threadIdx.x;   // N*128 total
    int i = idx >> 7, j = idx & 127;
    float v = agg[idx] * inn[i] + b[j];
    if (do_relu) v = fmaxf(v, 0.0f);
    out[idx] = v;
}

// S = h h^T, 64x64 tile per block, upper-triangular tiles only (S symmetric).
// MODE 0: global max of S (via order-key atomicMax).
// MODE 1: recompute S, emit mask bits: mask[i][j] = (i==j) || ((i<j) bit from P,u).
template<int MODE>
__global__ __launch_bounds__(256) void k_stile(const float* __restrict__ h,
                                               const float* __restrict__ u,
                                               unsigned* __restrict__ smax_key,
                                               unsigned* __restrict__ mb) {
    int ti = blockIdx.y, tj = blockIdx.x;
    if (tj < ti) return;
    __shared__ float Ah[TS][68];
    __shared__ float Bh[TS][68];
    int tid = threadIdx.x;
    int tx = tid & 15, ty = tid >> 4;
    const float4* ha = (const float4*)(h + (size_t)ti * TS * 128);
    const float4* hb = (const float4*)(h + (size_t)tj * TS * 128);

    float acc[4][4];
    #pragma unroll
    for (int r = 0; r < 4; ++r)
        #pragma unroll
        for (int c = 0; c < 4; ++c) acc[r][c] = 0.0f;

    for (int half = 0; half < 2; ++half) {
        __syncthreads();
        #pragma unroll
        for (int t = 0; t < 4; ++t) {
            int f = tid + t * 256;        // float4 index within 64x64-float half-tile
            int r = f >> 4, kk = f & 15;  // 16 float4 per row-half
            *(float4*)&Ah[r][kk * 4] = ha[(size_t)r * 32 + half * 16 + kk];
            *(float4*)&Bh[r][kk * 4] = hb[(size_t)r * 32 + half * 16 + kk];
        }
        __syncthreads();
        for (int k4 = 0; k4 < 16; ++k4) {
            float4 a[4], b[4];
            #pragma unroll
            for (int r = 0; r < 4; ++r) a[r] = *(const float4*)&Ah[ty * 4 + r][k4 * 4];
            #pragma unroll
            for (int c = 0; c < 4; ++c) b[c] = *(const float4*)&Bh[tx * 4 + c][k4 * 4];
            #pragma unroll
            for (int r = 0; r < 4; ++r)
                #pragma unroll
                for (int c = 0; c < 4; ++c) {
                    acc[r][c] = fmaf(a[r].x, b[c].x, acc[r][c]);
                    acc[r][c] = fmaf(a[r].y, b[c].y, acc[r][c]);
                    acc[r][c] = fmaf(a[r].z, b[c].z, acc[r][c]);
                    acc[r][c] = fmaf(a[r].w, b[c].w, acc[r][c]);
                }
        }
    }

    if constexpr (MODE == 0) {
        float m = -3.4e38f;
        #pragma unroll
        for (int r = 0; r < 4; ++r)
            #pragma unroll
            for (int c = 0; c < 4; ++c) m = fmaxf(m, acc[r][c]);
        #pragma unroll
        for (int o = 1; o < 64; o <<= 1) m = fmaxf(m, __shfl_xor(m, o, 64));
        __shared__ float wm[4];
        if ((tid & 63) == 0) wm[tid >> 6] = m;
        __syncthreads();
        if (tid == 0) {
            float mm = fmaxf(fmaxf(wm[0], wm[1]), fmaxf(wm[2], wm[3]));
            atomicMax(smax_key, fkey(mm));
        }
    } else {
        float smax = funkey(*smax_key);
        float epmax = 1.0f / (1.0f + expf(-smax));
        __shared__ unsigned lm[TS][2];
        __shared__ unsigned lmT[TS][2];
        if (tid < 128) { lm[tid >> 1][tid & 1] = 0u; lmT[tid >> 1][tid & 1] = 0u; }
        __syncthreads();
        #pragma unroll
        for (int r = 0; r < 4; ++r) {
            #pragma unroll
            for (int c = 0; c < 4; ++c) {
                int li = ty * 4 + r, lj = tx * 4 + c;
                int gi = ti * TS + li, gj = tj * TS + lj;
                bool bit = false;
                if (gi < gj) {
                    float s = acc[r][c];
                    float ep = 1.0f / (1.0f + expf(-s));
                    float P = ep / epmax;
                    float Pc = fminf(fmaxf(P, 1e-6f), 1.0f - 1e-6f);
                    float lo = logf(Pc) - log1pf(-Pc);
                    float uu = u[(size_t)gi * NN + gj];
                    float ucv = fminf(fmaxf(uu, 1e-6f), 1.0f - 1e-6f);
                    float no = logf(ucv) - log1pf(-ucv);
                    bit = (lo + no) > 0.0f;     // y = round(sigmoid(x/T)) == 1  iff  x > 0
                } else if (gi == gj) {
                    bit = true;                 // self-loop: diag forced to 1
                }
                if (bit) {
                    atomicOr(&lm[li][lj >> 5], 1u << (lj & 31));
                    atomicOr(&lmT[lj][li >> 5], 1u << (li & 31));
                }
            }
        }
        __syncthreads();
        if (tid < 128) {
            int r = tid >> 1, w = tid & 1;
            unsigned word = lm[r][w];
            if (ti == tj) word |= lmT[r][w];
            mb[(size_t)(ti * TS + r) * 128 + tj * 2 + w] = word;
        } else if (ti != tj) {
            int r = (tid - 128) >> 1, w = tid & 1;
            mb[(size_t)(tj * TS + r) * 128 + ti * 2 + w] = lmT[r][w];
        }
    }
}

// agg[i][d] = max over j in mask-row i of z[j][d]; one block per row, D threads.
template<int D>
__global__ void k_maskmax(const unsigned* __restrict__ mb, const float* __restrict__ z,
                          float* __restrict__ out) {
    int i = blockIdx.x;
    int d = threadIdx.x;
    const unsigned* row = mb + (size_t)i * 128;
    float m = -3.4e38f;
    for (int w = 0; w < 128; ++w) {
        unsigned word = row[w];
        while (word) {
            int b = __ffs(word) - 1;
            word &= word - 1;
            int j = w * 32 + b;
            m = fmaxf(m, z[(size_t)j * D + d]);
        }
    }
    out[(size_t)i * D + d] = m;
}

__global__ void k_relu_l2norm(float* __restrict__ h) {
    int i = blockIdx.x, d = threadIdx.x;   // 128 threads
    float v = fmaxf(h[(size_t)i * 128 + d], 0.0f);
    float ss = v * v;
    #pragma unroll
    for (int o = 1; o < 64; o <<= 1) ss += __shfl_xor(ss, o, 64);
    __shared__ float w2[2];
    if ((d & 63) == 0) w2[d >> 6] = ss;
    __syncthreads();
    float tot = w2[0] + w2[1];
    float denom = fmaxf(sqrtf(tot), 1e-12f);
    h[(size_t)i * 128 + d] = v / denom;
}

__global__ void k_gemm_final(const float* __restrict__ X, const float* __restrict__ W,
                             const float* __restrict__ b1, const float* __restrict__ b2,
                             float* __restrict__ out) {
    int i = blockIdx.x * 2 + (threadIdx.x >> 5);
    int j = threadIdx.x & 31;
    float acc = 0.0f;
    #pragma unroll 8
    for (int k = 0; k < 128; ++k) acc = fmaf(X[(size_t)i * 128 + k], W[k * 32 + j], acc);
    out[(size_t)i * 32 + j] = acc + b1[j] + b2[j];
}

extern "C" void kernel_launch(void* const* d_in, const int* in_sizes, int n_in,
                              void* d_out, int out_size, void* d_ws, size_t ws_size,
                              hipStream_t stream) {
    // input order per setup_inputs(): adj unused (ALPHA == 1.0 -> coefficient 0)
    const float* inputs = (const float*)d_in[1];
    const float* feat   = (const float*)d_in[2];
    const float* u      = (const float*)d_in[3];
    const int*   src    = (const int*)d_in[4];
    const int*   dst    = (const int*)d_in[5];
    const float* gc0W = (const float*)d_in[6],  *gc0b = (const float*)d_in[7];
    const float* gc1W = (const float*)d_in[8],  *gc1b = (const float*)d_in[9];
    const float* p0W  = (const float*)d_in[10], *p0b  = (const float*)d_in[11];
    const float* l0W  = (const float*)d_in[12], *l0b  = (const float*)d_in[13];
    const float* b0   = (const float*)d_in[14];
    const float* p1W  = (const float*)d_in[15], *p1b  = (const float*)d_in[16];
    const float* l1W  = (const float*)d_in[17], *l1b  = (const float*)d_in[18];
    const float* b1   = (const float*)d_in[19];
    const float* p2W  = (const float*)d_in[20], *p2b  = (const float*)d_in[21];
    const float* l2W  = (const float*)d_in[22], *l2b  = (const float*)d_in[23];
    const float* b2   = (const float*)d_in[24];
    float* out = (float*)d_out;

    char* w = (char*)d_ws;
    int*      cnt_src  = (int*)(w + 0);                         // 16 KB
    int*      cnt_dst  = (int*)(w + 16384);                     // 16 KB
    float*    on       = (float*)(w + 32768);                   // 16 KB
    float*    inn      = (float*)(w + 49152);                   // 16 KB
    unsigned* smax_key = (unsigned*)(w + 65536);                // (padded to 16 KB)
    float*    tmp      = (float*)(w + 81920);                   // 2 MB (4096x128)
    float*    agg      = (float*)(w + 81920 + 2097152);         // 2 MB
    float*    hbuf     = (float*)(w + 81920 + 2 * 2097152);     // 2 MB
    unsigned* mb       = (unsigned*)(w + 81920 + 3 * 2097152);  // 2 MB bitmask 4096x128 words
    float*    z        = (float*)(w + 81920 + 4 * 2097152);     // 4 MB (4096x256)
    float*    amax     = (float*)(w + 81920 + 4 * 2097152 + 4194304);      // 4 MB
    float*    hs       = (float*)(w + 81920 + 4 * 2097152 + 2 * 4194304);  // 2 MB

    // zero accumulators (counts, norms area, smax key)
    hipMemsetAsync(w, 0, 81920, stream);
    k_count<<<EE / 256, 256, 0, stream>>>(src, dst, cnt_src, cnt_dst);
    k_norm<<<NN / 256, 256, 0, stream>>>(cnt_src, cnt_dst, on, inn);

    // --- GCN layer 0 ---
    k_gemm_scale<256, 128><<<NN, 128, 0, stream>>>(inputs, gc0W, on, tmp);
    hipMemsetAsync(agg, 0, (size_t)NN * 128 * 4, stream);
    k_scatter<<<EE, 128, 0, stream>>>(tmp, src, dst, agg);
    k_gcn_out<<<NN * 128 / 256, 256, 0, stream>>>(agg, inn, gc0b, hbuf, 1);

    // --- GCN layer 1 ---
    k_gemm_scale<128, 128><<<NN, 128, 0, stream>>>(hbuf, gc1W, on, tmp);
    hipMemsetAsync(agg, 0, (size_t)NN * 128 * 4, stream);
    k_scatter<<<EE, 128, 0, stream>>>(tmp, src, dst, agg);
    k_gcn_out<<<NN * 128 / 256, 256, 0, stream>>>(agg, inn, gc1b, hbuf, 0);

    // --- decode: max(S) then mask bits ---
    dim3 tg(64, 64);
    k_stile<0><<<tg, 256, 0, stream>>>(hbuf, nullptr, smax_key, nullptr);
    k_stile<1><<<tg, 256, 0, stream>>>(hbuf, u, smax_key, mb);

    // --- GraphSAGE layer 0 (256 -> 128) ---
    k_gemm_ab<256, 256><<<NN, 256, 0, stream>>>(feat, p0W, p0b, nullptr, z, 1);
    k_maskmax<256><<<NN, 256, 0, stream>>>(mb, z, amax);
    k_gemm_ab<256, 128><<<NN, 128, 0, stream>>>(amax, l0W, l0b, b0, hs, 0);
    k_relu_l2norm<<<NN, 128, 0, stream>>>(hs);

    // --- GraphSAGE layer 1 (128 -> 128) ---
    k_gemm_ab<128, 128><<<NN, 128, 0, stream>>>(hs, p1W, p1b, nullptr, z, 1);
    k_maskmax<128><<<NN, 128, 0, stream>>>(mb, z, amax);
    k_gemm_ab<128, 128><<<NN, 128, 0, stream>>>(amax, l1W, l1b, b1, tmp, 0);
    k_relu_l2norm<<<NN, 128, 0, stream>>>(tmp);

    // --- GraphSAGE layer 2 (128 -> 32) ---
    k_gemm_ab<128, 128><<<NN, 128, 0, stream>>>(tmp, p2W, p2b, nullptr, z, 1);
    k_maskmax<128><<<NN, 128, 0, stream>>>(mb, z, amax);
    k_gemm_final<<<NN / 2, 64, 0, stream>>>(amax, l2W, l2b, b2, out);
}

// Round 2
// 2752.092 us; speedup vs baseline: 1.8519x; 1.8519x over previous
//
#include <hip/hip_runtime.h>
#include <cstdint>
#include <cstddef>

#define NN 4096
#define EE 131072
#define TS 64

__device__ __forceinline__ unsigned fkey(float f) {
    unsigned u = __float_as_uint(f);
    return (u & 0x80000000u) ? ~u : (u | 0x80000000u);
}
__device__ __forceinline__ float funkey(unsigned k) {
    unsigned u = (k & 0x80000000u) ? (k & 0x7fffffffu) : ~k;
    return __uint_as_float(u);
}

__global__ void k_count(const int* __restrict__ src, const int* __restrict__ dst,
                        int* __restrict__ cs, int* __restrict__ cd) {
    int e = blockIdx.x * 256 + threadIdx.x;
    if (e < EE) {
        atomicAdd(&cs[src[e]], 1);
        atomicAdd(&cd[dst[e]], 1);
    }
}

__global__ void k_norm(const int* __restrict__ cs, const int* __restrict__ cd,
                       float* __restrict__ on, float* __restrict__ inn) {
    int i = blockIdx.x * 256 + threadIdx.x;
    if (i < NN) {
        int a = cs[i] > 1 ? cs[i] : 1;
        int b = cd[i] > 1 ? cd[i] : 1;
        on[i]  = 1.0f / sqrtf((float)a);
        inn[i] = 1.0f / sqrtf((float)b);
    }
}

// out[i][j] = (sum_k X[i][k] * W[k][j]) * scale[i]
template<int K, int ND>
__global__ void k_gemm_scale(const float* __restrict__ X, const float* __restrict__ W,
                             const float* __restrict__ scale, float* __restrict__ out) {
    __shared__ float xr[K];
    int i = blockIdx.x;
    for (int k = threadIdx.x; k < K; k += ND) xr[k] = X[(size_t)i * K + k];
    __syncthreads();
    int j = threadIdx.x;
    float acc = 0.0f;
    #pragma unroll 8
    for (int k = 0; k < K; ++k) acc = fmaf(xr[k], W[k * ND + j], acc);
    out[(size_t)i * ND + j] = acc * scale[i];
}

// out[i][j] = X@W + b1[j] (+ b2[j]) (optionally relu)
template<int K, int ND>
__global__ void k_gemm_ab(const float* __restrict__ X, const float* __restrict__ W,
                          const float* __restrict__ b1, const float* __restrict__ b2,
                          float* __restrict__ out, int do_relu) {
    __shared__ float xr[K];
    int i = blockIdx.x;
    for (int k = threadIdx.x; k < K; k += ND) xr[k] = X[(size_t)i * K + k];
    __syncthreads();
    int j = threadIdx.x;
    float acc = 0.0f;
    #pragma unroll 8
    for (int k = 0; k < K; ++k) acc = fmaf(xr[k], W[k * ND + j], acc);
    acc += b1[j];
    if (b2) acc += b2[j];
    if (do_relu) acc = fmaxf(acc, 0.0f);
    out[(size_t)i * ND + j] = acc;
}

__global__ void k_scatter(const float* __restrict__ t, const int* __restrict__ src,
                          const int* __restrict__ dst, float* __restrict__ agg) {
    int e = blockIdx.x;
    int j = threadIdx.x;   // 128 threads
    int s = src[e], d = dst[e];
    atomicAdd(&agg[(size_t)d * 128 + j], t[(size_t)s * 128 + j]);
}

__global__ void k_gcn_out(const float* __restrict__ agg, const float* __restrict__ inn,
                          const float* __restrict__ b, float* __restrict__ out, int do_relu) {
    int idx = blockIdx.x * 256 + threadIdx.x;   // N*128 total
    int i = idx >> 7, j = idx & 127;
    float v = agg[idx] * inn[i] + b[j];
    if (do_relu) v = fmaxf(v, 0.0f);
    out[idx] = v;
}

// S = h h^T, 64x64 tile per block, upper-triangular tiles only (S symmetric).
// Thread (tx,ty) owns rows {ty+16r}, cols {tx+16c} of the tile (stride-16
// mapping: 2-way LDS bank aliasing on b128 reads instead of 8-way).
// MODE 0: global max of S (via order-key atomicMax).
// MODE 1: recompute S, emit mask bits. bit test: logit(Pc)+logit(uc) > 0
//         <=> Pc > 1-uc  (logit monotone) -- one expf, no logf.
template<int MODE>
__global__ __launch_bounds__(256, 4) void k_stile(const float* __restrict__ h,
                                                  const float* __restrict__ u,
                                                  unsigned* __restrict__ smax_key,
                                                  unsigned* __restrict__ mb) {
    int ti = blockIdx.y, tj = blockIdx.x;
    if (tj < ti) return;
    __shared__ float Ah[TS][68];
    __shared__ float Bh[TS][68];
    int tid = threadIdx.x;
    int tx = tid & 15, ty = tid >> 4;
    const float* ha = h + (size_t)ti * TS * 128;
    const float* hb = h + (size_t)tj * TS * 128;

    float acc[4][4];
    #pragma unroll
    for (int r = 0; r < 4; ++r)
        #pragma unroll
        for (int c = 0; c < 4; ++c) acc[r][c] = 0.0f;

    for (int half = 0; half < 2; ++half) {
        __syncthreads();
        #pragma unroll
        for (int t = 0; t < 4; ++t) {
            int f = tid + t * 256;        // 1024 float4 slots per 64x64-float half-tile
            int row = f >> 4, kk = f & 15;
            float4 va = *(const float4*)(ha + (size_t)row * 128 + half * 64 + kk * 4);
            float4 vb = *(const float4*)(hb + (size_t)row * 128 + half * 64 + kk * 4);
            *(float4*)&Ah[row][kk * 4] = va;
            *(float4*)&Bh[row][kk * 4] = vb;
        }
        __syncthreads();
        #pragma unroll 2
        for (int k4 = 0; k4 < 16; ++k4) {
            float4 a[4], b[4];
            #pragma unroll
            for (int r = 0; r < 4; ++r) a[r] = *(const float4*)&Ah[ty + 16 * r][k4 * 4];
            #pragma unroll
            for (int c = 0; c < 4; ++c) b[c] = *(const float4*)&Bh[tx + 16 * c][k4 * 4];
            #pragma unroll
            for (int r = 0; r < 4; ++r)
                #pragma unroll
                for (int c = 0; c < 4; ++c) {
                    acc[r][c] = fmaf(a[r].x, b[c].x, acc[r][c]);
                    acc[r][c] = fmaf(a[r].y, b[c].y, acc[r][c]);
                    acc[r][c] = fmaf(a[r].z, b[c].z, acc[r][c]);
                    acc[r][c] = fmaf(a[r].w, b[c].w, acc[r][c]);
                }
        }
    }

    if constexpr (MODE == 0) {
        float m = -3.4e38f;
        #pragma unroll
        for (int r = 0; r < 4; ++r)
            #pragma unroll
            for (int c = 0; c < 4; ++c) m = fmaxf(m, acc[r][c]);
        #pragma unroll
        for (int o = 1; o < 64; o <<= 1) m = fmaxf(m, __shfl_xor(m, o, 64));
        __shared__ float wm[4];
        if ((tid & 63) == 0) wm[tid >> 6] = m;
        __syncthreads();
        if (tid == 0) {
            float mm = fmaxf(fmaxf(wm[0], wm[1]), fmaxf(wm[2], wm[3]));
            atomicMax(smax_key, fkey(mm));
        }
    } else {
        float smax = funkey(*smax_key);
        float epmax = 1.0f / (1.0f + expf(-smax));
        __shared__ unsigned lm[TS][2];
        __shared__ unsigned lmT[TS][2];
        if (tid < 128) { lm[tid >> 1][tid & 1] = 0u; lmT[tid >> 1][tid & 1] = 0u; }
        __syncthreads();
        #pragma unroll
        for (int r = 0; r < 4; ++r) {
            #pragma unroll
            for (int c = 0; c < 4; ++c) {
                int li = ty + 16 * r, lj = tx + 16 * c;
                int gi = ti * TS + li, gj = tj * TS + lj;
                bool bit = false;
                if (gi < gj) {
                    float s = acc[r][c];
                    float ep = 1.0f / (1.0f + expf(-s));
                    float P = ep / epmax;
                    float Pc = fminf(fmaxf(P, 1e-6f), 1.0f - 1e-6f);
                    float uu = u[(size_t)gi * NN + gj];
                    float ucv = fminf(fmaxf(uu, 1e-6f), 1.0f - 1e-6f);
                    bit = Pc > (1.0f - ucv);    // logit(Pc)+logit(uc) > 0
                } else if (gi == gj) {
                    bit = true;                 // self-loop: diag forced to 1
                }
                if (bit) {
                    atomicOr(&lm[li][lj >> 5], 1u << (lj & 31));
                    atomicOr(&lmT[lj][li >> 5], 1u << (li & 31));
                }
            }
        }
        __syncthreads();
        if (tid < 128) {
            int r = tid >> 1, w = tid & 1;
            unsigned word = lm[r][w];
            if (ti == tj) word |= lmT[r][w];
            mb[(size_t)(ti * TS + r) * 128 + tj * 2 + w] = word;
        } else if (ti != tj) {
            int r = (tid - 128) >> 1, w = tid & 1;
            mb[(size_t)(tj * TS + r) * 128 + ti * 2 + w] = lmT[r][w];
        }
    }
}

// agg[i][d] = max over j in mask-row i of z[j][d]; one block per row, D threads.
template<int D>
__global__ void k_maskmax(const unsigned* __restrict__ mb, const float* __restrict__ z,
                          float* __restrict__ out) {
    int i = blockIdx.x;
    int d = threadIdx.x;
    const unsigned* row = mb + (size_t)i * 128;
    float m = -3.4e38f;
    for (int w = 0; w < 128; ++w) {
        unsigned word = row[w];
        while (word) {
            int b = __ffs(word) - 1;
            word &= word - 1;
            int j = w * 32 + b;
            m = fmaxf(m, z[(size_t)j * D + d]);
        }
    }
    out[(size_t)i * D + d] = m;
}

__global__ void k_relu_l2norm(float* __restrict__ h) {
    int i = blockIdx.x, d = threadIdx.x;   // 128 threads
    float v = fmaxf(h[(size_t)i * 128 + d], 0.0f);
    float ss = v * v;
    #pragma unroll
    for (int o = 1; o < 64; o <<= 1) ss += __shfl_xor(ss, o, 64);
    __shared__ float w2[2];
    if ((d & 63) == 0) w2[d >> 6] = ss;
    __syncthreads();
    float tot = w2[0] + w2[1];
    float denom = fmaxf(sqrtf(tot), 1e-12f);
    h[(size_t)i * 128 + d] = v / denom;
}

__global__ void k_gemm_final(const float* __restrict__ X, const float* __restrict__ W,
                             const float* __restrict__ b1, const float* __restrict__ b2,
                             float* __restrict__ out) {
    int i = blockIdx.x * 2 + (threadIdx.x >> 5);
    int j = threadIdx.x & 31;
    float acc = 0.0f;
    #pragma unroll 8
    for (int k = 0; k < 128; ++k) acc = fmaf(X[(size_t)i * 128 + k], W[k * 32 + j], acc);
    out[(size_t)i * 32 + j] = acc + b1[j] + b2[j];
}

extern "C" void kernel_launch(void* const* d_in, const int* in_sizes, int n_in,
                              void* d_out, int out_size, void* d_ws, size_t ws_size,
                              hipStream_t stream) {
    // input order per setup_inputs(): adj unused (ALPHA == 1.0 -> coefficient 0)
    const float* inputs = (const float*)d_in[1];
    const float* feat   = (const float*)d_in[2];
    const float* u      = (const float*)d_in[3];
    const int*   src    = (const int*)d_in[4];
    const int*   dst    = (const int*)d_in[5];
    const float* gc0W = (const float*)d_in[6],  *gc0b = (const float*)d_in[7];
    const float* gc1W = (const float*)d_in[8],  *gc1b = (const float*)d_in[9];
    const float* p0W  = (const float*)d_in[10], *p0b  = (const float*)d_in[11];
    const float* l0W  = (const float*)d_in[12], *l0b  = (const float*)d_in[13];
    const float* b0   = (const float*)d_in[14];
    const float* p1W  = (const float*)d_in[15], *p1b  = (const float*)d_in[16];
    const float* l1W  = (const float*)d_in[17], *l1b  = (const float*)d_in[18];
    const float* b1   = (const float*)d_in[19];
    const float* p2W  = (const float*)d_in[20], *p2b  = (const float*)d_in[21];
    const float* l2W  = (const float*)d_in[22], *l2b  = (const float*)d_in[23];
    const float* b2   = (const float*)d_in[24];
    float* out = (float*)d_out;

    char* w = (char*)d_ws;
    int*      cnt_src  = (int*)(w + 0);                         // 16 KB
    int*      cnt_dst  = (int*)(w + 16384);                     // 16 KB
    float*    on       = (float*)(w + 32768);                   // 16 KB
    float*    inn      = (float*)(w + 49152);                   // 16 KB
    unsigned* smax_key = (unsigned*)(w + 65536);                // (padded to 16 KB)
    float*    tmp      = (float*)(w + 81920);                   // 2 MB (4096x128)
    float*    agg      = (float*)(w + 81920 + 2097152);         // 2 MB
    float*    hbuf     = (float*)(w + 81920 + 2 * 2097152);     // 2 MB
    unsigned* mb       = (unsigned*)(w + 81920 + 3 * 2097152);  // 2 MB bitmask 4096x128 words
    float*    z        = (float*)(w + 81920 + 4 * 2097152);     // 4 MB (4096x256)
    float*    amax     = (float*)(w + 81920 + 4 * 2097152 + 4194304);      // 4 MB
    float*    hs       = (float*)(w + 81920 + 4 * 2097152 + 2 * 4194304);  // 2 MB

    // zero accumulators (counts, norms area, smax key)
    hipMemsetAsync(w, 0, 81920, stream);
    k_count<<<EE / 256, 256, 0, stream>>>(src, dst, cnt_src, cnt_dst);
    k_norm<<<NN / 256, 256, 0, stream>>>(cnt_src, cnt_dst, on, inn);

    // --- GCN layer 0 ---
    k_gemm_scale<256, 128><<<NN, 128, 0, stream>>>(inputs, gc0W, on, tmp);
    hipMemsetAsync(agg, 0, (size_t)NN * 128 * 4, stream);
    k_scatter<<<EE, 128, 0, stream>>>(tmp, src, dst, agg);
    k_gcn_out<<<NN * 128 / 256, 256, 0, stream>>>(agg, inn, gc0b, hbuf, 1);

    // --- GCN layer 1 ---
    k_gemm_scale<128, 128><<<NN, 128, 0, stream>>>(hbuf, gc1W, on, tmp);
    hipMemsetAsync(agg, 0, (size_t)NN * 128 * 4, stream);
    k_scatter<<<EE, 128, 0, stream>>>(tmp, src, dst, agg);
    k_gcn_out<<<NN * 128 / 256, 256, 0, stream>>>(agg, inn, gc1b, hbuf, 0);

    // --- decode: max(S) then mask bits ---
    dim3 tg(64, 64);
    k_stile<0><<<tg, 256, 0, stream>>>(hbuf, nullptr, smax_key, nullptr);
    k_stile<1><<<tg, 256, 0, stream>>>(hbuf, u, smax_key, mb);

    // --- GraphSAGE layer 0 (256 -> 128) ---
    k_gemm_ab<256, 256><<<NN, 256, 0, stream>>>(feat, p0W, p0b, nullptr, z, 1);
    k_maskmax<256><<<NN, 256, 0, stream>>>(mb, z, amax);
    k_gemm_ab<256, 128><<<NN, 128, 0, stream>>>(amax, l0W, l0b, b0, hs, 0);
    k_relu_l2norm<<<NN, 128, 0, stream>>>(hs);

    // --- GraphSAGE layer 1 (128 -> 128) ---
    k_gemm_ab<128, 128><<<NN, 128, 0, stream>>>(hs, p1W, p1b, nullptr, z, 1);
    k_maskmax<128><<<NN, 128, 0, stream>>>(mb, z, amax);
    k_gemm_ab<128, 128><<<NN, 128, 0, stream>>>(amax, l1W, l1b, b1, tmp, 0);
    k_relu_l2norm<<<NN, 128, 0, stream>>>(tmp);

    // --- GraphSAGE layer 2 (128 -> 32) ---
    k_gemm_ab<128, 128><<<NN, 128, 0, stream>>>(tmp, p2W, p2b, nullptr, z, 1);
    k_maskmax<128><<<NN, 128, 0, stream>>>(mb, z, amax);
    k_gemm_final<<<NN / 2, 64, 0, stream>>>(amax, l2W, l2b, b2, out);
}

// Round 3
// 1887.744 us; speedup vs baseline: 2.6998x; 1.4579x over previous
//
#include <hip/hip_runtime.h>
#include <cstdint>
#include <cstddef>

#define NN 4096
#define EE 131072
#define TS 64

__device__ __forceinline__ unsigned fkey(float f) {
    unsigned u = __float_as_uint(f);
    return (u & 0x80000000u) ? ~u : (u | 0x80000000u);
}
__device__ __forceinline__ float funkey(unsigned k) {
    unsigned u = (k & 0x80000000u) ? (k & 0x7fffffffu) : ~k;
    return __uint_as_float(u);
}

__global__ void k_count(const int* __restrict__ src, const int* __restrict__ dst,
                        int* __restrict__ cs, int* __restrict__ cd) {
    int e = blockIdx.x * 256 + threadIdx.x;
    if (e < EE) {
        atomicAdd(&cs[src[e]], 1);
        atomicAdd(&cd[dst[e]], 1);
    }
}

__global__ void k_norm(const int* __restrict__ cs, const int* __restrict__ cd,
                       float* __restrict__ on, float* __restrict__ inn) {
    int i = blockIdx.x * 256 + threadIdx.x;
    if (i < NN) {
        int a = cs[i] > 1 ? cs[i] : 1;
        int b = cd[i] > 1 ? cd[i] : 1;
        on[i]  = 1.0f / sqrtf((float)a);
        inn[i] = 1.0f / sqrtf((float)b);
    }
}

// out[i][j] = (sum_k X[i][k] * W[k][j]) * scale[i]
template<int K, int ND>
__global__ void k_gemm_scale(const float* __restrict__ X, const float* __restrict__ W,
                             const float* __restrict__ scale, float* __restrict__ out) {
    __shared__ float xr[K];
    int i = blockIdx.x;
    for (int k = threadIdx.x; k < K; k += ND) xr[k] = X[(size_t)i * K + k];
    __syncthreads();
    int j = threadIdx.x;
    float acc = 0.0f;
    #pragma unroll 8
    for (int k = 0; k < K; ++k) acc = fmaf(xr[k], W[k * ND + j], acc);
    out[(size_t)i * ND + j] = acc * scale[i];
}

// out[i][j] = X@W + b1[j] (+ b2[j]) (optionally relu).
// If X2 != nullptr, the effective X row is fmaxf(X, X2) (merges maskmax j-splits).
template<int K, int ND>
__global__ void k_gemm_ab(const float* __restrict__ X, const float* __restrict__ X2,
                          const float* __restrict__ W,
                          const float* __restrict__ b1, const float* __restrict__ b2,
                          float* __restrict__ out, int do_relu) {
    __shared__ float xr[K];
    int i = blockIdx.x;
    for (int k = threadIdx.x; k < K; k += ND) {
        float v = X[(size_t)i * K + k];
        if (X2) v = fmaxf(v, X2[(size_t)i * K + k]);
        xr[k] = v;
    }
    __syncthreads();
    int j = threadIdx.x;
    float acc = 0.0f;
    #pragma unroll 8
    for (int k = 0; k < K; ++k) acc = fmaf(xr[k], W[k * ND + j], acc);
    acc += b1[j];
    if (b2) acc += b2[j];
    if (do_relu) acc = fmaxf(acc, 0.0f);
    out[(size_t)i * ND + j] = acc;
}

__global__ void k_scatter(const float* __restrict__ t, const int* __restrict__ src,
                          const int* __restrict__ dst, float* __restrict__ agg) {
    int e = blockIdx.x;
    int j = threadIdx.x;   // 128 threads
    int s = src[e], d = dst[e];
    atomicAdd(&agg[(size_t)d * 128 + j], t[(size_t)s * 128 + j]);
}

__global__ void k_gcn_out(const float* __restrict__ agg, const float* __restrict__ inn,
                          const float* __restrict__ b, float* __restrict__ out, int do_relu) {
    int idx = blockIdx.x * 256 + threadIdx.x;   // N*128 total
    int i = idx >> 7, j = idx & 127;
    float v = agg[idx] * inn[i] + b[j];
    if (do_relu) v = fmaxf(v, 0.0f);
    out[idx] = v;
}

// S = h h^T, 64x64 tile per block, upper-triangular tiles only (S symmetric).
template<int MODE>
__global__ __launch_bounds__(256, 4) void k_stile(const float* __restrict__ h,
                                                  const float* __restrict__ u,
                                                  unsigned* __restrict__ smax_key,
                                                  unsigned* __restrict__ mb) {
    int ti = blockIdx.y, tj = blockIdx.x;
    if (tj < ti) return;
    __shared__ float Ah[TS][68];
    __shared__ float Bh[TS][68];
    int tid = threadIdx.x;
    int tx = tid & 15, ty = tid >> 4;
    const float* ha = h + (size_t)ti * TS * 128;
    const float* hb = h + (size_t)tj * TS * 128;

    float acc[4][4];
    #pragma unroll
    for (int r = 0; r < 4; ++r)
        #pragma unroll
        for (int c = 0; c < 4; ++c) acc[r][c] = 0.0f;

    for (int half = 0; half < 2; ++half) {
        __syncthreads();
        #pragma unroll
        for (int t = 0; t < 4; ++t) {
            int f = tid + t * 256;
            int row = f >> 4, kk = f & 15;
            float4 va = *(const float4*)(ha + (size_t)row * 128 + half * 64 + kk * 4);
            float4 vb = *(const float4*)(hb + (size_t)row * 128 + half * 64 + kk * 4);
            *(float4*)&Ah[row][kk * 4] = va;
            *(float4*)&Bh[row][kk * 4] = vb;
        }
        __syncthreads();
        #pragma unroll 2
        for (int k4 = 0; k4 < 16; ++k4) {
            float4 a[4], b[4];
            #pragma unroll
            for (int r = 0; r < 4; ++r) a[r] = *(const float4*)&Ah[ty + 16 * r][k4 * 4];
            #pragma unroll
            for (int c = 0; c < 4; ++c) b[c] = *(const float4*)&Bh[tx + 16 * c][k4 * 4];
            #pragma unroll
            for (int r = 0; r < 4; ++r)
                #pragma unroll
                for (int c = 0; c < 4; ++c) {
                    acc[r][c] = fmaf(a[r].x, b[c].x, acc[r][c]);
                    acc[r][c] = fmaf(a[r].y, b[c].y, acc[r][c]);
                    acc[r][c] = fmaf(a[r].z, b[c].z, acc[r][c]);
                    acc[r][c] = fmaf(a[r].w, b[c].w, acc[r][c]);
                }
        }
    }

    if constexpr (MODE == 0) {
        float m = -3.4e38f;
        #pragma unroll
        for (int r = 0; r < 4; ++r)
            #pragma unroll
            for (int c = 0; c < 4; ++c) m = fmaxf(m, acc[r][c]);
        #pragma unroll
        for (int o = 1; o < 64; o <<= 1) m = fmaxf(m, __shfl_xor(m, o, 64));
        __shared__ float wm[4];
        if ((tid & 63) == 0) wm[tid >> 6] = m;
        __syncthreads();
        if (tid == 0) {
            float mm = fmaxf(fmaxf(wm[0], wm[1]), fmaxf(wm[2], wm[3]));
            atomicMax(smax_key, fkey(mm));
        }
    } else {
        float smax = funkey(*smax_key);
        float epmax = 1.0f / (1.0f + expf(-smax));
        __shared__ unsigned lm[TS][2];
        __shared__ unsigned lmT[TS][2];
        if (tid < 128) { lm[tid >> 1][tid & 1] = 0u; lmT[tid >> 1][tid & 1] = 0u; }
        __syncthreads();
        #pragma unroll
        for (int r = 0; r < 4; ++r) {
            #pragma unroll
            for (int c = 0; c < 4; ++c) {
                int li = ty + 16 * r, lj = tx + 16 * c;
                int gi = ti * TS + li, gj = tj * TS + lj;
                bool bit = false;
                if (gi < gj) {
                    float s = acc[r][c];
                    float ep = 1.0f / (1.0f + expf(-s));
                    float P = ep / epmax;
                    float Pc = fminf(fmaxf(P, 1e-6f), 1.0f - 1e-6f);
                    float uu = u[(size_t)gi * NN + gj];
                    float ucv = fminf(fmaxf(uu, 1e-6f), 1.0f - 1e-6f);
                    bit = Pc > (1.0f - ucv);    // logit(Pc)+logit(uc) > 0
                } else if (gi == gj) {
                    bit = true;                 // self-loop
                }
                if (bit) {
                    atomicOr(&lm[li][lj >> 5], 1u << (lj & 31));
                    atomicOr(&lmT[lj][li >> 5], 1u << (li & 31));
                }
            }
        }
        __syncthreads();
        if (tid < 128) {
            int r = tid >> 1, w = tid & 1;
            unsigned word = lm[r][w];
            if (ti == tj) word |= lmT[r][w];
            mb[(size_t)(ti * TS + r) * 128 + tj * 2 + w] = word;
        } else if (ti != tj) {
            int r = (tid - 128) >> 1, w = tid & 1;
            mb[(size_t)(tj * TS + r) * 128 + ti * 2 + w] = lmT[r][w];
        }
    }
}

// Dense masked max: part[js][i][d] = max_j in split js of (bit(i,j) ? z[j][d] : 0).
// Valid because z = relu(..) >= 0 and every full row has its diagonal bit set,
// so +0.0 stand-ins never change the (>= 0) row max after merging splits.
// Block: RT rows x (NN/JS) cols. Threads: 256 = G groups x D4 lanes (D4 = D/4).
// Each thread holds RPG=RT/G float4 accumulators (64 independent max chains).
template<int D, int RT, int JS>
__global__ __launch_bounds__(256, 2) void k_maskmax_dense(const unsigned* __restrict__ mb,
                                                          const float* __restrict__ z,
                                                          float* __restrict__ part) {
    constexpr int D4 = D / 4;
    constexpr int G = 256 / D4;
    constexpr int RPG = RT / G;
    constexpr int W = 128 / JS;          // mask words per row in this split

    int bid = blockIdx.x;
    int rowblk = bid / JS, js = bid % JS;
    int i0 = rowblk * RT;

    __shared__ unsigned msk[RT][W];
    for (int t = threadIdx.x; t < RT * W; t += 256)
        msk[t / W][t % W] = mb[(size_t)(i0 + t / W) * 128 + js * W + t % W];
    __syncthreads();

    int d4 = threadIdx.x % D4;
    int g = threadIdx.x / D4;
    const float4* zr = (const float4*)z;

    float4 acc[RPG];
    #pragma unroll
    for (int r = 0; r < RPG; ++r) acc[r] = make_float4(0.f, 0.f, 0.f, 0.f);

    int jbase = js * (NN / JS);
    for (int w = 0; w < W; ++w) {
        unsigned wr[RPG];
        #pragma unroll
        for (int r = 0; r < RPG; ++r) wr[r] = msk[g * RPG + r][w];
        size_t zb = (size_t)(jbase + w * 32) * D4 + d4;
        #pragma unroll 8
        for (int jj = 0; jj < 32; jj += 2) {
            float4 z0 = zr[zb + (size_t)jj * D4];
            float4 z1 = zr[zb + (size_t)(jj + 1) * D4];
            #pragma unroll
            for (int r = 0; r < RPG; ++r) {
                unsigned m0 = (unsigned)(-(int)((wr[r] >> jj) & 1u));
                unsigned m1 = (unsigned)(-(int)((wr[r] >> (jj + 1)) & 1u));
                acc[r].x = fmaxf(acc[r].x, fmaxf(__uint_as_float(m0 & __float_as_uint(z0.x)),
                                                 __uint_as_float(m1 & __float_as_uint(z1.x))));
                acc[r].y = fmaxf(acc[r].y, fmaxf(__uint_as_float(m0 & __float_as_uint(z0.y)),
                                                 __uint_as_float(m1 & __float_as_uint(z1.y))));
                acc[r].z = fmaxf(acc[r].z, fmaxf(__uint_as_float(m0 & __float_as_uint(z0.z)),
                                                 __uint_as_float(m1 & __float_as_uint(z1.z))));
                acc[r].w = fmaxf(acc[r].w, fmaxf(__uint_as_float(m0 & __float_as_uint(z0.w)),
                                                 __uint_as_float(m1 & __float_as_uint(z1.w))));
            }
        }
    }

    float4* po = (float4*)(part + (size_t)js * NN * D);
    #pragma unroll
    for (int r = 0; r < RPG; ++r)
        po[(size_t)(i0 + g * RPG + r) * D4 + d4] = acc[r];
}

__global__ void k_relu_l2norm(float* __restrict__ h) {
    int i = blockIdx.x, d = threadIdx.x;   // 128 threads
    float v = fmaxf(h[(size_t)i * 128 + d], 0.0f);
    float ss = v * v;
    #pragma unroll
    for (int o = 1; o < 64; o <<= 1) ss += __shfl_xor(ss, o, 64);
    __shared__ float w2[2];
    if ((d & 63) == 0) w2[d >> 6] = ss;
    __syncthreads();
    float tot = w2[0] + w2[1];
    float denom = fmaxf(sqrtf(tot), 1e-12f);
    h[(size_t)i * 128 + d] = v / denom;
}

__global__ void k_gemm_final(const float* __restrict__ X, const float* __restrict__ X2,
                             const float* __restrict__ W,
                             const float* __restrict__ b1, const float* __restrict__ b2,
                             float* __restrict__ out) {
    int i = blockIdx.x * 2 + (threadIdx.x >> 5);
    int j = threadIdx.x & 31;
    float acc = 0.0f;
    #pragma unroll 8
    for (int k = 0; k < 128; ++k) {
        float v = fmaxf(X[(size_t)i * 128 + k], X2[(size_t)i * 128 + k]);
        acc = fmaf(v, W[k * 32 + j], acc);
    }
    out[(size_t)i * 32 + j] = acc + b1[j] + b2[j];
}

extern "C" void kernel_launch(void* const* d_in, const int* in_sizes, int n_in,
                              void* d_out, int out_size, void* d_ws, size_t ws_size,
                              hipStream_t stream) {
    // input order per setup_inputs(): adj unused (ALPHA == 1.0 -> coefficient 0)
    const float* inputs = (const float*)d_in[1];
    const float* feat   = (const float*)d_in[2];
    const float* u      = (const float*)d_in[3];
    const int*   src    = (const int*)d_in[4];
    const int*   dst    = (const int*)d_in[5];
    const float* gc0W = (const float*)d_in[6],  *gc0b = (const float*)d_in[7];
    const float* gc1W = (const float*)d_in[8],  *gc1b = (const float*)d_in[9];
    const float* p0W  = (const float*)d_in[10], *p0b  = (const float*)d_in[11];
    const float* l0W  = (const float*)d_in[12], *l0b  = (const float*)d_in[13];
    const float* b0   = (const float*)d_in[14];
    const float* p1W  = (const float*)d_in[15], *p1b  = (const float*)d_in[16];
    const float* l1W  = (const float*)d_in[17], *l1b  = (const float*)d_in[18];
    const float* b1   = (const float*)d_in[19];
    const float* p2W  = (const float*)d_in[20], *p2b  = (const float*)d_in[21];
    const float* l2W  = (const float*)d_in[22], *l2b  = (const float*)d_in[23];
    const float* b2   = (const float*)d_in[24];
    float* out = (float*)d_out;

    char* w = (char*)d_ws;
    int*      cnt_src  = (int*)(w + 0);
    int*      cnt_dst  = (int*)(w + 16384);
    float*    on       = (float*)(w + 32768);
    float*    inn      = (float*)(w + 49152);
    unsigned* smax_key = (unsigned*)(w + 65536);
    float*    tmp      = (float*)(w + 81920);                   // 2 MB
    float*    agg      = (float*)(w + 81920 + 2097152);         // 2 MB
    float*    hbuf     = (float*)(w + 81920 + 2 * 2097152);     // 2 MB
    unsigned* mb       = (unsigned*)(w + 81920 + 3 * 2097152);  // 2 MB
    float*    z        = (float*)(w + 81920 + 4 * 2097152);     // 4 MB (4096x256 max)
    float*    pm       = (float*)(w + 81920 + 4 * 2097152 + 4194304);      // 8 MB (2 splits)
    float*    hs       = (float*)(w + 81920 + 4 * 2097152 + 3 * 4194304);  // 2 MB

    hipMemsetAsync(w, 0, 81920, stream);
    k_count<<<EE / 256, 256, 0, stream>>>(src, dst, cnt_src, cnt_dst);
    k_norm<<<NN / 256, 256, 0, stream>>>(cnt_src, cnt_dst, on, inn);

    // --- GCN layer 0 ---
    k_gemm_scale<256, 128><<<NN, 128, 0, stream>>>(inputs, gc0W, on, tmp);
    hipMemsetAsync(agg, 0, (size_t)NN * 128 * 4, stream);
    k_scatter<<<EE, 128, 0, stream>>>(tmp, src, dst, agg);
    k_gcn_out<<<NN * 128 / 256, 256, 0, stream>>>(agg, inn, gc0b, hbuf, 1);

    // --- GCN layer 1 ---
    k_gemm_scale<128, 128><<<NN, 128, 0, stream>>>(hbuf, gc1W, on, tmp);
    hipMemsetAsync(agg, 0, (size_t)NN * 128 * 4, stream);
    k_scatter<<<EE, 128, 0, stream>>>(tmp, src, dst, agg);
    k_gcn_out<<<NN * 128 / 256, 256, 0, stream>>>(agg, inn, gc1b, hbuf, 0);

    // --- decode: max(S) then mask bits ---
    dim3 tg(64, 64);
    k_stile<0><<<tg, 256, 0, stream>>>(hbuf, nullptr, smax_key, nullptr);
    k_stile<1><<<tg, 256, 0, stream>>>(hbuf, u, smax_key, mb);

    // --- GraphSAGE layer 0 (256 -> 128) ---
    k_gemm_ab<256, 256><<<NN, 256, 0, stream>>>(feat, nullptr, p0W, p0b, nullptr, z, 1);
    k_maskmax_dense<256, 32, 2><<<(NN / 32) * 2, 256, 0, stream>>>(mb, z, pm);
    k_gemm_ab<256, 128><<<NN, 128, 0, stream>>>(pm, pm + (size_t)NN * 256, l0W, l0b, b0, hs, 0);
    k_relu_l2norm<<<NN, 128, 0, stream>>>(hs);

    // --- GraphSAGE layer 1 (128 -> 128) ---
    k_gemm_ab<128, 128><<<NN, 128, 0, stream>>>(hs, nullptr, p1W, p1b, nullptr, z, 1);
    k_maskmax_dense<128, 32, 2><<<(NN / 32) * 2, 256, 0, stream>>>(mb, z, pm);
    k_gemm_ab<128, 128><<<NN, 128, 0, stream>>>(pm, pm + (size_t)NN * 128, l1W, l1b, b1, tmp, 0);
    k_relu_l2norm<<<NN, 128, 0, stream>>>(tmp);

    // --- GraphSAGE layer 2 (128 -> 32) ---
    k_gemm_ab<128, 128><<<NN, 128, 0, stream>>>(tmp, nullptr, p2W, p2b, nullptr, z, 1);
    k_maskmax_dense<128, 32, 2><<<(NN / 32) * 2, 256, 0, stream>>>(mb, z, pm);
    k_gemm_final<<<NN / 2, 64, 0, stream>>>(pm, pm + (size_t)NN * 128, l2W, l2b, b2, out);
}

// Round 4
// 1485.798 us; speedup vs baseline: 3.4302x; 1.2705x over previous
//
#include <hip/hip_runtime.h>
#include <cstdint>
#include <cstddef>

#define NN 4096
#define EE 131072
#define TS 64

__device__ __forceinline__ unsigned fkey(float f) {
    unsigned u = __float_as_uint(f);
    return (u & 0x80000000u) ? ~u : (u | 0x80000000u);
}
__device__ __forceinline__ float funkey(unsigned k) {
    unsigned u = (k & 0x80000000u) ? (k & 0x7fffffffu) : ~k;
    return __uint_as_float(u);
}

__global__ void k_count(const int* __restrict__ src, const int* __restrict__ dst,
                        int* __restrict__ cs, int* __restrict__ cd) {
    int e = blockIdx.x * 256 + threadIdx.x;
    if (e < EE) {
        atomicAdd(&cs[src[e]], 1);
        atomicAdd(&cd[dst[e]], 1);
    }
}

__global__ void k_norm(const int* __restrict__ cs, const int* __restrict__ cd,
                       float* __restrict__ on, float* __restrict__ inn) {
    int i = blockIdx.x * 256 + threadIdx.x;
    if (i < NN) {
        int a = cs[i] > 1 ? cs[i] : 1;
        int b = cd[i] > 1 ? cd[i] : 1;
        on[i]  = 1.0f / sqrtf((float)a);
        inn[i] = 1.0f / sqrtf((float)b);
    }
}

// out[i][j] = (sum_k X[i][k] * W[k][j]) * scale[i]
template<int K, int ND>
__global__ void k_gemm_scale(const float* __restrict__ X, const float* __restrict__ W,
                             const float* __restrict__ scale, float* __restrict__ out) {
    __shared__ float xr[K];
    int i = blockIdx.x;
    for (int k = threadIdx.x; k < K; k += ND) xr[k] = X[(size_t)i * K + k];
    __syncthreads();
    int j = threadIdx.x;
    float acc = 0.0f;
    #pragma unroll 8
    for (int k = 0; k < K; ++k) acc = fmaf(xr[k], W[k * ND + j], acc);
    out[(size_t)i * ND + j] = acc * scale[i];
}

// out[i][j] = X@W + b1[j] (+ b2[j]) (optionally relu).
template<int K, int ND>
__global__ void k_gemm_ab(const float* __restrict__ X, const float* __restrict__ W,
                          const float* __restrict__ b1, const float* __restrict__ b2,
                          float* __restrict__ out, int do_relu) {
    __shared__ float xr[K];
    int i = blockIdx.x;
    for (int k = threadIdx.x; k < K; k += ND) xr[k] = X[(size_t)i * K + k];
    __syncthreads();
    int j = threadIdx.x;
    float acc = 0.0f;
    #pragma unroll 8
    for (int k = 0; k < K; ++k) acc = fmaf(xr[k], W[k * ND + j], acc);
    acc += b1[j];
    if (b2) acc += b2[j];
    if (do_relu) acc = fmaxf(acc, 0.0f);
    out[(size_t)i * ND + j] = acc;
}

__global__ void k_scatter(const float* __restrict__ t, const int* __restrict__ src,
                          const int* __restrict__ dst, float* __restrict__ agg) {
    int e = blockIdx.x;
    int j = threadIdx.x;   // 128 threads
    int s = src[e], d = dst[e];
    atomicAdd(&agg[(size_t)d * 128 + j], t[(size_t)s * 128 + j]);
}

__global__ void k_gcn_out(const float* __restrict__ agg, const float* __restrict__ inn,
                          const float* __restrict__ b, float* __restrict__ out, int do_relu) {
    int idx = blockIdx.x * 256 + threadIdx.x;   // N*128 total
    int i = idx >> 7, j = idx & 127;
    float v = agg[idx] * inn[i] + b[j];
    if (do_relu) v = fmaxf(v, 0.0f);
    out[idx] = v;
}

// S = h h^T, 64x64 tile per block, upper-triangular tiles only (S symmetric).
template<int MODE>
__global__ __launch_bounds__(256, 4) void k_stile(const float* __restrict__ h,
                                                  const float* __restrict__ u,
                                                  unsigned* __restrict__ smax_key,
                                                  unsigned* __restrict__ mb) {
    int ti = blockIdx.y, tj = blockIdx.x;
    if (tj < ti) return;
    __shared__ float Ah[TS][68];
    __shared__ float Bh[TS][68];
    int tid = threadIdx.x;
    int tx = tid & 15, ty = tid >> 4;
    const float* ha = h + (size_t)ti * TS * 128;
    const float* hb = h + (size_t)tj * TS * 128;

    float acc[4][4];
    #pragma unroll
    for (int r = 0; r < 4; ++r)
        #pragma unroll
        for (int c = 0; c < 4; ++c) acc[r][c] = 0.0f;

    for (int half = 0; half < 2; ++half) {
        __syncthreads();
        #pragma unroll
        for (int t = 0; t < 4; ++t) {
            int f = tid + t * 256;
            int row = f >> 4, kk = f & 15;
            float4 va = *(const float4*)(ha + (size_t)row * 128 + half * 64 + kk * 4);
            float4 vb = *(const float4*)(hb + (size_t)row * 128 + half * 64 + kk * 4);
            *(float4*)&Ah[row][kk * 4] = va;
            *(float4*)&Bh[row][kk * 4] = vb;
        }
        __syncthreads();
        #pragma unroll 2
        for (int k4 = 0; k4 < 16; ++k4) {
            float4 a[4], b[4];
            #pragma unroll
            for (int r = 0; r < 4; ++r) a[r] = *(const float4*)&Ah[ty + 16 * r][k4 * 4];
            #pragma unroll
            for (int c = 0; c < 4; ++c) b[c] = *(const float4*)&Bh[tx + 16 * c][k4 * 4];
            #pragma unroll
            for (int r = 0; r < 4; ++r)
                #pragma unroll
                for (int c = 0; c < 4; ++c) {
                    acc[r][c] = fmaf(a[r].x, b[c].x, acc[r][c]);
                    acc[r][c] = fmaf(a[r].y, b[c].y, acc[r][c]);
                    acc[r][c] = fmaf(a[r].z, b[c].z, acc[r][c]);
                    acc[r][c] = fmaf(a[r].w, b[c].w, acc[r][c]);
                }
        }
    }

    if constexpr (MODE == 0) {
        float m = -3.4e38f;
        #pragma unroll
        for (int r = 0; r < 4; ++r)
            #pragma unroll
            for (int c = 0; c < 4; ++c) m = fmaxf(m, acc[r][c]);
        #pragma unroll
        for (int o = 1; o < 64; o <<= 1) m = fmaxf(m, __shfl_xor(m, o, 64));
        __shared__ float wm[4];
        if ((tid & 63) == 0) wm[tid >> 6] = m;
        __syncthreads();
        if (tid == 0) {
            float mm = fmaxf(fmaxf(wm[0], wm[1]), fmaxf(wm[2], wm[3]));
            atomicMax(smax_key, fkey(mm));
        }
    } else {
        float smax = funkey(*smax_key);
        float epmax = 1.0f / (1.0f + expf(-smax));
        __shared__ unsigned lm[TS][2];
        __shared__ unsigned lmT[TS][2];
        if (tid < 128) { lm[tid >> 1][tid & 1] = 0u; lmT[tid >> 1][tid & 1] = 0u; }
        __syncthreads();
        #pragma unroll
        for (int r = 0; r < 4; ++r) {
            #pragma unroll
            for (int c = 0; c < 4; ++c) {
                int li = ty + 16 * r, lj = tx + 16 * c;
                int gi = ti * TS + li, gj = tj * TS + lj;
                bool bit = false;
                if (gi < gj) {
                    float s = acc[r][c];
                    float ep = 1.0f / (1.0f + expf(-s));
                    float P = ep / epmax;
                    float Pc = fminf(fmaxf(P, 1e-6f), 1.0f - 1e-6f);
                    float uu = u[(size_t)gi * NN + gj];
                    float ucv = fminf(fmaxf(uu, 1e-6f), 1.0f - 1e-6f);
                    bit = Pc > (1.0f - ucv);    // logit(Pc)+logit(uc) > 0
                } else if (gi == gj) {
                    bit = true;                 // self-loop
                }
                if (bit) {
                    atomicOr(&lm[li][lj >> 5], 1u << (lj & 31));
                    atomicOr(&lmT[lj][li >> 5], 1u << (li & 31));
                }
            }
        }
        __syncthreads();
        if (tid < 128) {
            int r = tid >> 1, w = tid & 1;
            unsigned word = lm[r][w];
            if (ti == tj) word |= lmT[r][w];
            mb[(size_t)(ti * TS + r) * 128 + tj * 2 + w] = word;
        } else if (ti != tj) {
            int r = (tid - 128) >> 1, w = tid & 1;
            mb[(size_t)(tj * TS + r) * 128 + ti * 2 + w] = lmT[r][w];
        }
    }
}

// Dense masked max: out[i][d] = max_j (bit(i,j) ? z[j][d] : 0).
// Valid because z = relu(..) >= 0 and every row has its diagonal bit set.
// Block: RT=8 rows x all 4096 cols. 256 thr = G row-groups x D4 lanes.
// Mask bit -> full-word mask via (wr << (31-jj)) >> 31  (v_bfe_i32, 1 inst);
// two j's merged per acc update via v_max3_f32 fusion.
template<int D, int RT>
__global__ __launch_bounds__(256, 4) void k_maskmax_dense(const unsigned* __restrict__ mb,
                                                          const float* __restrict__ z,
                                                          float* __restrict__ outp) {
    constexpr int D4 = D / 4;          // 64 (D=256) or 32 (D=128)
    constexpr int G = 256 / D4;        // 4 or 8
    constexpr int RPG = RT / G;        // 2 or 1

    int i0 = blockIdx.x * RT;

    __shared__ unsigned msk[RT][129];  // pad: avoid same-bank across row-groups
    for (int t = threadIdx.x; t < RT * 128; t += 256)
        msk[t >> 7][t & 127] = mb[(size_t)(i0 + (t >> 7)) * 128 + (t & 127)];
    __syncthreads();

    int d4 = threadIdx.x % D4;
    int g = threadIdx.x / D4;
    const float4* zr = (const float4*)z + d4;

    float4 acc[RPG];
    #pragma unroll
    for (int r = 0; r < RPG; ++r) acc[r] = make_float4(0.f, 0.f, 0.f, 0.f);

    for (int w = 0; w < 128; ++w) {
        unsigned wr[RPG];
        #pragma unroll
        for (int r = 0; r < RPG; ++r) wr[r] = msk[g * RPG + r][w];
        const float4* zp = zr + (size_t)(w * 32) * D4;
        #pragma unroll 8
        for (int jj = 0; jj < 32; jj += 2) {
            float4 z0 = zp[jj * D4];
            float4 z1 = zp[(jj + 1) * D4];
            #pragma unroll
            for (int r = 0; r < RPG; ++r) {
                unsigned m0 = (unsigned)(((int)(wr[r] << (31 - jj))) >> 31);
                unsigned m1 = (unsigned)(((int)(wr[r] << (30 - jj))) >> 31);
                acc[r].x = fmaxf(acc[r].x, fmaxf(__uint_as_float(m0 & __float_as_uint(z0.x)),
                                                 __uint_as_float(m1 & __float_as_uint(z1.x))));
                acc[r].y = fmaxf(acc[r].y, fmaxf(__uint_as_float(m0 & __float_as_uint(z0.y)),
                                                 __uint_as_float(m1 & __float_as_uint(z1.y))));
                acc[r].z = fmaxf(acc[r].z, fmaxf(__uint_as_float(m0 & __float_as_uint(z0.z)),
                                                 __uint_as_float(m1 & __float_as_uint(z1.z))));
                acc[r].w = fmaxf(acc[r].w, fmaxf(__uint_as_float(m0 & __float_as_uint(z0.w)),
                                                 __uint_as_float(m1 & __float_as_uint(z1.w))));
            }
        }
    }

    float4* po = (float4*)outp;
    #pragma unroll
    for (int r = 0; r < RPG; ++r)
        po[(size_t)(i0 + g * RPG + r) * D4 + d4] = acc[r];
}

__global__ void k_relu_l2norm(float* __restrict__ h) {
    int i = blockIdx.x, d = threadIdx.x;   // 128 threads
    float v = fmaxf(h[(size_t)i * 128 + d], 0.0f);
    float ss = v * v;
    #pragma unroll
    for (int o = 1; o < 64; o <<= 1) ss += __shfl_xor(ss, o, 64);
    __shared__ float w2[2];
    if ((d & 63) == 0) w2[d >> 6] = ss;
    __syncthreads();
    float tot = w2[0] + w2[1];
    float denom = fmaxf(sqrtf(tot), 1e-12f);
    h[(size_t)i * 128 + d] = v / denom;
}

__global__ void k_gemm_final(const float* __restrict__ X, const float* __restrict__ W,
                             const float* __restrict__ b1, const float* __restrict__ b2,
                             float* __restrict__ out) {
    int i = blockIdx.x * 2 + (threadIdx.x >> 5);
    int j = threadIdx.x & 31;
    float acc = 0.0f;
    #pragma unroll 8
    for (int k = 0; k < 128; ++k) acc = fmaf(X[(size_t)i * 128 + k], W[k * 32 + j], acc);
    out[(size_t)i * 32 + j] = acc + b1[j] + b2[j];
}

extern "C" void kernel_launch(void* const* d_in, const int* in_sizes, int n_in,
                              void* d_out, int out_size, void* d_ws, size_t ws_size,
                              hipStream_t stream) {
    // input order per setup_inputs(): adj unused (ALPHA == 1.0 -> coefficient 0)
    const float* inputs = (const float*)d_in[1];
    const float* feat   = (const float*)d_in[2];
    const float* u      = (const float*)d_in[3];
    const int*   src    = (const int*)d_in[4];
    const int*   dst    = (const int*)d_in[5];
    const float* gc0W = (const float*)d_in[6],  *gc0b = (const float*)d_in[7];
    const float* gc1W = (const float*)d_in[8],  *gc1b = (const float*)d_in[9];
    const float* p0W  = (const float*)d_in[10], *p0b  = (const float*)d_in[11];
    const float* l0W  = (const float*)d_in[12], *l0b  = (const float*)d_in[13];
    const float* b0   = (const float*)d_in[14];
    const float* p1W  = (const float*)d_in[15], *p1b  = (const float*)d_in[16];
    const float* l1W  = (const float*)d_in[17], *l1b  = (const float*)d_in[18];
    const float* b1   = (const float*)d_in[19];
    const float* p2W  = (const float*)d_in[20], *p2b  = (const float*)d_in[21];
    const float* l2W  = (const float*)d_in[22], *l2b  = (const float*)d_in[23];
    const float* b2   = (const float*)d_in[24];
    float* out = (float*)d_out;

    char* w = (char*)d_ws;
    int*      cnt_src  = (int*)(w + 0);
    int*      cnt_dst  = (int*)(w + 16384);
    float*    on       = (float*)(w + 32768);
    float*    inn      = (float*)(w + 49152);
    unsigned* smax_key = (unsigned*)(w + 65536);
    float*    tmp      = (float*)(w + 81920);                   // 2 MB
    float*    agg      = (float*)(w + 81920 + 2097152);         // 2 MB
    float*    hbuf     = (float*)(w + 81920 + 2 * 2097152);     // 2 MB
    unsigned* mb       = (unsigned*)(w + 81920 + 3 * 2097152);  // 2 MB
    float*    z        = (float*)(w + 81920 + 4 * 2097152);     // 4 MB (4096x256 max)
    float*    pm       = (float*)(w + 81920 + 4 * 2097152 + 4194304);      // 4 MB
    float*    hs       = (float*)(w + 81920 + 4 * 2097152 + 2 * 4194304);  // 2 MB

    hipMemsetAsync(w, 0, 81920, stream);
    k_count<<<EE / 256, 256, 0, stream>>>(src, dst, cnt_src, cnt_dst);
    k_norm<<<NN / 256, 256, 0, stream>>>(cnt_src, cnt_dst, on, inn);

    // --- GCN layer 0 ---
    k_gemm_scale<256, 128><<<NN, 128, 0, stream>>>(inputs, gc0W, on, tmp);
    hipMemsetAsync(agg, 0, (size_t)NN * 128 * 4, stream);
    k_scatter<<<EE, 128, 0, stream>>>(tmp, src, dst, agg);
    k_gcn_out<<<NN * 128 / 256, 256, 0, stream>>>(agg, inn, gc0b, hbuf, 1);

    // --- GCN layer 1 ---
    k_gemm_scale<128, 128><<<NN, 128, 0, stream>>>(hbuf, gc1W, on, tmp);
    hipMemsetAsync(agg, 0, (size_t)NN * 128 * 4, stream);
    k_scatter<<<EE, 128, 0, stream>>>(tmp, src, dst, agg);
    k_gcn_out<<<NN * 128 / 256, 256, 0, stream>>>(agg, inn, gc1b, hbuf, 0);

    // --- decode: max(S) then mask bits ---
    dim3 tg(64, 64);
    k_stile<0><<<tg, 256, 0, stream>>>(hbuf, nullptr, smax_key, nullptr);
    k_stile<1><<<tg, 256, 0, stream>>>(hbuf, u, smax_key, mb);

    // --- GraphSAGE layer 0 (256 -> 128) ---
    k_gemm_ab<256, 256><<<NN, 256, 0, stream>>>(feat, p0W, p0b, nullptr, z, 1);
    k_maskmax_dense<256, 8><<<NN / 8, 256, 0, stream>>>(mb, z, pm);
    k_gemm_ab<256, 128><<<NN, 128, 0, stream>>>(pm, l0W, l0b, b0, hs, 0);
    k_relu_l2norm<<<NN, 128, 0, stream>>>(hs);

    // --- GraphSAGE layer 1 (128 -> 128) ---
    k_gemm_ab<128, 128><<<NN, 128, 0, stream>>>(hs, p1W, p1b, nullptr, z, 1);
    k_maskmax_dense<128, 8><<<NN / 8, 256, 0, stream>>>(mb, z, pm);
    k_gemm_ab<128, 128><<<NN, 128, 0, stream>>>(pm, l1W, l1b, b1, tmp, 0);
    k_relu_l2norm<<<NN, 128, 0, stream>>>(tmp);

    // --- GraphSAGE layer 2 (128 -> 32) ---
    k_gemm_ab<128, 128><<<NN, 128, 0, stream>>>(tmp, p2W, p2b, nullptr, z, 1);
    k_maskmax_dense<128, 8><<<NN / 8, 256, 0, stream>>>(mb, z, pm);
    k_gemm_final<<<NN / 2, 64, 0, stream>>>(pm, l2W, l2b, b2, out);
}

// Round 5
// 1465.287 us; speedup vs baseline: 3.4782x; 1.0140x over previous
//
#include <hip/hip_runtime.h>
#include <cstdint>
#include <cstddef>

#define NN 4096
#define EE 131072
#define TS 64

__device__ __forceinline__ unsigned fkey(float f) {
    unsigned u = __float_as_uint(f);
    return (u & 0x80000000u) ? ~u : (u | 0x80000000u);
}
__device__ __forceinline__ float funkey(unsigned k) {
    unsigned u = (k & 0x80000000u) ? (k & 0x7fffffffu) : ~k;
    return __uint_as_float(u);
}

__global__ void k_count(const int* __restrict__ src, const int* __restrict__ dst,
                        int* __restrict__ cs, int* __restrict__ cd) {
    int e = blockIdx.x * 256 + threadIdx.x;
    if (e < EE) {
        atomicAdd(&cs[src[e]], 1);
        atomicAdd(&cd[dst[e]], 1);
    }
}

__global__ void k_norm(const int* __restrict__ cs, const int* __restrict__ cd,
                       float* __restrict__ on, float* __restrict__ inn) {
    int i = blockIdx.x * 256 + threadIdx.x;
    if (i < NN) {
        int a = cs[i] > 1 ? cs[i] : 1;
        int b = cd[i] > 1 ? cd[i] : 1;
        on[i]  = 1.0f / sqrtf((float)a);
        inn[i] = 1.0f / sqrtf((float)b);
    }
}

// out[i][j] = (sum_k X[i][k] * W[k][j]) * scale[i]
template<int K, int ND>
__global__ void k_gemm_scale(const float* __restrict__ X, const float* __restrict__ W,
                             const float* __restrict__ scale, float* __restrict__ out) {
    __shared__ float xr[K];
    int i = blockIdx.x;
    for (int k = threadIdx.x; k < K; k += ND) xr[k] = X[(size_t)i * K + k];
    __syncthreads();
    int j = threadIdx.x;
    float acc = 0.0f;
    #pragma unroll 8
    for (int k = 0; k < K; ++k) acc = fmaf(xr[k], W[k * ND + j], acc);
    out[(size_t)i * ND + j] = acc * scale[i];
}

// out[i][j] = X@W + b1[j] (+ b2[j]) (optionally relu).
template<int K, int ND>
__global__ void k_gemm_ab(const float* __restrict__ X, const float* __restrict__ W,
                          const float* __restrict__ b1, const float* __restrict__ b2,
                          float* __restrict__ out, int do_relu) {
    __shared__ float xr[K];
    int i = blockIdx.x;
    for (int k = threadIdx.x; k < K; k += ND) xr[k] = X[(size_t)i * K + k];
    __syncthreads();
    int j = threadIdx.x;
    float acc = 0.0f;
    #pragma unroll 8
    for (int k = 0; k < K; ++k) acc = fmaf(xr[k], W[k * ND + j], acc);
    acc += b1[j];
    if (b2) acc += b2[j];
    if (do_relu) acc = fmaxf(acc, 0.0f);
    out[(size_t)i * ND + j] = acc;
}

__global__ void k_scatter(const float* __restrict__ t, const int* __restrict__ src,
                          const int* __restrict__ dst, float* __restrict__ agg) {
    int e = blockIdx.x;
    int j = threadIdx.x;   // 128 threads
    int s = src[e], d = dst[e];
    atomicAdd(&agg[(size_t)d * 128 + j], t[(size_t)s * 128 + j]);
}

__global__ void k_gcn_out(const float* __restrict__ agg, const float* __restrict__ inn,
                          const float* __restrict__ b, float* __restrict__ out, int do_relu) {
    int idx = blockIdx.x * 256 + threadIdx.x;   // N*128 total
    int i = idx >> 7, j = idx & 127;
    float v = agg[idx] * inn[i] + b[j];
    if (do_relu) v = fmaxf(v, 0.0f);
    out[idx] = v;
}

// S = h h^T, 64x64 tile per block, upper-triangular tiles only (S symmetric).
template<int MODE>
__global__ __launch_bounds__(256, 4) void k_stile(const float* __restrict__ h,
                                                  const float* __restrict__ u,
                                                  unsigned* __restrict__ smax_key,
                                                  unsigned* __restrict__ mb) {
    int ti = blockIdx.y, tj = blockIdx.x;
    if (tj < ti) return;
    __shared__ float Ah[TS][68];
    __shared__ float Bh[TS][68];
    int tid = threadIdx.x;
    int tx = tid & 15, ty = tid >> 4;
    const float* ha = h + (size_t)ti * TS * 128;
    const float* hb = h + (size_t)tj * TS * 128;

    float acc[4][4];
    #pragma unroll
    for (int r = 0; r < 4; ++r)
        #pragma unroll
        for (int c = 0; c < 4; ++c) acc[r][c] = 0.0f;

    for (int half = 0; half < 2; ++half) {
        __syncthreads();
        #pragma unroll
        for (int t = 0; t < 4; ++t) {
            int f = tid + t * 256;
            int row = f >> 4, kk = f & 15;
            float4 va = *(const float4*)(ha + (size_t)row * 128 + half * 64 + kk * 4);
            float4 vb = *(const float4*)(hb + (size_t)row * 128 + half * 64 + kk * 4);
            *(float4*)&Ah[row][kk * 4] = va;
            *(float4*)&Bh[row][kk * 4] = vb;
        }
        __syncthreads();
        #pragma unroll 2
        for (int k4 = 0; k4 < 16; ++k4) {
            float4 a[4], b[4];
            #pragma unroll
            for (int r = 0; r < 4; ++r) a[r] = *(const float4*)&Ah[ty + 16 * r][k4 * 4];
            #pragma unroll
            for (int c = 0; c < 4; ++c) b[c] = *(const float4*)&Bh[tx + 16 * c][k4 * 4];
            #pragma unroll
            for (int r = 0; r < 4; ++r)
                #pragma unroll
                for (int c = 0; c < 4; ++c) {
                    acc[r][c] = fmaf(a[r].x, b[c].x, acc[r][c]);
                    acc[r][c] = fmaf(a[r].y, b[c].y, acc[r][c]);
                    acc[r][c] = fmaf(a[r].z, b[c].z, acc[r][c]);
                    acc[r][c] = fmaf(a[r].w, b[c].w, acc[r][c]);
                }
        }
    }

    if constexpr (MODE == 0) {
        float m = -3.4e38f;
        #pragma unroll
        for (int r = 0; r < 4; ++r)
            #pragma unroll
            for (int c = 0; c < 4; ++c) m = fmaxf(m, acc[r][c]);
        #pragma unroll
        for (int o = 1; o < 64; o <<= 1) m = fmaxf(m, __shfl_xor(m, o, 64));
        __shared__ float wm[4];
        if ((tid & 63) == 0) wm[tid >> 6] = m;
        __syncthreads();
        if (tid == 0) {
            float mm = fmaxf(fmaxf(wm[0], wm[1]), fmaxf(wm[2], wm[3]));
            atomicMax(smax_key, fkey(mm));
        }
    } else {
        float smax = funkey(*smax_key);
        float epmax = 1.0f / (1.0f + expf(-smax));
        __shared__ unsigned lm[TS][2];
        __shared__ unsigned lmT[TS][2];
        if (tid < 128) { lm[tid >> 1][tid & 1] = 0u; lmT[tid >> 1][tid & 1] = 0u; }
        __syncthreads();
        #pragma unroll
        for (int r = 0; r < 4; ++r) {
            #pragma unroll
            for (int c = 0; c < 4; ++c) {
                int li = ty + 16 * r, lj = tx + 16 * c;
                int gi = ti * TS + li, gj = tj * TS + lj;
                bool bit = false;
                if (gi < gj) {
                    float s = acc[r][c];
                    float ep = 1.0f / (1.0f + expf(-s));
                    float P = ep / epmax;
                    float Pc = fminf(fmaxf(P, 1e-6f), 1.0f - 1e-6f);
                    float uu = u[(size_t)gi * NN + gj];
                    float ucv = fminf(fmaxf(uu, 1e-6f), 1.0f - 1e-6f);
                    bit = Pc > (1.0f - ucv);    // logit(Pc)+logit(uc) > 0
                } else if (gi == gj) {
                    bit = true;                 // self-loop
                }
                if (bit) {
                    atomicOr(&lm[li][lj >> 5], 1u << (lj & 31));
                    atomicOr(&lmT[lj][li >> 5], 1u << (li & 31));
                }
            }
        }
        __syncthreads();
        if (tid < 128) {
            int r = tid >> 1, w = tid & 1;
            unsigned word = lm[r][w];
            if (ti == tj) word |= lmT[r][w];
            mb[(size_t)(ti * TS + r) * 128 + tj * 2 + w] = word;
        } else if (ti != tj) {
            int r = (tid - 128) >> 1, w = tid & 1;
            mb[(size_t)(tj * TS + r) * 128 + ti * 2 + w] = lmT[r][w];
        }
    }
}

// Compact bitmask rows into u16 column-index lists (one wave per row).
// List padded to a multiple of 8 with duplicate (diag) indices: max is
// idempotent, so padding keeps the consumer loop branchless.
__global__ __launch_bounds__(256) void k_bits2idx(const unsigned* __restrict__ mb,
                                                  unsigned short* __restrict__ idx,
                                                  int* __restrict__ rowcnt) {
    int row = blockIdx.x * 4 + (threadIdx.x >> 6);
    int lane = threadIdx.x & 63;
    unsigned w0 = mb[(size_t)row * 128 + lane * 2];
    unsigned w1 = mb[(size_t)row * 128 + lane * 2 + 1];
    int c = __popc(w0) + __popc(w1);
    int inc = c;
    #pragma unroll
    for (int o = 1; o < 64; o <<= 1) {
        int v = __shfl_up(inc, o, 64);
        if (lane >= o) inc += v;
    }
    int total = __shfl(inc, 63, 64);
    int off = inc - c;
    unsigned short* op = idx + (size_t)row * 4096;
    int jb = lane * 64;
    while (w0) { int b = __ffs(w0) - 1; w0 &= w0 - 1; op[off++] = (unsigned short)(jb + b); }
    while (w1) { int b = __ffs(w1) - 1; w1 &= w1 - 1; op[off++] = (unsigned short)(jb + 32 + b); }
    int padded = (total + 7) & ~7;
    if (lane == 63) {
        for (int t = total; t < padded; ++t) op[t] = (unsigned short)row;
    }
    if (lane == 0) rowcnt[row] = padded;
}

// Sparse masked max, D=256: one wave per row; per index one dwordx4 load +
// 4 v_max. Two accumulators break the max dependence chain.
__global__ __launch_bounds__(256, 4) void k_maskmax_s256(const unsigned short* __restrict__ idx,
                                                         const int* __restrict__ rowcnt,
                                                         const float* __restrict__ z,
                                                         float* __restrict__ outp) {
    int row = blockIdx.x * 4 + (threadIdx.x >> 6);
    int d4 = threadIdx.x & 63;
    const float4* zr = (const float4*)z;
    const unsigned short* ip = idx + (size_t)row * 4096;
    int n = rowcnt[row];
    float4 a0 = make_float4(0.f, 0.f, 0.f, 0.f);
    float4 a1 = make_float4(0.f, 0.f, 0.f, 0.f);
    for (int i = 0; i < n; i += 8) {
        uint4 v = *(const uint4*)(ip + i);   // 8 u16 indices, wave-uniform broadcast
        unsigned js[8] = { v.x & 0xffffu, v.x >> 16, v.y & 0xffffu, v.y >> 16,
                           v.z & 0xffffu, v.z >> 16, v.w & 0xffffu, v.w >> 16 };
        #pragma unroll
        for (int t = 0; t < 8; t += 2) {
            float4 z0 = zr[js[t] * 64 + d4];
            float4 z1 = zr[js[t + 1] * 64 + d4];
            a0.x = fmaxf(a0.x, z0.x); a0.y = fmaxf(a0.y, z0.y);
            a0.z = fmaxf(a0.z, z0.z); a0.w = fmaxf(a0.w, z0.w);
            a1.x = fmaxf(a1.x, z1.x); a1.y = fmaxf(a1.y, z1.y);
            a1.z = fmaxf(a1.z, z1.z); a1.w = fmaxf(a1.w, z1.w);
        }
    }
    a0.x = fmaxf(a0.x, a1.x); a0.y = fmaxf(a0.y, a1.y);
    a0.z = fmaxf(a0.z, a1.z); a0.w = fmaxf(a0.w, a1.w);
    ((float4*)outp)[(size_t)row * 64 + d4] = a0;
}

// Sparse masked max, D=128: one wave per row, wave halves process two
// indices per step; halves merged by shfl_xor(32) at the end.
__global__ __launch_bounds__(256, 4) void k_maskmax_s128(const unsigned short* __restrict__ idx,
                                                         const int* __restrict__ rowcnt,
                                                         const float* __restrict__ z,
                                                         float* __restrict__ outp) {
    int row = blockIdx.x * 4 + (threadIdx.x >> 6);
    int lane = threadIdx.x & 63;
    int half = lane >> 5, d4 = lane & 31;
    const float4* zr = (const float4*)z;
    const unsigned short* ip = idx + (size_t)row * 4096;
    int n = rowcnt[row];
    float4 a0 = make_float4(0.f, 0.f, 0.f, 0.f);
    float4 a1 = make_float4(0.f, 0.f, 0.f, 0.f);
    for (int i = 0; i < n; i += 8) {
        uint4 v = *(const uint4*)(ip + i);   // 4 pairs of u16 indices
        unsigned j0 = half ? (v.x >> 16) : (v.x & 0xffffu);
        unsigned j1 = half ? (v.y >> 16) : (v.y & 0xffffu);
        unsigned j2 = half ? (v.z >> 16) : (v.z & 0xffffu);
        unsigned j3 = half ? (v.w >> 16) : (v.w & 0xffffu);
        float4 z0 = zr[j0 * 32 + d4];
        float4 z1 = zr[j1 * 32 + d4];
        float4 z2 = zr[j2 * 32 + d4];
        float4 z3 = zr[j3 * 32 + d4];
        a0.x = fmaxf(a0.x, fmaxf(z0.x, z1.x)); a0.y = fmaxf(a0.y, fmaxf(z0.y, z1.y));
        a0.z = fmaxf(a0.z, fmaxf(z0.z, z1.z)); a0.w = fmaxf(a0.w, fmaxf(z0.w, z1.w));
        a1.x = fmaxf(a1.x, fmaxf(z2.x, z3.x)); a1.y = fmaxf(a1.y, fmaxf(z2.y, z3.y));
        a1.z = fmaxf(a1.z, fmaxf(z2.z, z3.z)); a1.w = fmaxf(a1.w, fmaxf(z2.w, z3.w));
    }
    a0.x = fmaxf(a0.x, a1.x); a0.y = fmaxf(a0.y, a1.y);
    a0.z = fmaxf(a0.z, a1.z); a0.w = fmaxf(a0.w, a1.w);
    a0.x = fmaxf(a0.x, __shfl_xor(a0.x, 32, 64));
    a0.y = fmaxf(a0.y, __shfl_xor(a0.y, 32, 64));
    a0.z = fmaxf(a0.z, __shfl_xor(a0.z, 32, 64));
    a0.w = fmaxf(a0.w, __shfl_xor(a0.w, 32, 64));
    if (!half) ((float4*)outp)[(size_t)row * 32 + d4] = a0;
}

// Dense fallback (used only if ws_size is too small for the index lists).
template<int D, int RT>
__global__ __launch_bounds__(256, 4) void k_maskmax_dense(const unsigned* __restrict__ mb,
                                                          const float* __restrict__ z,
                                                          float* __restrict__ outp) {
    constexpr int D4 = D / 4;
    constexpr int G = 256 / D4;
    constexpr int RPG = RT / G;
    int i0 = blockIdx.x * RT;
    __shared__ unsigned msk[RT][129];
    for (int t = threadIdx.x; t < RT * 128; t += 256)
        msk[t >> 7][t & 127] = mb[(size_t)(i0 + (t >> 7)) * 128 + (t & 127)];
    __syncthreads();
    int d4 = threadIdx.x % D4;
    int g = threadIdx.x / D4;
    const float4* zr = (const float4*)z + d4;
    float4 acc[RPG];
    #pragma unroll
    for (int r = 0; r < RPG; ++r) acc[r] = make_float4(0.f, 0.f, 0.f, 0.f);
    for (int w = 0; w < 128; ++w) {
        unsigned wr[RPG];
        #pragma unroll
        for (int r = 0; r < RPG; ++r) wr[r] = msk[g * RPG + r][w];
        const float4* zp = zr + (size_t)(w * 32) * D4;
        #pragma unroll 8
        for (int jj = 0; jj < 32; jj += 2) {
            float4 z0 = zp[jj * D4];
            float4 z1 = zp[(jj + 1) * D4];
            #pragma unroll
            for (int r = 0; r < RPG; ++r) {
                unsigned m0 = (unsigned)(((int)(wr[r] << (31 - jj))) >> 31);
                unsigned m1 = (unsigned)(((int)(wr[r] << (30 - jj))) >> 31);
                acc[r].x = fmaxf(acc[r].x, fmaxf(__uint_as_float(m0 & __float_as_uint(z0.x)),
                                                 __uint_as_float(m1 & __float_as_uint(z1.x))));
                acc[r].y = fmaxf(acc[r].y, fmaxf(__uint_as_float(m0 & __float_as_uint(z0.y)),
                                                 __uint_as_float(m1 & __float_as_uint(z1.y))));
                acc[r].z = fmaxf(acc[r].z, fmaxf(__uint_as_float(m0 & __float_as_uint(z0.z)),
                                                 __uint_as_float(m1 & __float_as_uint(z1.z))));
                acc[r].w = fmaxf(acc[r].w, fmaxf(__uint_as_float(m0 & __float_as_uint(z0.w)),
                                                 __uint_as_float(m1 & __float_as_uint(z1.w))));
            }
        }
    }
    float4* po = (float4*)outp;
    #pragma unroll
    for (int r = 0; r < RPG; ++r)
        po[(size_t)(i0 + g * RPG + r) * D4 + d4] = acc[r];
}

__global__ void k_relu_l2norm(float* __restrict__ h) {
    int i = blockIdx.x, d = threadIdx.x;   // 128 threads
    float v = fmaxf(h[(size_t)i * 128 + d], 0.0f);
    float ss = v * v;
    #pragma unroll
    for (int o = 1; o < 64; o <<= 1) ss += __shfl_xor(ss, o, 64);
    __shared__ float w2[2];
    if ((d & 63) == 0) w2[d >> 6] = ss;
    __syncthreads();
    float tot = w2[0] + w2[1];
    float denom = fmaxf(sqrtf(tot), 1e-12f);
    h[(size_t)i * 128 + d] = v / denom;
}

__global__ void k_gemm_final(const float* __restrict__ X, const float* __restrict__ W,
                             const float* __restrict__ b1, const float* __restrict__ b2,
                             float* __restrict__ out) {
    int i = blockIdx.x * 2 + (threadIdx.x >> 5);
    int j = threadIdx.x & 31;
    float acc = 0.0f;
    #pragma unroll 8
    for (int k = 0; k < 128; ++k) acc = fmaf(X[(size_t)i * 128 + k], W[k * 32 + j], acc);
    out[(size_t)i * 32 + j] = acc + b1[j] + b2[j];
}

extern "C" void kernel_launch(void* const* d_in, const int* in_sizes, int n_in,
                              void* d_out, int out_size, void* d_ws, size_t ws_size,
                              hipStream_t stream) {
    // input order per setup_inputs(): adj unused (ALPHA == 1.0 -> coefficient 0)
    const float* inputs = (const float*)d_in[1];
    const float* feat   = (const float*)d_in[2];
    const float* u      = (const float*)d_in[3];
    const int*   src    = (const int*)d_in[4];
    const int*   dst    = (const int*)d_in[5];
    const float* gc0W = (const float*)d_in[6],  *gc0b = (const float*)d_in[7];
    const float* gc1W = (const float*)d_in[8],  *gc1b = (const float*)d_in[9];
    const float* p0W  = (const float*)d_in[10], *p0b  = (const float*)d_in[11];
    const float* l0W  = (const float*)d_in[12], *l0b  = (const float*)d_in[13];
    const float* b0   = (const float*)d_in[14];
    const float* p1W  = (const float*)d_in[15], *p1b  = (const float*)d_in[16];
    const float* l1W  = (const float*)d_in[17], *l1b  = (const float*)d_in[18];
    const float* b1   = (const float*)d_in[19];
    const float* p2W  = (const float*)d_in[20], *p2b  = (const float*)d_in[21];
    const float* l2W  = (const float*)d_in[22], *l2b  = (const float*)d_in[23];
    const float* b2   = (const float*)d_in[24];
    float* out = (float*)d_out;

    const size_t MB = 1048576;
    char* w = (char*)d_ws;
    int*      cnt_src  = (int*)(w + 0);
    int*      cnt_dst  = (int*)(w + 16384);
    float*    on       = (float*)(w + 32768);
    float*    inn      = (float*)(w + 49152);
    unsigned* smax_key = (unsigned*)(w + 65536);
    int*      rowcnt   = (int*)(w + 81920);
    char*     big      = w + 98304;
    float*    tmp      = (float*)(big);                // 2 MB
    float*    agg      = (float*)(big + 2 * MB);       // 2 MB
    float*    hbuf     = (float*)(big + 4 * MB);       // 2 MB
    unsigned* mb       = (unsigned*)(big + 6 * MB);    // 2 MB
    float*    z        = (float*)(big + 8 * MB);       // 4 MB
    float*    pm       = (float*)(big + 12 * MB);      // 4 MB
    float*    hs       = (float*)(big + 16 * MB);      // 2 MB
    unsigned short* idx = (unsigned short*)(big + 18 * MB);  // 32 MB
    const size_t NEEDED_SPARSE = 98304 + 50 * MB;
    bool use_sparse = ws_size >= NEEDED_SPARSE;

    hipMemsetAsync(w, 0, 98304, stream);
    k_count<<<EE / 256, 256, 0, stream>>>(src, dst, cnt_src, cnt_dst);
    k_norm<<<NN / 256, 256, 0, stream>>>(cnt_src, cnt_dst, on, inn);

    // --- GCN layer 0 ---
    k_gemm_scale<256, 128><<<NN, 128, 0, stream>>>(inputs, gc0W, on, tmp);
    hipMemsetAsync(agg, 0, (size_t)NN * 128 * 4, stream);
    k_scatter<<<EE, 128, 0, stream>>>(tmp, src, dst, agg);
    k_gcn_out<<<NN * 128 / 256, 256, 0, stream>>>(agg, inn, gc0b, hbuf, 1);

    // --- GCN layer 1 ---
    k_gemm_scale<128, 128><<<NN, 128, 0, stream>>>(hbuf, gc1W, on, tmp);
    hipMemsetAsync(agg, 0, (size_t)NN * 128 * 4, stream);
    k_scatter<<<EE, 128, 0, stream>>>(tmp, src, dst, agg);
    k_gcn_out<<<NN * 128 / 256, 256, 0, stream>>>(agg, inn, gc1b, hbuf, 0);

    // --- decode: max(S), mask bits, index lists ---
    dim3 tg(64, 64);
    k_stile<0><<<tg, 256, 0, stream>>>(hbuf, nullptr, smax_key, nullptr);
    k_stile<1><<<tg, 256, 0, stream>>>(hbuf, u, smax_key, mb);
    if (use_sparse)
        k_bits2idx<<<NN / 4, 256, 0, stream>>>(mb, idx, rowcnt);

    // --- GraphSAGE layer 0 (256 -> 128) ---
    k_gemm_ab<256, 256><<<NN, 256, 0, stream>>>(feat, p0W, p0b, nullptr, z, 1);
    if (use_sparse)
        k_maskmax_s256<<<NN / 4, 256, 0, stream>>>(idx, rowcnt, z, pm);
    else
        k_maskmax_dense<256, 8><<<NN / 8, 256, 0, stream>>>(mb, z, pm);
    k_gemm_ab<256, 128><<<NN, 128, 0, stream>>>(pm, l0W, l0b, b0, hs, 0);
    k_relu_l2norm<<<NN, 128, 0, stream>>>(hs);

    // --- GraphSAGE layer 1 (128 -> 128) ---
    k_gemm_ab<128, 128><<<NN, 128, 0, stream>>>(hs, p1W, p1b, nullptr, z, 1);
    if (use_sparse)
        k_maskmax_s128<<<NN / 4, 256, 0, stream>>>(idx, rowcnt, z, pm);
    else
        k_maskmax_dense<128, 8><<<NN / 8, 256, 0, stream>>>(mb, z, pm);
    k_gemm_ab<128, 128><<<NN, 128, 0, stream>>>(pm, l1W, l1b, b1, tmp, 0);
    k_relu_l2norm<<<NN, 128, 0, stream>>>(tmp);

    // --- GraphSAGE layer 2 (128 -> 32) ---
    k_gemm_ab<128, 128><<<NN, 128, 0, stream>>>(tmp, p2W, p2b, nullptr, z, 1);
    if (use_sparse)
        k_maskmax_s128<<<NN / 4, 256, 0, stream>>>(idx, rowcnt, z, pm);
    else
        k_maskmax_dense<128, 8><<<NN / 8, 256, 0, stream>>>(mb, z, pm);
    k_gemm_final<<<NN / 2, 64, 0, stream>>>(pm, l2W, l2b, b2, out);
}

// Round 6
// 1455.585 us; speedup vs baseline: 3.5014x; 1.0067x over previous
//
#include <hip/hip_runtime.h>
#include <cstdint>
#include <cstddef>

#define NN 4096
#define EE 131072
#define TS 64

__device__ __forceinline__ unsigned fkey(float f) {
    unsigned u = __float_as_uint(f);
    return (u & 0x80000000u) ? ~u : (u | 0x80000000u);
}
__device__ __forceinline__ float funkey(unsigned k) {
    unsigned u = (k & 0x80000000u) ? (k & 0x7fffffffu) : ~k;
    return __uint_as_float(u);
}

__global__ void k_count(const int* __restrict__ src, const int* __restrict__ dst,
                        int* __restrict__ cs, int* __restrict__ cd) {
    int e = blockIdx.x * 256 + threadIdx.x;
    if (e < EE) {
        atomicAdd(&cs[src[e]], 1);
        atomicAdd(&cd[dst[e]], 1);
    }
}

__global__ void k_norm(const int* __restrict__ cs, const int* __restrict__ cd,
                       float* __restrict__ on, float* __restrict__ inn) {
    int i = blockIdx.x * 256 + threadIdx.x;
    if (i < NN) {
        int a = cs[i] > 1 ? cs[i] : 1;
        int b = cd[i] > 1 ? cd[i] : 1;
        on[i]  = 1.0f / sqrtf((float)a);
        inn[i] = 1.0f / sqrtf((float)b);
    }
}

template<int K, int ND>
__global__ void k_gemm_scale(const float* __restrict__ X, const float* __restrict__ W,
                             const float* __restrict__ scale, float* __restrict__ out) {
    __shared__ float xr[K];
    int i = blockIdx.x;
    for (int k = threadIdx.x; k < K; k += ND) xr[k] = X[(size_t)i * K + k];
    __syncthreads();
    int j = threadIdx.x;
    float acc = 0.0f;
    #pragma unroll 8
    for (int k = 0; k < K; ++k) acc = fmaf(xr[k], W[k * ND + j], acc);
    out[(size_t)i * ND + j] = acc * scale[i];
}

// out[i][j] = X@W + b1[j] (+ b2[j]) (optional relu). X2: split-partial merge.
template<int K, int ND>
__global__ void k_gemm_ab(const float* __restrict__ X, const float* __restrict__ X2,
                          const float* __restrict__ W,
                          const float* __restrict__ b1, const float* __restrict__ b2,
                          float* __restrict__ out, int do_relu) {
    __shared__ float xr[K];
    int i = blockIdx.x;
    for (int k = threadIdx.x; k < K; k += ND) {
        float v = X[(size_t)i * K + k];
        if (X2) v = fmaxf(v, X2[(size_t)i * K + k]);
        xr[k] = v;
    }
    __syncthreads();
    int j = threadIdx.x;
    float acc = 0.0f;
    #pragma unroll 8
    for (int k = 0; k < K; ++k) acc = fmaf(xr[k], W[k * ND + j], acc);
    acc += b1[j];
    if (b2) acc += b2[j];
    if (do_relu) acc = fmaxf(acc, 0.0f);
    out[(size_t)i * ND + j] = acc;
}

__global__ void k_scatter(const float* __restrict__ t, const int* __restrict__ src,
                          const int* __restrict__ dst, float* __restrict__ agg) {
    int e = blockIdx.x;
    int j = threadIdx.x;   // 128 threads
    int s = src[e], d = dst[e];
    atomicAdd(&agg[(size_t)d * 128 + j], t[(size_t)s * 128 + j]);
}

__global__ void k_gcn_out(const float* __restrict__ agg, const float* __restrict__ inn,
                          const float* __restrict__ b, float* __restrict__ out, int do_relu) {
    int idx = blockIdx.x * 256 + threadIdx.x;
    int i = idx >> 7, j = idx & 127;
    float v = agg[idx] * inn[i] + b[j];
    if (do_relu) v = fmaxf(v, 0.0f);
    out[idx] = v;
}

// ---- S = h h^T tile compute (shared macro body via template) ----
// Thread (tx,ty) owns rows {ty+16r}, cols {tx+16c} of a 64x64 tile.
template<int MODE>  // 0: max-only; 1: recompute + bit-emit (fallback path)
__global__ __launch_bounds__(256, 4) void k_stile(const float* __restrict__ h,
                                                  const float* __restrict__ u,
                                                  unsigned* __restrict__ smax_key,
                                                  unsigned* __restrict__ mb) {
    int ti = blockIdx.y, tj = blockIdx.x;
    if (tj < ti) return;
    __shared__ float Ah[TS][68];
    __shared__ float Bh[TS][68];
    int tid = threadIdx.x;
    int tx = tid & 15, ty = tid >> 4;
    const float* ha = h + (size_t)ti * TS * 128;
    const float* hb = h + (size_t)tj * TS * 128;

    float acc[4][4];
    #pragma unroll
    for (int r = 0; r < 4; ++r)
        #pragma unroll
        for (int c = 0; c < 4; ++c) acc[r][c] = 0.0f;

    for (int half = 0; half < 2; ++half) {
        __syncthreads();
        #pragma unroll
        for (int t = 0; t < 4; ++t) {
            int f = tid + t * 256;
            int row = f >> 4, kk = f & 15;
            *(float4*)&Ah[row][kk * 4] = *(const float4*)(ha + (size_t)row * 128 + half * 64 + kk * 4);
            *(float4*)&Bh[row][kk * 4] = *(const float4*)(hb + (size_t)row * 128 + half * 64 + kk * 4);
        }
        __syncthreads();
        #pragma unroll 2
        for (int k4 = 0; k4 < 16; ++k4) {
            float4 a[4], b[4];
            #pragma unroll
            for (int r = 0; r < 4; ++r) a[r] = *(const float4*)&Ah[ty + 16 * r][k4 * 4];
            #pragma unroll
            for (int c = 0; c < 4; ++c) b[c] = *(const float4*)&Bh[tx + 16 * c][k4 * 4];
            #pragma unroll
            for (int r = 0; r < 4; ++r)
                #pragma unroll
                for (int c = 0; c < 4; ++c) {
                    acc[r][c] = fmaf(a[r].x, b[c].x, acc[r][c]);
                    acc[r][c] = fmaf(a[r].y, b[c].y, acc[r][c]);
                    acc[r][c] = fmaf(a[r].z, b[c].z, acc[r][c]);
                    acc[r][c] = fmaf(a[r].w, b[c].w, acc[r][c]);
                }
        }
    }

    if constexpr (MODE == 0) {
        float m = -3.4e38f;
        #pragma unroll
        for (int r = 0; r < 4; ++r)
            #pragma unroll
            for (int c = 0; c < 4; ++c) m = fmaxf(m, acc[r][c]);
        #pragma unroll
        for (int o = 1; o < 64; o <<= 1) m = fmaxf(m, __shfl_xor(m, o, 64));
        __shared__ float wm[4];
        if ((tid & 63) == 0) wm[tid >> 6] = m;
        __syncthreads();
        if (tid == 0) {
            float mm = fmaxf(fmaxf(wm[0], wm[1]), fmaxf(wm[2], wm[3]));
            atomicMax(smax_key, fkey(mm));
        }
    } else {
        float smax = funkey(*smax_key);
        float epmax = 1.0f / (1.0f + expf(-smax));
        __shared__ unsigned lm[TS][2];
        __shared__ unsigned lmT[TS][2];
        if (tid < 128) { lm[tid >> 1][tid & 1] = 0u; lmT[tid >> 1][tid & 1] = 0u; }
        __syncthreads();
        #pragma unroll
        for (int r = 0; r < 4; ++r) {
            #pragma unroll
            for (int c = 0; c < 4; ++c) {
                int li = ty + 16 * r, lj = tx + 16 * c;
                int gi = ti * TS + li, gj = tj * TS + lj;
                bool bit = false;
                if (gi < gj) {
                    float ep = 1.0f / (1.0f + expf(-acc[r][c]));
                    float P = ep / epmax;
                    float Pc = fminf(fmaxf(P, 1e-6f), 1.0f - 1e-6f);
                    float uu = u[(size_t)gi * NN + gj];
                    float ucv = fminf(fmaxf(uu, 1e-6f), 1.0f - 1e-6f);
                    bit = Pc > (1.0f - ucv);
                } else if (gi == gj) {
                    bit = true;
                }
                if (bit) {
                    atomicOr(&lm[li][lj >> 5], 1u << (lj & 31));
                    atomicOr(&lmT[lj][li >> 5], 1u << (li & 31));
                }
            }
        }
        __syncthreads();
        if (tid < 128) {
            int r = tid >> 1, wq = tid & 1;
            unsigned word = lm[r][wq];
            if (ti == tj) word |= lmT[r][wq];
            mb[(size_t)(ti * TS + r) * 128 + tj * 2 + wq] = word;
        } else if (ti != tj) {
            int r = (tid - 128) >> 1, wq = tid & 1;
            mb[(size_t)(tj * TS + r) * 128 + ti * 2 + wq] = lmT[r][wq];
        }
    }
}

// Pass 1 (S-store path): compute tile, store S to ws, fold into global max.
__global__ __launch_bounds__(256, 4) void k_stile_store(const float* __restrict__ h,
                                                        float* __restrict__ S,
                                                        unsigned* __restrict__ smax_key) {
    int ti = blockIdx.y, tj = blockIdx.x;
    if (tj < ti) return;
    __shared__ float Ah[TS][68];
    __shared__ float Bh[TS][68];
    int tid = threadIdx.x;
    int tx = tid & 15, ty = tid >> 4;
    const float* ha = h + (size_t)ti * TS * 128;
    const float* hb = h + (size_t)tj * TS * 128;

    float acc[4][4];
    #pragma unroll
    for (int r = 0; r < 4; ++r)
        #pragma unroll
        for (int c = 0; c < 4; ++c) acc[r][c] = 0.0f;

    for (int half = 0; half < 2; ++half) {
        __syncthreads();
        #pragma unroll
        for (int t = 0; t < 4; ++t) {
            int f = tid + t * 256;
            int row = f >> 4, kk = f & 15;
            *(float4*)&Ah[row][kk * 4] = *(const float4*)(ha + (size_t)row * 128 + half * 64 + kk * 4);
            *(float4*)&Bh[row][kk * 4] = *(const float4*)(hb + (size_t)row * 128 + half * 64 + kk * 4);
        }
        __syncthreads();
        #pragma unroll 2
        for (int k4 = 0; k4 < 16; ++k4) {
            float4 a[4], b[4];
            #pragma unroll
            for (int r = 0; r < 4; ++r) a[r] = *(const float4*)&Ah[ty + 16 * r][k4 * 4];
            #pragma unroll
            for (int c = 0; c < 4; ++c) b[c] = *(const float4*)&Bh[tx + 16 * c][k4 * 4];
            #pragma unroll
            for (int r = 0; r < 4; ++r)
                #pragma unroll
                for (int c = 0; c < 4; ++c) {
                    acc[r][c] = fmaf(a[r].x, b[c].x, acc[r][c]);
                    acc[r][c] = fmaf(a[r].y, b[c].y, acc[r][c]);
                    acc[r][c] = fmaf(a[r].z, b[c].z, acc[r][c]);
                    acc[r][c] = fmaf(a[r].w, b[c].w, acc[r][c]);
                }
        }
    }

    float* sp = S + (size_t)(ti * 64 + tj) * 4096;
    #pragma unroll
    for (int r = 0; r < 4; ++r)
        #pragma unroll
        for (int c = 0; c < 4; ++c)
            sp[(ty + 16 * r) * 64 + tx + 16 * c] = acc[r][c];

    float m = -3.4e38f;
    #pragma unroll
    for (int r = 0; r < 4; ++r)
        #pragma unroll
        for (int c = 0; c < 4; ++c) m = fmaxf(m, acc[r][c]);
    #pragma unroll
    for (int o = 1; o < 64; o <<= 1) m = fmaxf(m, __shfl_xor(m, o, 64));
    __shared__ float wm[4];
    if ((tid & 63) == 0) wm[tid >> 6] = m;
    __syncthreads();
    if (tid == 0)
        atomicMax(smax_key, fkey(fmaxf(fmaxf(wm[0], wm[1]), fmaxf(wm[2], wm[3]))));
}

// Pass 2 (S-store path): read stored S, emit mask bits. Cheap (no GEMM).
__global__ __launch_bounds__(256, 4) void k_bitemit(const float* __restrict__ S,
                                                    const float* __restrict__ u,
                                                    const unsigned* __restrict__ smax_key,
                                                    unsigned* __restrict__ mb) {
    int ti = blockIdx.y, tj = blockIdx.x;
    if (tj < ti) return;
    int tid = threadIdx.x;
    int tx = tid & 15, ty = tid >> 4;
    float smax = funkey(*smax_key);
    float epmax = 1.0f / (1.0f + expf(-smax));
    __shared__ unsigned lm[TS][2];
    __shared__ unsigned lmT[TS][2];
    if (tid < 128) { lm[tid >> 1][tid & 1] = 0u; lmT[tid >> 1][tid & 1] = 0u; }
    __syncthreads();
    const float* sp = S + (size_t)(ti * 64 + tj) * 4096;
    #pragma unroll
    for (int r = 0; r < 4; ++r) {
        #pragma unroll
        for (int c = 0; c < 4; ++c) {
            int li = ty + 16 * r, lj = tx + 16 * c;
            int gi = ti * TS + li, gj = tj * TS + lj;
            bool bit = false;
            if (gi < gj) {
                float ep = 1.0f / (1.0f + expf(-sp[li * 64 + lj]));
                float P = ep / epmax;
                float Pc = fminf(fmaxf(P, 1e-6f), 1.0f - 1e-6f);
                float uu = u[(size_t)gi * NN + gj];
                float ucv = fminf(fmaxf(uu, 1e-6f), 1.0f - 1e-6f);
                bit = Pc > (1.0f - ucv);
            } else if (gi == gj) {
                bit = true;
            }
            if (bit) {
                atomicOr(&lm[li][lj >> 5], 1u << (lj & 31));
                atomicOr(&lmT[lj][li >> 5], 1u << (li & 31));
            }
        }
    }
    __syncthreads();
    if (tid < 128) {
        int r = tid >> 1, wq = tid & 1;
        unsigned word = lm[r][wq];
        if (ti == tj) word |= lmT[r][wq];
        mb[(size_t)(ti * TS + r) * 128 + tj * 2 + wq] = word;
    } else if (ti != tj) {
        int r = (tid - 128) >> 1, wq = tid & 1;
        mb[(size_t)(tj * TS + r) * 128 + ti * 2 + wq] = lmT[r][wq];
    }
}

// Bitmask -> per-(row, column-split) u16 index lists. One wave per task.
// Lists padded to a multiple of 16 with a present index (max idempotent).
__global__ __launch_bounds__(256) void k_bits2idx2(const unsigned* __restrict__ mb,
                                                   unsigned short* __restrict__ idx,
                                                   int* __restrict__ rowcnt) {
    int gwid = blockIdx.x * 4 + (threadIdx.x >> 6);   // [0, NN*2)
    int row = gwid >> 1, split = gwid & 1;
    int lane = threadIdx.x & 63;
    unsigned w0 = mb[(size_t)row * 128 + split * 64 + lane];
    int c = __popc(w0);
    unsigned long long act = __ballot(w0 != 0);
    int inc = c;
    #pragma unroll
    for (int o = 1; o < 64; o <<= 1) {
        int v = __shfl_up(inc, o, 64);
        if (lane >= o) inc += v;
    }
    int total = __shfl(inc, 63, 64);
    int off = inc - c;
    unsigned short* op = idx + (size_t)gwid * 2048;
    int jb = split * 2048 + lane * 32;
    unsigned wtmp = w0;
    while (wtmp) { int b = __ffs(wtmp) - 1; wtmp &= wtmp - 1; op[off++] = (unsigned short)(jb + b); }
    int fl = act ? (__ffsll(act) - 1) : 0;
    unsigned fw = __shfl(w0, fl, 64);
    int padv = split * 2048 + fl * 32 + (fw ? (__ffs(fw) - 1) : 0);
    int padded = (total + 15) & ~15;
    if (lane == 63) {
        for (int t = total; t < padded; ++t) op[t] = (unsigned short)padv;
        rowcnt[gwid] = padded;
    }
}

// Sparse masked max, D=256: one wave per (row,split); 16 gathers in flight.
__global__ __launch_bounds__(256, 4) void k_maskmax_s256(const unsigned short* __restrict__ idx,
                                                         const int* __restrict__ rowcnt,
                                                         const float* __restrict__ z,
                                                         float* __restrict__ outp) {
    int gwid = blockIdx.x * 4 + (threadIdx.x >> 6);
    int row = gwid >> 1, split = gwid & 1;
    int d4 = threadIdx.x & 63;
    const float4* zr = (const float4*)z;
    const unsigned short* ip = idx + (size_t)gwid * 2048;
    int n = rowcnt[gwid];
    float4 a0 = make_float4(0.f, 0.f, 0.f, 0.f), a1 = a0, a2 = a0, a3 = a0;
    for (int i = 0; i < n; i += 16) {
        uint4 v0 = *(const uint4*)(ip + i);
        uint4 v1 = *(const uint4*)(ip + i + 8);
        unsigned js[16] = { v0.x & 0xffffu, v0.x >> 16, v0.y & 0xffffu, v0.y >> 16,
                            v0.z & 0xffffu, v0.z >> 16, v0.w & 0xffffu, v0.w >> 16,
                            v1.x & 0xffffu, v1.x >> 16, v1.y & 0xffffu, v1.y >> 16,
                            v1.z & 0xffffu, v1.z >> 16, v1.w & 0xffffu, v1.w >> 16 };
        float4 zv[16];
        #pragma unroll
        for (int t = 0; t < 16; ++t) zv[t] = zr[(size_t)js[t] * 64 + d4];
        float4* as[4] = { &a0, &a1, &a2, &a3 };
        #pragma unroll
        for (int q = 0; q < 4; ++q) {
            float4& a = *as[q];
            const float4& p0 = zv[q * 4], &p1 = zv[q * 4 + 1], &p2 = zv[q * 4 + 2], &p3 = zv[q * 4 + 3];
            a.x = fmaxf(a.x, fmaxf(p0.x, p1.x)); a.x = fmaxf(a.x, fmaxf(p2.x, p3.x));
            a.y = fmaxf(a.y, fmaxf(p0.y, p1.y)); a.y = fmaxf(a.y, fmaxf(p2.y, p3.y));
            a.z = fmaxf(a.z, fmaxf(p0.z, p1.z)); a.z = fmaxf(a.z, fmaxf(p2.z, p3.z));
            a.w = fmaxf(a.w, fmaxf(p0.w, p1.w)); a.w = fmaxf(a.w, fmaxf(p2.w, p3.w));
        }
    }
    a0.x = fmaxf(fmaxf(a0.x, a1.x), fmaxf(a2.x, a3.x));
    a0.y = fmaxf(fmaxf(a0.y, a1.y), fmaxf(a2.y, a3.y));
    a0.z = fmaxf(fmaxf(a0.z, a1.z), fmaxf(a2.z, a3.z));
    a0.w = fmaxf(fmaxf(a0.w, a1.w), fmaxf(a2.w, a3.w));
    ((float4*)outp)[((size_t)split * NN + row) * 64 + d4] = a0;
}

// Sparse masked max, D=128: wave halves each gather 8 rows/iter; merged by shfl.
__global__ __launch_bounds__(256, 4) void k_maskmax_s128(const unsigned short* __restrict__ idx,
                                                         const int* __restrict__ rowcnt,
                                                         const float* __restrict__ z,
                                                         float* __restrict__ outp) {
    int gwid = blockIdx.x * 4 + (threadIdx.x >> 6);
    int row = gwid >> 1, split = gwid & 1;
    int lane = threadIdx.x & 63;
    int half = lane >> 5, d4 = lane & 31;
    const float4* zr = (const float4*)z;
    const unsigned short* ip = idx + (size_t)gwid * 2048;
    int n = rowcnt[gwid];
    float4 a0 = make_float4(0.f, 0.f, 0.f, 0.f), a1 = a0;
    for (int i = 0; i < n; i += 16) {
        uint4 v0 = *(const uint4*)(ip + i);
        uint4 v1 = *(const uint4*)(ip + i + 8);
        unsigned j[8];
        j[0] = half ? (v0.x >> 16) : (v0.x & 0xffffu);
        j[1] = half ? (v0.y >> 16) : (v0.y & 0xffffu);
        j[2] = half ? (v0.z >> 16) : (v0.z & 0xffffu);
        j[3] = half ? (v0.w >> 16) : (v0.w & 0xffffu);
        j[4] = half ? (v1.x >> 16) : (v1.x & 0xffffu);
        j[5] = half ? (v1.y >> 16) : (v1.y & 0xffffu);
        j[6] = half ? (v1.z >> 16) : (v1.z & 0xffffu);
        j[7] = half ? (v1.w >> 16) : (v1.w & 0xffffu);
        float4 zv[8];
        #pragma unroll
        for (int t = 0; t < 8; ++t) zv[t] = zr[(size_t)j[t] * 32 + d4];
        a0.x = fmaxf(a0.x, fmaxf(zv[0].x, zv[1].x)); a0.x = fmaxf(a0.x, fmaxf(zv[2].x, zv[3].x));
        a0.y = fmaxf(a0.y, fmaxf(zv[0].y, zv[1].y)); a0.y = fmaxf(a0.y, fmaxf(zv[2].y, zv[3].y));
        a0.z = fmaxf(a0.z, fmaxf(zv[0].z, zv[1].z)); a0.z = fmaxf(a0.z, fmaxf(zv[2].z, zv[3].z));
        a0.w = fmaxf(a0.w, fmaxf(zv[0].w, zv[1].w)); a0.w = fmaxf(a0.w, fmaxf(zv[2].w, zv[3].w));
        a1.x = fmaxf(a1.x, fmaxf(zv[4].x, zv[5].x)); a1.x = fmaxf(a1.x, fmaxf(zv[6].x, zv[7].x));
        a1.y = fmaxf(a1.y, fmaxf(zv[4].y, zv[5].y)); a1.y = fmaxf(a1.y, fmaxf(zv[6].y, zv[7].y));
        a1.z = fmaxf(a1.z, fmaxf(zv[4].z, zv[5].z)); a1.z = fmaxf(a1.z, fmaxf(zv[6].z, zv[7].z));
        a1.w = fmaxf(a1.w, fmaxf(zv[4].w, zv[5].w)); a1.w = fmaxf(a1.w, fmaxf(zv[6].w, zv[7].w));
    }
    a0.x = fmaxf(a0.x, a1.x); a0.y = fmaxf(a0.y, a1.y);
    a0.z = fmaxf(a0.z, a1.z); a0.w = fmaxf(a0.w, a1.w);
    a0.x = fmaxf(a0.x, __shfl_xor(a0.x, 32, 64));
    a0.y = fmaxf(a0.y, __shfl_xor(a0.y, 32, 64));
    a0.z = fmaxf(a0.z, __shfl_xor(a0.z, 32, 64));
    a0.w = fmaxf(a0.w, __shfl_xor(a0.w, 32, 64));
    if (!half) ((float4*)outp)[((size_t)split * NN + row) * 32 + d4] = a0;
}

// Dense fallback (only if ws too small for index lists).
template<int D, int RT>
__global__ __launch_bounds__(256, 4) void k_maskmax_dense(const unsigned* __restrict__ mb,
                                                          const float* __restrict__ z,
                                                          float* __restrict__ outp) {
    constexpr int D4 = D / 4;
    constexpr int G = 256 / D4;
    constexpr int RPG = RT / G;
    int i0 = blockIdx.x * RT;
    __shared__ unsigned msk[RT][129];
    for (int t = threadIdx.x; t < RT * 128; t += 256)
        msk[t >> 7][t & 127] = mb[(size_t)(i0 + (t >> 7)) * 128 + (t & 127)];
    __syncthreads();
    int d4 = threadIdx.x % D4;
    int g = threadIdx.x / D4;
    const float4* zr = (const float4*)z + d4;
    float4 acc[RPG];
    #pragma unroll
    for (int r = 0; r < RPG; ++r) acc[r] = make_float4(0.f, 0.f, 0.f, 0.f);
    for (int w = 0; w < 128; ++w) {
        unsigned wr[RPG];
        #pragma unroll
        for (int r = 0; r < RPG; ++r) wr[r] = msk[g * RPG + r][w];
        const float4* zp = zr + (size_t)(w * 32) * D4;
        #pragma unroll 8
        for (int jj = 0; jj < 32; jj += 2) {
            float4 z0 = zp[jj * D4];
            float4 z1 = zp[(jj + 1) * D4];
            #pragma unroll
            for (int r = 0; r < RPG; ++r) {
                unsigned m0 = (unsigned)(((int)(wr[r] << (31 - jj))) >> 31);
                unsigned m1 = (unsigned)(((int)(wr[r] << (30 - jj))) >> 31);
                acc[r].x = fmaxf(acc[r].x, fmaxf(__uint_as_float(m0 & __float_as_uint(z0.x)),
                                                 __uint_as_float(m1 & __float_as_uint(z1.x))));
                acc[r].y = fmaxf(acc[r].y, fmaxf(__uint_as_float(m0 & __float_as_uint(z0.y)),
                                                 __uint_as_float(m1 & __float_as_uint(z1.y))));
                acc[r].z = fmaxf(acc[r].z, fmaxf(__uint_as_float(m0 & __float_as_uint(z0.z)),
                                                 __uint_as_float(m1 & __float_as_uint(z1.z))));
                acc[r].w = fmaxf(acc[r].w, fmaxf(__uint_as_float(m0 & __float_as_uint(z0.w)),
                                                 __uint_as_float(m1 & __float_as_uint(z1.w))));
            }
        }
    }
    float4* po = (float4*)outp;
    #pragma unroll
    for (int r = 0; r < RPG; ++r)
        po[(size_t)(i0 + g * RPG + r) * D4 + d4] = acc[r];
}

__global__ void k_relu_l2norm(float* __restrict__ h) {
    int i = blockIdx.x, d = threadIdx.x;
    float v = fmaxf(h[(size_t)i * 128 + d], 0.0f);
    float ss = v * v;
    #pragma unroll
    for (int o = 1; o < 64; o <<= 1) ss += __shfl_xor(ss, o, 64);
    __shared__ float w2[2];
    if ((d & 63) == 0) w2[d >> 6] = ss;
    __syncthreads();
    float tot = w2[0] + w2[1];
    float denom = fmaxf(sqrtf(tot), 1e-12f);
    h[(size_t)i * 128 + d] = v / denom;
}

__global__ void k_gemm_final(const float* __restrict__ X, const float* __restrict__ X2,
                             const float* __restrict__ W,
                             const float* __restrict__ b1, const float* __restrict__ b2,
                             float* __restrict__ out) {
    int i = blockIdx.x * 2 + (threadIdx.x >> 5);
    int j = threadIdx.x & 31;
    float acc = 0.0f;
    #pragma unroll 8
    for (int k = 0; k < 128; ++k) {
        float v = X[(size_t)i * 128 + k];
        if (X2) v = fmaxf(v, X2[(size_t)i * 128 + k]);
        acc = fmaf(v, W[k * 32 + j], acc);
    }
    out[(size_t)i * 32 + j] = acc + b1[j] + b2[j];
}

extern "C" void kernel_launch(void* const* d_in, const int* in_sizes, int n_in,
                              void* d_out, int out_size, void* d_ws, size_t ws_size,
                              hipStream_t stream) {
    const float* inputs = (const float*)d_in[1];
    const float* feat   = (const float*)d_in[2];
    const float* u      = (const float*)d_in[3];
    const int*   src    = (const int*)d_in[4];
    const int*   dst    = (const int*)d_in[5];
    const float* gc0W = (const float*)d_in[6],  *gc0b = (const float*)d_in[7];
    const float* gc1W = (const float*)d_in[8],  *gc1b = (const float*)d_in[9];
    const float* p0W  = (const float*)d_in[10], *p0b  = (const float*)d_in[11];
    const float* l0W  = (const float*)d_in[12], *l0b  = (const float*)d_in[13];
    const float* b0   = (const float*)d_in[14];
    const float* p1W  = (const float*)d_in[15], *p1b  = (const float*)d_in[16];
    const float* l1W  = (const float*)d_in[17], *l1b  = (const float*)d_in[18];
    const float* b1   = (const float*)d_in[19];
    const float* p2W  = (const float*)d_in[20], *p2b  = (const float*)d_in[21];
    const float* l2W  = (const float*)d_in[22], *l2b  = (const float*)d_in[23];
    const float* b2   = (const float*)d_in[24];
    float* out = (float*)d_out;

    const size_t MB = 1048576;
    char* w = (char*)d_ws;
    int*      cnt_src  = (int*)(w + 0);            // 16 KB
    int*      cnt_dst  = (int*)(w + 16384);        // 16 KB
    float*    on       = (float*)(w + 32768);      // 16 KB
    float*    inn      = (float*)(w + 49152);      // 16 KB
    unsigned* smax_key = (unsigned*)(w + 65536);   // 16 KB pad
    int*      rowcnt   = (int*)(w + 81920);        // 32 KB (8192 tasks)
    char*     big      = w + 131072;
    float*    tmp      = (float*)(big);            // 2 MB
    float*    agg      = (float*)(big + 2 * MB);   // 2 MB
    float*    hbuf     = (float*)(big + 4 * MB);   // 2 MB
    unsigned* mb       = (unsigned*)(big + 6 * MB);// 2 MB
    float*    z        = (float*)(big + 8 * MB);   // 4 MB
    float*    pm       = (float*)(big + 12 * MB);  // 8 MB (2 split partials)
    float*    hs       = (float*)(big + 20 * MB);  // 2 MB
    unsigned short* idx = (unsigned short*)(big + 22 * MB);  // 32 MB
    float*    Sbuf     = (float*)(big + 54 * MB);  // 64 MB
    bool use_sparse = ws_size >= 131072 + 54 * MB;
    bool use_sstore = ws_size >= 131072 + 118 * MB;

    hipMemsetAsync(w, 0, 131072, stream);
    k_count<<<EE / 256, 256, 0, stream>>>(src, dst, cnt_src, cnt_dst);
    k_norm<<<NN / 256, 256, 0, stream>>>(cnt_src, cnt_dst, on, inn);

    // --- GCN layer 0 ---
    k_gemm_scale<256, 128><<<NN, 128, 0, stream>>>(inputs, gc0W, on, tmp);
    hipMemsetAsync(agg, 0, (size_t)NN * 128 * 4, stream);
    k_scatter<<<EE, 128, 0, stream>>>(tmp, src, dst, agg);
    k_gcn_out<<<NN * 128 / 256, 256, 0, stream>>>(agg, inn, gc0b, hbuf, 1);

    // --- GCN layer 1 ---
    k_gemm_scale<128, 128><<<NN, 128, 0, stream>>>(hbuf, gc1W, on, tmp);
    hipMemsetAsync(agg, 0, (size_t)NN * 128 * 4, stream);
    k_scatter<<<EE, 128, 0, stream>>>(tmp, src, dst, agg);
    k_gcn_out<<<NN * 128 / 256, 256, 0, stream>>>(agg, inn, gc1b, hbuf, 0);

    // --- decode: S max + mask bits (+ index lists) ---
    dim3 tg(64, 64);
    if (use_sstore) {
        k_stile_store<<<tg, 256, 0, stream>>>(hbuf, Sbuf, smax_key);
        k_bitemit<<<tg, 256, 0, stream>>>(Sbuf, u, smax_key, mb);
    } else {
        k_stile<0><<<tg, 256, 0, stream>>>(hbuf, nullptr, smax_key, nullptr);
        k_stile<1><<<tg, 256, 0, stream>>>(hbuf, u, smax_key, mb);
    }
    if (use_sparse)
        k_bits2idx2<<<NN * 2 / 4, 256, 0, stream>>>(mb, idx, rowcnt);

    const float* pm2_256 = pm + (size_t)NN * 256;
    const float* pm2_128 = pm + (size_t)NN * 128;

    // --- GraphSAGE layer 0 (256 -> 128) ---
    k_gemm_ab<256, 256><<<NN, 256, 0, stream>>>(feat, nullptr, p0W, p0b, nullptr, z, 1);
    if (use_sparse) {
        k_maskmax_s256<<<NN * 2 / 4, 256, 0, stream>>>(idx, rowcnt, z, pm);
        k_gemm_ab<256, 128><<<NN, 128, 0, stream>>>(pm, pm2_256, l0W, l0b, b0, hs, 0);
    } else {
        k_maskmax_dense<256, 8><<<NN / 8, 256, 0, stream>>>(mb, z, pm);
        k_gemm_ab<256, 128><<<NN, 128, 0, stream>>>(pm, nullptr, l0W, l0b, b0, hs, 0);
    }
    k_relu_l2norm<<<NN, 128, 0, stream>>>(hs);

    // --- GraphSAGE layer 1 (128 -> 128) ---
    k_gemm_ab<128, 128><<<NN, 128, 0, stream>>>(hs, nullptr, p1W, p1b, nullptr, z, 1);
    if (use_sparse) {
        k_maskmax_s128<<<NN * 2 / 4, 256, 0, stream>>>(idx, rowcnt, z, pm);
        k_gemm_ab<128, 128><<<NN, 128, 0, stream>>>(pm, pm2_128, l1W, l1b, b1, tmp, 0);
    } else {
        k_maskmax_dense<128, 8><<<NN / 8, 256, 0, stream>>>(mb, z, pm);
        k_gemm_ab<128, 128><<<NN, 128, 0, stream>>>(pm, nullptr, l1W, l1b, b1, tmp, 0);
    }
    k_relu_l2norm<<<NN, 128, 0, stream>>>(tmp);

    // --- GraphSAGE layer 2 (128 -> 32) ---
    k_gemm_ab<128, 128><<<NN, 128, 0, stream>>>(tmp, nullptr, p2W, p2b, nullptr, z, 1);
    if (use_sparse) {
        k_maskmax_s128<<<NN * 2 / 4, 256, 0, stream>>>(idx, rowcnt, z, pm);
        k_gemm_final<<<NN / 2, 64, 0, stream>>>(pm, pm2_128, l2W, l2b, b2, out);
    } else {
        k_maskmax_dense<128, 8><<<NN / 8, 256, 0, stream>>>(mb, z, pm);
        k_gemm_final<<<NN / 2, 64, 0, stream>>>(pm, nullptr, l2W, l2b, b2, out);
    }
}

// Round 7
// 1161.821 us; speedup vs baseline: 4.3867x; 1.2528x over previous
//
#include <hip/hip_runtime.h>
#include <cstdint>
#include <cstddef>

#define NN 4096
#define EE 131072
#define TS 64

__device__ __forceinline__ unsigned fkey(float f) {
    unsigned u = __float_as_uint(f);
    return (u & 0x80000000u) ? ~u : (u | 0x80000000u);
}
__device__ __forceinline__ float funkey(unsigned k) {
    unsigned u = (k & 0x80000000u) ? (k & 0x7fffffffu) : ~k;
    return __uint_as_float(u);
}

__global__ void k_count(const int* __restrict__ src, const int* __restrict__ dst,
                        int* __restrict__ cs, int* __restrict__ cd) {
    int e = blockIdx.x * 256 + threadIdx.x;
    if (e < EE) {
        atomicAdd(&cs[src[e]], 1);
        atomicAdd(&cd[dst[e]], 1);
    }
}

__global__ void k_norm(const int* __restrict__ cs, const int* __restrict__ cd,
                       float* __restrict__ on, float* __restrict__ inn) {
    int i = blockIdx.x * 256 + threadIdx.x;
    if (i < NN) {
        int a = cs[i] > 1 ? cs[i] : 1;
        int b = cd[i] > 1 ? cd[i] : 1;
        on[i]  = 1.0f / sqrtf((float)a);
        inn[i] = 1.0f / sqrtf((float)b);
    }
}

template<int K, int ND>
__global__ void k_gemm_scale(const float* __restrict__ X, const float* __restrict__ W,
                             const float* __restrict__ scale, float* __restrict__ out) {
    __shared__ float xr[K];
    int i = blockIdx.x;
    for (int k = threadIdx.x; k < K; k += ND) xr[k] = X[(size_t)i * K + k];
    __syncthreads();
    int j = threadIdx.x;
    float acc = 0.0f;
    #pragma unroll 8
    for (int k = 0; k < K; ++k) acc = fmaf(xr[k], W[k * ND + j], acc);
    out[(size_t)i * ND + j] = acc * scale[i];
}

// out[i][j] = (max over NS split-partials of X)[i][:] @ W + b1 (+b2) (opt relu).
template<int K, int ND, int NS>
__global__ void k_gemm_mrg(const float* __restrict__ X, size_t xstride,
                           const float* __restrict__ W,
                           const float* __restrict__ b1, const float* __restrict__ b2,
                           float* __restrict__ out, int do_relu) {
    __shared__ float xr[K];
    int i = blockIdx.x;
    for (int k = threadIdx.x; k < K; k += ND) {
        float v = X[(size_t)i * K + k];
        #pragma unroll
        for (int s = 1; s < NS; ++s)
            v = fmaxf(v, X[(size_t)s * xstride + (size_t)i * K + k]);
        xr[k] = v;
    }
    __syncthreads();
    int j = threadIdx.x;
    float acc = 0.0f;
    #pragma unroll 8
    for (int k = 0; k < K; ++k) acc = fmaf(xr[k], W[k * ND + j], acc);
    acc += b1[j];
    if (b2) acc += b2[j];
    if (do_relu) acc = fmaxf(acc, 0.0f);
    out[(size_t)i * ND + j] = acc;
}

__global__ void k_scatter(const float* __restrict__ t, const int* __restrict__ src,
                          const int* __restrict__ dst, float* __restrict__ agg) {
    int e = blockIdx.x;
    int j = threadIdx.x;   // 128 threads
    int s = src[e], d = dst[e];
    atomicAdd(&agg[(size_t)d * 128 + j], t[(size_t)s * 128 + j]);
}

__global__ void k_gcn_out(const float* __restrict__ agg, const float* __restrict__ inn,
                          const float* __restrict__ b, float* __restrict__ out, int do_relu) {
    int idx = blockIdx.x * 256 + threadIdx.x;
    int i = idx >> 7, j = idx & 127;
    float v = agg[idx] * inn[i] + b[j];
    if (do_relu) v = fmaxf(v, 0.0f);
    out[idx] = v;
}

// ---- S = h h^T 64x64 tile; MODE 0: max-only; MODE 1: recompute + bit-emit ----
template<int MODE>
__global__ __launch_bounds__(256, 4) void k_stile(const float* __restrict__ h,
                                                  const float* __restrict__ u,
                                                  unsigned* __restrict__ smax_key,
                                                  unsigned* __restrict__ mb) {
    int ti = blockIdx.y, tj = blockIdx.x;
    if (tj < ti) return;
    __shared__ float Ah[TS][68];
    __shared__ float Bh[TS][68];
    int tid = threadIdx.x;
    int tx = tid & 15, ty = tid >> 4;
    const float* ha = h + (size_t)ti * TS * 128;
    const float* hb = h + (size_t)tj * TS * 128;

    float acc[4][4];
    #pragma unroll
    for (int r = 0; r < 4; ++r)
        #pragma unroll
        for (int c = 0; c < 4; ++c) acc[r][c] = 0.0f;

    for (int half = 0; half < 2; ++half) {
        __syncthreads();
        #pragma unroll
        for (int t = 0; t < 4; ++t) {
            int f = tid + t * 256;
            int row = f >> 4, kk = f & 15;
            *(float4*)&Ah[row][kk * 4] = *(const float4*)(ha + (size_t)row * 128 + half * 64 + kk * 4);
            *(float4*)&Bh[row][kk * 4] = *(const float4*)(hb + (size_t)row * 128 + half * 64 + kk * 4);
        }
        __syncthreads();
        #pragma unroll 2
        for (int k4 = 0; k4 < 16; ++k4) {
            float4 a[4], b[4];
            #pragma unroll
            for (int r = 0; r < 4; ++r) a[r] = *(const float4*)&Ah[ty + 16 * r][k4 * 4];
            #pragma unroll
            for (int c = 0; c < 4; ++c) b[c] = *(const float4*)&Bh[tx + 16 * c][k4 * 4];
            #pragma unroll
            for (int r = 0; r < 4; ++r)
                #pragma unroll
                for (int c = 0; c < 4; ++c) {
                    acc[r][c] = fmaf(a[r].x, b[c].x, acc[r][c]);
                    acc[r][c] = fmaf(a[r].y, b[c].y, acc[r][c]);
                    acc[r][c] = fmaf(a[r].z, b[c].z, acc[r][c]);
                    acc[r][c] = fmaf(a[r].w, b[c].w, acc[r][c]);
                }
        }
    }

    if constexpr (MODE == 0) {
        float m = -3.4e38f;
        #pragma unroll
        for (int r = 0; r < 4; ++r)
            #pragma unroll
            for (int c = 0; c < 4; ++c) m = fmaxf(m, acc[r][c]);
        #pragma unroll
        for (int o = 1; o < 64; o <<= 1) m = fmaxf(m, __shfl_xor(m, o, 64));
        __shared__ float wm[4];
        if ((tid & 63) == 0) wm[tid >> 6] = m;
        __syncthreads();
        if (tid == 0) {
            float mm = fmaxf(fmaxf(wm[0], wm[1]), fmaxf(wm[2], wm[3]));
            atomicMax(smax_key, fkey(mm));
        }
    } else {
        float smax = funkey(*smax_key);
        float epmax = 1.0f / (1.0f + expf(-smax));
        __shared__ unsigned lm[TS][2];
        __shared__ unsigned lmT[TS][2];
        if (tid < 128) { lm[tid >> 1][tid & 1] = 0u; lmT[tid >> 1][tid & 1] = 0u; }
        __syncthreads();
        #pragma unroll
        for (int r = 0; r < 4; ++r) {
            #pragma unroll
            for (int c = 0; c < 4; ++c) {
                int li = ty + 16 * r, lj = tx + 16 * c;
                int gi = ti * TS + li, gj = tj * TS + lj;
                bool bit = false;
                if (gi < gj) {
                    float ep = 1.0f / (1.0f + expf(-acc[r][c]));
                    float P = ep / epmax;
                    float Pc = fminf(fmaxf(P, 1e-6f), 1.0f - 1e-6f);
                    float uu = u[(size_t)gi * NN + gj];
                    float ucv = fminf(fmaxf(uu, 1e-6f), 1.0f - 1e-6f);
                    bit = Pc > (1.0f - ucv);
                } else if (gi == gj) {
                    bit = true;
                }
                if (bit) {
                    atomicOr(&lm[li][lj >> 5], 1u << (lj & 31));
                    atomicOr(&lmT[lj][li >> 5], 1u << (li & 31));
                }
            }
        }
        __syncthreads();
        if (tid < 128) {
            int r = tid >> 1, wq = tid & 1;
            unsigned word = lm[r][wq];
            if (ti == tj) word |= lmT[r][wq];
            mb[(size_t)(ti * TS + r) * 128 + tj * 2 + wq] = word;
        } else if (ti != tj) {
            int r = (tid - 128) >> 1, wq = tid & 1;
            mb[(size_t)(tj * TS + r) * 128 + ti * 2 + wq] = lmT[r][wq];
        }
    }
}

// Pass 1 (S-store path): compute tile, store S to ws, fold into global max.
__global__ __launch_bounds__(256, 4) void k_stile_store(const float* __restrict__ h,
                                                        float* __restrict__ S,
                                                        unsigned* __restrict__ smax_key) {
    int ti = blockIdx.y, tj = blockIdx.x;
    if (tj < ti) return;
    __shared__ float Ah[TS][68];
    __shared__ float Bh[TS][68];
    int tid = threadIdx.x;
    int tx = tid & 15, ty = tid >> 4;
    const float* ha = h + (size_t)ti * TS * 128;
    const float* hb = h + (size_t)tj * TS * 128;

    float acc[4][4];
    #pragma unroll
    for (int r = 0; r < 4; ++r)
        #pragma unroll
        for (int c = 0; c < 4; ++c) acc[r][c] = 0.0f;

    for (int half = 0; half < 2; ++half) {
        __syncthreads();
        #pragma unroll
        for (int t = 0; t < 4; ++t) {
            int f = tid + t * 256;
            int row = f >> 4, kk = f & 15;
            *(float4*)&Ah[row][kk * 4] = *(const float4*)(ha + (size_t)row * 128 + half * 64 + kk * 4);
            *(float4*)&Bh[row][kk * 4] = *(const float4*)(hb + (size_t)row * 128 + half * 64 + kk * 4);
        }
        __syncthreads();
        #pragma unroll 2
        for (int k4 = 0; k4 < 16; ++k4) {
            float4 a[4], b[4];
            #pragma unroll
            for (int r = 0; r < 4; ++r) a[r] = *(const float4*)&Ah[ty + 16 * r][k4 * 4];
            #pragma unroll
            for (int c = 0; c < 4; ++c) b[c] = *(const float4*)&Bh[tx + 16 * c][k4 * 4];
            #pragma unroll
            for (int r = 0; r < 4; ++r)
                #pragma unroll
                for (int c = 0; c < 4; ++c) {
                    acc[r][c] = fmaf(a[r].x, b[c].x, acc[r][c]);
                    acc[r][c] = fmaf(a[r].y, b[c].y, acc[r][c]);
                    acc[r][c] = fmaf(a[r].z, b[c].z, acc[r][c]);
                    acc[r][c] = fmaf(a[r].w, b[c].w, acc[r][c]);
                }
        }
    }

    float* sp = S + (size_t)(ti * 64 + tj) * 4096;
    #pragma unroll
    for (int r = 0; r < 4; ++r)
        #pragma unroll
        for (int c = 0; c < 4; ++c)
            sp[(ty + 16 * r) * 64 + tx + 16 * c] = acc[r][c];

    float m = -3.4e38f;
    #pragma unroll
    for (int r = 0; r < 4; ++r)
        #pragma unroll
        for (int c = 0; c < 4; ++c) m = fmaxf(m, acc[r][c]);
    #pragma unroll
    for (int o = 1; o < 64; o <<= 1) m = fmaxf(m, __shfl_xor(m, o, 64));
    __shared__ float wm[4];
    if ((tid & 63) == 0) wm[tid >> 6] = m;
    __syncthreads();
    if (tid == 0)
        atomicMax(smax_key, fkey(fmaxf(fmaxf(wm[0], wm[1]), fmaxf(wm[2], wm[3]))));
}

// Pass 2 (S-store path): read stored S, emit mask bits.
__global__ __launch_bounds__(256, 4) void k_bitemit(const float* __restrict__ S,
                                                    const float* __restrict__ u,
                                                    const unsigned* __restrict__ smax_key,
                                                    unsigned* __restrict__ mb) {
    int ti = blockIdx.y, tj = blockIdx.x;
    if (tj < ti) return;
    int tid = threadIdx.x;
    int tx = tid & 15, ty = tid >> 4;
    float smax = funkey(*smax_key);
    float epmax = 1.0f / (1.0f + expf(-smax));
    __shared__ unsigned lm[TS][2];
    __shared__ unsigned lmT[TS][2];
    if (tid < 128) { lm[tid >> 1][tid & 1] = 0u; lmT[tid >> 1][tid & 1] = 0u; }
    __syncthreads();
    const float* sp = S + (size_t)(ti * 64 + tj) * 4096;
    #pragma unroll
    for (int r = 0; r < 4; ++r) {
        #pragma unroll
        for (int c = 0; c < 4; ++c) {
            int li = ty + 16 * r, lj = tx + 16 * c;
            int gi = ti * TS + li, gj = tj * TS + lj;
            bool bit = false;
            if (gi < gj) {
                float ep = 1.0f / (1.0f + expf(-sp[li * 64 + lj]));
                float P = ep / epmax;
                float Pc = fminf(fmaxf(P, 1e-6f), 1.0f - 1e-6f);
                float uu = u[(size_t)gi * NN + gj];
                float ucv = fminf(fmaxf(uu, 1e-6f), 1.0f - 1e-6f);
                bit = Pc > (1.0f - ucv);
            } else if (gi == gj) {
                bit = true;
            }
            if (bit) {
                atomicOr(&lm[li][lj >> 5], 1u << (lj & 31));
                atomicOr(&lmT[lj][li >> 5], 1u << (li & 31));
            }
        }
    }
    __syncthreads();
    if (tid < 128) {
        int r = tid >> 1, wq = tid & 1;
        unsigned word = lm[r][wq];
        if (ti == tj) word |= lmT[r][wq];
        mb[(size_t)(ti * TS + r) * 128 + tj * 2 + wq] = word;
    } else if (ti != tj) {
        int r = (tid - 128) >> 1, wq = tid & 1;
        mb[(size_t)(tj * TS + r) * 128 + ti * 2 + wq] = lmT[r][wq];
    }
}

// Dense masked max with register row-reuse: part[js][i][d] = max over j in
// segment js of (bit(i,j) ? z[j][d] : 0). Each z float4 load is amortized over
// RPG rows held in register accumulators -> 4-8x less cache traffic than RPG=1.
// Valid because z = relu(..) >= 0 and every full row has its diagonal bit set.
template<int D, int RT, int JS>
__global__ __launch_bounds__(256, 4) void k_mmax(const unsigned* __restrict__ mb,
                                                 const float* __restrict__ z,
                                                 float* __restrict__ part) {
    constexpr int D4 = D / 4;        // 64 (D=256) / 32 (D=128)
    constexpr int G = 256 / D4;      // 4 / 8 groups
    constexpr int RPG = RT / G;      // 8 / 4 rows per thread
    constexpr int JPS = NN / JS;     // 512 columns per segment
    constexpr int WPS = JPS / 32;    // 16 mask words per row-segment

    int nrb = NN / RT;               // 128 row-tiles
    int rowblk = blockIdx.x % nrb, js = blockIdx.x / nrb;
    int i0 = rowblk * RT;

    __shared__ unsigned msk[RT][WPS + 1];
    for (int t = threadIdx.x; t < RT * WPS; t += 256) {
        int r = t / WPS, wq = t % WPS;
        msk[r][wq] = mb[(size_t)(i0 + r) * 128 + js * WPS + wq];
    }
    __syncthreads();

    int d4 = threadIdx.x % D4;
    int g = threadIdx.x / D4;
    const float4* zr = (const float4*)z + (size_t)js * JPS * D4 + d4;

    float4 acc[RPG];
    #pragma unroll
    for (int r = 0; r < RPG; ++r) acc[r] = make_float4(0.f, 0.f, 0.f, 0.f);

    for (int wq = 0; wq < WPS; ++wq) {
        unsigned wr[RPG];
        #pragma unroll
        for (int r = 0; r < RPG; ++r) wr[r] = msk[g * RPG + r][wq];
        const float4* zp = zr + (size_t)(wq * 32) * D4;
        #pragma unroll 4
        for (int jj = 0; jj < 32; jj += 2) {
            float4 z0 = zp[jj * D4];
            float4 z1 = zp[(jj + 1) * D4];
            #pragma unroll
            for (int r = 0; r < RPG; ++r) {
                unsigned m0 = (unsigned)(((int)(wr[r] << (31 - jj))) >> 31);
                unsigned m1 = (unsigned)(((int)(wr[r] << (30 - jj))) >> 31);
                acc[r].x = fmaxf(acc[r].x, fmaxf(__uint_as_float(m0 & __float_as_uint(z0.x)),
                                                 __uint_as_float(m1 & __float_as_uint(z1.x))));
                acc[r].y = fmaxf(acc[r].y, fmaxf(__uint_as_float(m0 & __float_as_uint(z0.y)),
                                                 __uint_as_float(m1 & __float_as_uint(z1.y))));
                acc[r].z = fmaxf(acc[r].z, fmaxf(__uint_as_float(m0 & __float_as_uint(z0.z)),
                                                 __uint_as_float(m1 & __float_as_uint(z1.z))));
                acc[r].w = fmaxf(acc[r].w, fmaxf(__uint_as_float(m0 & __float_as_uint(z0.w)),
                                                 __uint_as_float(m1 & __float_as_uint(z1.w))));
            }
        }
    }

    float4* po = (float4*)(part + (size_t)js * NN * D);
    #pragma unroll
    for (int r = 0; r < RPG; ++r)
        po[(size_t)(i0 + g * RPG + r) * D4 + d4] = acc[r];
}

__global__ void k_relu_l2norm(float* __restrict__ h) {
    int i = blockIdx.x, d = threadIdx.x;
    float v = fmaxf(h[(size_t)i * 128 + d], 0.0f);
    float ss = v * v;
    #pragma unroll
    for (int o = 1; o < 64; o <<= 1) ss += __shfl_xor(ss, o, 64);
    __shared__ float w2[2];
    if ((d & 63) == 0) w2[d >> 6] = ss;
    __syncthreads();
    float tot = w2[0] + w2[1];
    float denom = fmaxf(sqrtf(tot), 1e-12f);
    h[(size_t)i * 128 + d] = v / denom;
}

// Final 128->32 GEMM with NS-way partial merge, LDS-staged. 4 rows per block.
template<int NS>
__global__ void k_gemm_final(const float* __restrict__ X, size_t xstride,
                             const float* __restrict__ W,
                             const float* __restrict__ b1, const float* __restrict__ b2,
                             float* __restrict__ out) {
    __shared__ float xr[4][128];
    int i0 = blockIdx.x * 4;
    for (int t = threadIdx.x; t < 512; t += 128) {
        int r = t >> 7, k = t & 127;
        float v = X[(size_t)(i0 + r) * 128 + k];
        #pragma unroll
        for (int s = 1; s < NS; ++s)
            v = fmaxf(v, X[(size_t)s * xstride + (size_t)(i0 + r) * 128 + k]);
        xr[r][k] = v;
    }
    __syncthreads();
    int il = threadIdx.x >> 5, j = threadIdx.x & 31;
    float acc = 0.0f;
    #pragma unroll 8
    for (int k = 0; k < 128; ++k) acc = fmaf(xr[il][k], W[k * 32 + j], acc);
    out[(size_t)(i0 + il) * 32 + j] = acc + b1[j] + b2[j];
}

extern "C" void kernel_launch(void* const* d_in, const int* in_sizes, int n_in,
                              void* d_out, int out_size, void* d_ws, size_t ws_size,
                              hipStream_t stream) {
    const float* inputs = (const float*)d_in[1];
    const float* feat   = (const float*)d_in[2];
    const float* u      = (const float*)d_in[3];
    const int*   src    = (const int*)d_in[4];
    const int*   dst    = (const int*)d_in[5];
    const float* gc0W = (const float*)d_in[6],  *gc0b = (const float*)d_in[7];
    const float* gc1W = (const float*)d_in[8],  *gc1b = (const float*)d_in[9];
    const float* p0W  = (const float*)d_in[10], *p0b  = (const float*)d_in[11];
    const float* l0W  = (const float*)d_in[12], *l0b  = (const float*)d_in[13];
    const float* b0   = (const float*)d_in[14];
    const float* p1W  = (const float*)d_in[15], *p1b  = (const float*)d_in[16];
    const float* l1W  = (const float*)d_in[17], *l1b  = (const float*)d_in[18];
    const float* b1   = (const float*)d_in[19];
    const float* p2W  = (const float*)d_in[20], *p2b  = (const float*)d_in[21];
    const float* l2W  = (const float*)d_in[22], *l2b  = (const float*)d_in[23];
    const float* b2   = (const float*)d_in[24];
    float* out = (float*)d_out;

    const size_t MB = 1048576;
    char* w = (char*)d_ws;
    int*      cnt_src  = (int*)(w + 0);            // 16 KB
    int*      cnt_dst  = (int*)(w + 16384);        // 16 KB
    float*    on       = (float*)(w + 32768);      // 16 KB
    float*    inn      = (float*)(w + 49152);      // 16 KB
    unsigned* smax_key = (unsigned*)(w + 65536);   // pad to 128 KB
    char*     big      = w + 131072;
    float*    tmp      = (float*)(big);            // 2 MB
    float*    agg      = (float*)(big + 2 * MB);   // 2 MB
    float*    hbuf     = (float*)(big + 4 * MB);   // 2 MB
    unsigned* mb       = (unsigned*)(big + 6 * MB);// 2 MB
    float*    z        = (float*)(big + 8 * MB);   // 4 MB
    float*    pm       = (float*)(big + 12 * MB);  // 32 MB (8 split partials)
    float*    hs       = (float*)(big + 44 * MB);  // 2 MB
    float*    Sbuf     = (float*)(big + 46 * MB);  // 64 MB
    bool use_sstore = ws_size >= 131072 + 110 * MB;

    hipMemsetAsync(w, 0, 131072, stream);
    k_count<<<EE / 256, 256, 0, stream>>>(src, dst, cnt_src, cnt_dst);
    k_norm<<<NN / 256, 256, 0, stream>>>(cnt_src, cnt_dst, on, inn);

    // --- GCN layer 0 ---
    k_gemm_scale<256, 128><<<NN, 128, 0, stream>>>(inputs, gc0W, on, tmp);
    hipMemsetAsync(agg, 0, (size_t)NN * 128 * 4, stream);
    k_scatter<<<EE, 128, 0, stream>>>(tmp, src, dst, agg);
    k_gcn_out<<<NN * 128 / 256, 256, 0, stream>>>(agg, inn, gc0b, hbuf, 1);

    // --- GCN layer 1 ---
    k_gemm_scale<128, 128><<<NN, 128, 0, stream>>>(hbuf, gc1W, on, tmp);
    hipMemsetAsync(agg, 0, (size_t)NN * 128 * 4, stream);
    k_scatter<<<EE, 128, 0, stream>>>(tmp, src, dst, agg);
    k_gcn_out<<<NN * 128 / 256, 256, 0, stream>>>(agg, inn, gc1b, hbuf, 0);

    // --- decode: S max + mask bits ---
    dim3 tg(64, 64);
    if (use_sstore) {
        k_stile_store<<<tg, 256, 0, stream>>>(hbuf, Sbuf, smax_key);
        k_bitemit<<<tg, 256, 0, stream>>>(Sbuf, u, smax_key, mb);
    } else {
        k_stile<0><<<tg, 256, 0, stream>>>(hbuf, nullptr, smax_key, nullptr);
        k_stile<1><<<tg, 256, 0, stream>>>(hbuf, u, smax_key, mb);
    }

    // --- GraphSAGE layer 0 (256 -> 128) ---
    k_gemm_mrg<256, 256, 1><<<NN, 256, 0, stream>>>(feat, 0, p0W, p0b, nullptr, z, 1);
    k_mmax<256, 32, 8><<<(NN / 32) * 8, 256, 0, stream>>>(mb, z, pm);
    k_gemm_mrg<256, 128, 8><<<NN, 128, 0, stream>>>(pm, (size_t)NN * 256, l0W, l0b, b0, hs, 0);
    k_relu_l2norm<<<NN, 128, 0, stream>>>(hs);

    // --- GraphSAGE layer 1 (128 -> 128) ---
    k_gemm_mrg<128, 128, 1><<<NN, 128, 0, stream>>>(hs, 0, p1W, p1b, nullptr, z, 1);
    k_mmax<128, 32, 8><<<(NN / 32) * 8, 256, 0, stream>>>(mb, z, pm);
    k_gemm_mrg<128, 128, 8><<<NN, 128, 0, stream>>>(pm, (size_t)NN * 128, l1W, l1b, b1, tmp, 0);
    k_relu_l2norm<<<NN, 128, 0, stream>>>(tmp);

    // --- GraphSAGE layer 2 (128 -> 32) ---
    k_gemm_mrg<128, 128, 1><<<NN, 128, 0, stream>>>(tmp, 0, p2W, p2b, nullptr, z, 1);
    k_mmax<128, 32, 8><<<(NN / 32) * 8, 256, 0, stream>>>(mb, z, pm);
    k_gemm_final<8><<<NN / 4, 128, 0, stream>>>(pm, (size_t)NN * 128, l2W, l2b, b2, out);
}

// Round 8
// 894.100 us; speedup vs baseline: 5.7002x; 1.2994x over previous
//
#include <hip/hip_runtime.h>
#include <cstdint>
#include <cstddef>

#define NN 4096
#define EE 131072
#define TS 64

__device__ __forceinline__ unsigned fkey(float f) {
    unsigned u = __float_as_uint(f);
    return (u & 0x80000000u) ? ~u : (u | 0x80000000u);
}
__device__ __forceinline__ float funkey(unsigned k) {
    unsigned u = (k & 0x80000000u) ? (k & 0x7fffffffu) : ~k;
    return __uint_as_float(u);
}

__device__ __forceinline__ float4 max4(float4 a, float4 b) {
    return make_float4(fmaxf(a.x, b.x), fmaxf(a.y, b.y), fmaxf(a.z, b.z), fmaxf(a.w, b.w));
}
// sign-extended 1-bit field extract: 0 -> 0x0, 1 -> 0xFFFFFFFF (v_bfe_i32)
__device__ __forceinline__ unsigned bit_sext(unsigned w, unsigned off) {
#if __has_builtin(__builtin_amdgcn_sbfe)
    return (unsigned)__builtin_amdgcn_sbfe((int)w, off, 1u);
#else
    return (unsigned)(-(int)((w >> off) & 1u));
#endif
}
__device__ __forceinline__ float4 and4(unsigned m, float4 v) {
    return make_float4(__uint_as_float(m & __float_as_uint(v.x)),
                       __uint_as_float(m & __float_as_uint(v.y)),
                       __uint_as_float(m & __float_as_uint(v.z)),
                       __uint_as_float(m & __float_as_uint(v.w)));
}

__global__ void k_count(const int* __restrict__ src, const int* __restrict__ dst,
                        int* __restrict__ cs, int* __restrict__ cd) {
    int e = blockIdx.x * 256 + threadIdx.x;
    if (e < EE) {
        atomicAdd(&cs[src[e]], 1);
        atomicAdd(&cd[dst[e]], 1);
    }
}

__global__ void k_norm(const int* __restrict__ cs, const int* __restrict__ cd,
                       float* __restrict__ on, float* __restrict__ inn) {
    int i = blockIdx.x * 256 + threadIdx.x;
    if (i < NN) {
        int a = cs[i] > 1 ? cs[i] : 1;
        int b = cd[i] > 1 ? cd[i] : 1;
        on[i]  = 1.0f / sqrtf((float)a);
        inn[i] = 1.0f / sqrtf((float)b);
    }
}

template<int K, int ND>
__global__ void k_gemm_scale(const float* __restrict__ X, const float* __restrict__ W,
                             const float* __restrict__ scale, float* __restrict__ out) {
    __shared__ float xr[K];
    int i = blockIdx.x;
    for (int k = threadIdx.x; k < K; k += ND) xr[k] = X[(size_t)i * K + k];
    __syncthreads();
    int j = threadIdx.x;
    float acc = 0.0f;
    #pragma unroll 8
    for (int k = 0; k < K; ++k) acc = fmaf(xr[k], W[k * ND + j], acc);
    out[(size_t)i * ND + j] = acc * scale[i];
}

// out[i][j] = (max over NS split-partials of X)[i][:] @ W + b1 (+b2) (opt relu).
template<int K, int ND, int NS>
__global__ void k_gemm_mrg(const float* __restrict__ X, size_t xstride,
                           const float* __restrict__ W,
                           const float* __restrict__ b1, const float* __restrict__ b2,
                           float* __restrict__ out, int do_relu) {
    __shared__ float xr[K];
    int i = blockIdx.x;
    for (int k = threadIdx.x; k < K; k += ND) {
        float v = X[(size_t)i * K + k];
        #pragma unroll
        for (int s = 1; s < NS; ++s)
            v = fmaxf(v, X[(size_t)s * xstride + (size_t)i * K + k]);
        xr[k] = v;
    }
    __syncthreads();
    int j = threadIdx.x;
    float acc = 0.0f;
    #pragma unroll 8
    for (int k = 0; k < K; ++k) acc = fmaf(xr[k], W[k * ND + j], acc);
    acc += b1[j];
    if (b2) acc += b2[j];
    if (do_relu) acc = fmaxf(acc, 0.0f);
    out[(size_t)i * ND + j] = acc;
}

__global__ void k_scatter(const float* __restrict__ t, const int* __restrict__ src,
                          const int* __restrict__ dst, float* __restrict__ agg) {
    int e = blockIdx.x;
    int j = threadIdx.x;   // 128 threads
    int s = src[e], d = dst[e];
    atomicAdd(&agg[(size_t)d * 128 + j], t[(size_t)s * 128 + j]);
}

__global__ void k_gcn_out(const float* __restrict__ agg, const float* __restrict__ inn,
                          const float* __restrict__ b, float* __restrict__ out, int do_relu) {
    int idx = blockIdx.x * 256 + threadIdx.x;
    int i = idx >> 7, j = idx & 127;
    float v = agg[idx] * inn[i] + b[j];
    if (do_relu) v = fmaxf(v, 0.0f);
    out[idx] = v;
}

// ---- S = h h^T 64x64 tile; MODE 0: max-only; MODE 1: recompute + bit-emit ----
template<int MODE>
__global__ __launch_bounds__(256, 4) void k_stile(const float* __restrict__ h,
                                                  const float* __restrict__ u,
                                                  unsigned* __restrict__ smax_key,
                                                  unsigned* __restrict__ mb) {
    int ti = blockIdx.y, tj = blockIdx.x;
    if (tj < ti) return;
    __shared__ float Ah[TS][68];
    __shared__ float Bh[TS][68];
    int tid = threadIdx.x;
    int tx = tid & 15, ty = tid >> 4;
    const float* ha = h + (size_t)ti * TS * 128;
    const float* hb = h + (size_t)tj * TS * 128;

    float acc[4][4];
    #pragma unroll
    for (int r = 0; r < 4; ++r)
        #pragma unroll
        for (int c = 0; c < 4; ++c) acc[r][c] = 0.0f;

    for (int half = 0; half < 2; ++half) {
        __syncthreads();
        #pragma unroll
        for (int t = 0; t < 4; ++t) {
            int f = tid + t * 256;
            int row = f >> 4, kk = f & 15;
            *(float4*)&Ah[row][kk * 4] = *(const float4*)(ha + (size_t)row * 128 + half * 64 + kk * 4);
            *(float4*)&Bh[row][kk * 4] = *(const float4*)(hb + (size_t)row * 128 + half * 64 + kk * 4);
        }
        __syncthreads();
        #pragma unroll 2
        for (int k4 = 0; k4 < 16; ++k4) {
            float4 a[4], b[4];
            #pragma unroll
            for (int r = 0; r < 4; ++r) a[r] = *(const float4*)&Ah[ty + 16 * r][k4 * 4];
            #pragma unroll
            for (int c = 0; c < 4; ++c) b[c] = *(const float4*)&Bh[tx + 16 * c][k4 * 4];
            #pragma unroll
            for (int r = 0; r < 4; ++r)
                #pragma unroll
                for (int c = 0; c < 4; ++c) {
                    acc[r][c] = fmaf(a[r].x, b[c].x, acc[r][c]);
                    acc[r][c] = fmaf(a[r].y, b[c].y, acc[r][c]);
                    acc[r][c] = fmaf(a[r].z, b[c].z, acc[r][c]);
                    acc[r][c] = fmaf(a[r].w, b[c].w, acc[r][c]);
                }
        }
    }

    if constexpr (MODE == 0) {
        float m = -3.4e38f;
        #pragma unroll
        for (int r = 0; r < 4; ++r)
            #pragma unroll
            for (int c = 0; c < 4; ++c) m = fmaxf(m, acc[r][c]);
        #pragma unroll
        for (int o = 1; o < 64; o <<= 1) m = fmaxf(m, __shfl_xor(m, o, 64));
        __shared__ float wm[4];
        if ((tid & 63) == 0) wm[tid >> 6] = m;
        __syncthreads();
        if (tid == 0) {
            float mm = fmaxf(fmaxf(wm[0], wm[1]), fmaxf(wm[2], wm[3]));
            atomicMax(smax_key, fkey(mm));
        }
    } else {
        float smax = funkey(*smax_key);
        float epmax = 1.0f / (1.0f + expf(-smax));
        __shared__ unsigned lm[TS][2];
        __shared__ unsigned lmT[TS][2];
        if (tid < 128) { lm[tid >> 1][tid & 1] = 0u; lmT[tid >> 1][tid & 1] = 0u; }
        __syncthreads();
        #pragma unroll
        for (int r = 0; r < 4; ++r) {
            #pragma unroll
            for (int c = 0; c < 4; ++c) {
                int li = ty + 16 * r, lj = tx + 16 * c;
                int gi = ti * TS + li, gj = tj * TS + lj;
                bool bit = false;
                if (gi < gj) {
                    float ep = 1.0f / (1.0f + expf(-acc[r][c]));
                    float P = ep / epmax;
                    float Pc = fminf(fmaxf(P, 1e-6f), 1.0f - 1e-6f);
                    float uu = u[(size_t)gi * NN + gj];
                    float ucv = fminf(fmaxf(uu, 1e-6f), 1.0f - 1e-6f);
                    bit = Pc > (1.0f - ucv);
                } else if (gi == gj) {
                    bit = true;
                }
                if (bit) {
                    atomicOr(&lm[li][lj >> 5], 1u << (lj & 31));
                    atomicOr(&lmT[lj][li >> 5], 1u << (li & 31));
                }
            }
        }
        __syncthreads();
        if (tid < 128) {
            int r = tid >> 1, wq = tid & 1;
            unsigned word = lm[r][wq];
            if (ti == tj) word |= lmT[r][wq];
            mb[(size_t)(ti * TS + r) * 128 + tj * 2 + wq] = word;
        } else if (ti != tj) {
            int r = (tid - 128) >> 1, wq = tid & 1;
            mb[(size_t)(tj * TS + r) * 128 + ti * 2 + wq] = lmT[r][wq];
        }
    }
}

// Pass 1 (S-store path): compute tile, store S to ws, fold into global max.
__global__ __launch_bounds__(256, 4) void k_stile_store(const float* __restrict__ h,
                                                        float* __restrict__ S,
                                                        unsigned* __restrict__ smax_key) {
    int ti = blockIdx.y, tj = blockIdx.x;
    if (tj < ti) return;
    __shared__ float Ah[TS][68];
    __shared__ float Bh[TS][68];
    int tid = threadIdx.x;
    int tx = tid & 15, ty = tid >> 4;
    const float* ha = h + (size_t)ti * TS * 128;
    const float* hb = h + (size_t)tj * TS * 128;

    float acc[4][4];
    #pragma unroll
    for (int r = 0; r < 4; ++r)
        #pragma unroll
        for (int c = 0; c < 4; ++c) acc[r][c] = 0.0f;

    for (int half = 0; half < 2; ++half) {
        __syncthreads();
        #pragma unroll
        for (int t = 0; t < 4; ++t) {
            int f = tid + t * 256;
            int row = f >> 4, kk = f & 15;
            *(float4*)&Ah[row][kk * 4] = *(const float4*)(ha + (size_t)row * 128 + half * 64 + kk * 4);
            *(float4*)&Bh[row][kk * 4] = *(const float4*)(hb + (size_t)row * 128 + half * 64 + kk * 4);
        }
        __syncthreads();
        #pragma unroll 2
        for (int k4 = 0; k4 < 16; ++k4) {
            float4 a[4], b[4];
            #pragma unroll
            for (int r = 0; r < 4; ++r) a[r] = *(const float4*)&Ah[ty + 16 * r][k4 * 4];
            #pragma unroll
            for (int c = 0; c < 4; ++c) b[c] = *(const float4*)&Bh[tx + 16 * c][k4 * 4];
            #pragma unroll
            for (int r = 0; r < 4; ++r)
                #pragma unroll
                for (int c = 0; c < 4; ++c) {
                    acc[r][c] = fmaf(a[r].x, b[c].x, acc[r][c]);
                    acc[r][c] = fmaf(a[r].y, b[c].y, acc[r][c]);
                    acc[r][c] = fmaf(a[r].z, b[c].z, acc[r][c]);
                    acc[r][c] = fmaf(a[r].w, b[c].w, acc[r][c]);
                }
        }
    }

    float* sp = S + (size_t)(ti * 64 + tj) * 4096;
    #pragma unroll
    for (int r = 0; r < 4; ++r)
        #pragma unroll
        for (int c = 0; c < 4; ++c)
            sp[(ty + 16 * r) * 64 + tx + 16 * c] = acc[r][c];

    float m = -3.4e38f;
    #pragma unroll
    for (int r = 0; r < 4; ++r)
        #pragma unroll
        for (int c = 0; c < 4; ++c) m = fmaxf(m, acc[r][c]);
    #pragma unroll
    for (int o = 1; o < 64; o <<= 1) m = fmaxf(m, __shfl_xor(m, o, 64));
    __shared__ float wm[4];
    if ((tid & 63) == 0) wm[tid >> 6] = m;
    __syncthreads();
    if (tid == 0)
        atomicMax(smax_key, fkey(fmaxf(fmaxf(wm[0], wm[1]), fmaxf(wm[2], wm[3]))));
}

// Pass 2 (S-store path): read stored S, emit mask bits.
__global__ __launch_bounds__(256, 4) void k_bitemit(const float* __restrict__ S,
                                                    const float* __restrict__ u,
                                                    const unsigned* __restrict__ smax_key,
                                                    unsigned* __restrict__ mb) {
    int ti = blockIdx.y, tj = blockIdx.x;
    if (tj < ti) return;
    int tid = threadIdx.x;
    int tx = tid & 15, ty = tid >> 4;
    float smax = funkey(*smax_key);
    float epmax = 1.0f / (1.0f + expf(-smax));
    __shared__ unsigned lm[TS][2];
    __shared__ unsigned lmT[TS][2];
    if (tid < 128) { lm[tid >> 1][tid & 1] = 0u; lmT[tid >> 1][tid & 1] = 0u; }
    __syncthreads();
    const float* sp = S + (size_t)(ti * 64 + tj) * 4096;
    #pragma unroll
    for (int r = 0; r < 4; ++r) {
        #pragma unroll
        for (int c = 0; c < 4; ++c) {
            int li = ty + 16 * r, lj = tx + 16 * c;
            int gi = ti * TS + li, gj = tj * TS + lj;
            bool bit = false;
            if (gi < gj) {
                float ep = 1.0f / (1.0f + expf(-sp[li * 64 + lj]));
                float P = ep / epmax;
                float Pc = fminf(fmaxf(P, 1e-6f), 1.0f - 1e-6f);
                float uu = u[(size_t)gi * NN + gj];
                float ucv = fminf(fmaxf(uu, 1e-6f), 1.0f - 1e-6f);
                bit = Pc > (1.0f - ucv);
            } else if (gi == gj) {
                bit = true;
            }
            if (bit) {
                atomicOr(&lm[li][lj >> 5], 1u << (lj & 31));
                atomicOr(&lmT[lj][li >> 5], 1u << (li & 31));
            }
        }
    }
    __syncthreads();
    if (tid < 128) {
        int r = tid >> 1, wq = tid & 1;
        unsigned word = lm[r][wq];
        if (ti == tj) word |= lmT[r][wq];
        mb[(size_t)(ti * TS + r) * 128 + tj * 2 + wq] = word;
    } else if (ti != tj) {
        int r = (tid - 128) >> 1, wq = tid & 1;
        mb[(size_t)(tj * TS + r) * 128 + ti * 2 + wq] = lmT[r][wq];
    }
}

// Masked max, D=256. Mask bit is WAVE-UNIFORM (64 lanes = one row-group), so
// hoist mask words to SGPR via readfirstlane and branch: masked-out (row,j)
// pairs cost zero VALU (scalar pipe only); present pairs cost 4 v_max.
template<int RT, int JS>
__global__ __launch_bounds__(256, 4) void k_mmax256(const unsigned* __restrict__ mb,
                                                    const float* __restrict__ z,
                                                    float* __restrict__ part) {
    constexpr int JPS = NN / JS;   // 512
    constexpr int WPS = JPS / 32;  // 16
    constexpr int RPG = RT / 4;    // rows per thread (4 waves/block)
    constexpr int NRB = NN / RT;
    int rowblk = blockIdx.x % NRB, js = blockIdx.x / NRB;
    int i0 = rowblk * RT;

    __shared__ unsigned msk[RT][WPS + 1];
    for (int t = threadIdx.x; t < RT * WPS; t += 256)
        msk[t / WPS][t % WPS] = mb[(size_t)(i0 + t / WPS) * 128 + js * WPS + t % WPS];
    __syncthreads();

    int d4 = threadIdx.x & 63;
    int g = threadIdx.x >> 6;
    const float4* zr = (const float4*)z + (size_t)js * JPS * 64 + d4;

    float4 acc[RPG];
    #pragma unroll
    for (int r = 0; r < RPG; ++r) acc[r] = make_float4(0.f, 0.f, 0.f, 0.f);

    for (int wq = 0; wq < WPS; ++wq) {
        unsigned m[RPG];
        #pragma unroll
        for (int r = 0; r < RPG; ++r)
            m[r] = (unsigned)__builtin_amdgcn_readfirstlane((int)msk[g * RPG + r][wq]);
        const float4* zp = zr + (size_t)(wq * 32) * 64;
        #pragma unroll 4
        for (int jj = 0; jj < 32; ++jj) {
            float4 zv = zp[(size_t)jj * 64];
            #pragma unroll
            for (int r = 0; r < RPG; ++r)
                if (m[r] & (1u << jj)) acc[r] = max4(acc[r], zv);
        }
    }

    float4* po = (float4*)(part + (size_t)js * NN * 256);
    #pragma unroll
    for (int r = 0; r < RPG; ++r)
        po[(size_t)(i0 + g * RPG + r) * 64 + d4] = acc[r];
}

// Masked max, D=128. A wave processes 2 j's at once (jpar = lane>>5); mask ->
// full-word via single v_bfe_i32 (sbfe), then and+max. ~1.2 VALU/element.
template<int RT, int JS>
__global__ __launch_bounds__(256, 4) void k_mmax128(const unsigned* __restrict__ mb,
                                                    const float* __restrict__ z,
                                                    float* __restrict__ part) {
    constexpr int JPS = NN / JS;   // 512
    constexpr int WPS = JPS / 32;  // 16
    constexpr int RPG = RT / 4;    // rows per thread (4 waves/block)
    constexpr int NRB = NN / RT;
    int rowblk = blockIdx.x % NRB, js = blockIdx.x / NRB;
    int i0 = rowblk * RT;

    __shared__ unsigned msk[RT][WPS + 1];
    for (int t = threadIdx.x; t < RT * WPS; t += 256)
        msk[t / WPS][t % WPS] = mb[(size_t)(i0 + t / WPS) * 128 + js * WPS + t % WPS];
    __syncthreads();

    int lane = threadIdx.x & 63;
    int g = threadIdx.x >> 6;
    unsigned jpar = lane >> 5;
    int d4 = lane & 31;
    const float4* zr = (const float4*)z + (size_t)js * JPS * 32 + d4;

    float4 acc[RPG];
    #pragma unroll
    for (int r = 0; r < RPG; ++r) acc[r] = make_float4(0.f, 0.f, 0.f, 0.f);

    for (int wq = 0; wq < WPS; ++wq) {
        unsigned m[RPG];
        #pragma unroll
        for (int r = 0; r < RPG; ++r) m[r] = msk[g * RPG + r][wq];
        const float4* zp = zr + (size_t)(wq * 32) * 32;
        #pragma unroll 8
        for (int jp = 0; jp < 32; jp += 2) {
            float4 zv = zp[(size_t)(jp + jpar) * 32];
            unsigned off = jp + jpar;
            #pragma unroll
            for (int r = 0; r < RPG; ++r)
                acc[r] = max4(acc[r], and4(bit_sext(m[r], off), zv));
        }
    }

    // merge the two j-halves of the wave
    #pragma unroll
    for (int r = 0; r < RPG; ++r) {
        acc[r].x = fmaxf(acc[r].x, __shfl_xor(acc[r].x, 32, 64));
        acc[r].y = fmaxf(acc[r].y, __shfl_xor(acc[r].y, 32, 64));
        acc[r].z = fmaxf(acc[r].z, __shfl_xor(acc[r].z, 32, 64));
        acc[r].w = fmaxf(acc[r].w, __shfl_xor(acc[r].w, 32, 64));
    }
    if (!jpar) {
        float4* po = (float4*)(part + (size_t)js * NN * 128);
        #pragma unroll
        for (int r = 0; r < RPG; ++r)
            po[(size_t)(i0 + g * RPG + r) * 32 + d4] = acc[r];
    }
}

__global__ void k_relu_l2norm(float* __restrict__ h) {
    int i = blockIdx.x, d = threadIdx.x;
    float v = fmaxf(h[(size_t)i * 128 + d], 0.0f);
    float ss = v * v;
    #pragma unroll
    for (int o = 1; o < 64; o <<= 1) ss += __shfl_xor(ss, o, 64);
    __shared__ float w2[2];
    if ((d & 63) == 0) w2[d >> 6] = ss;
    __syncthreads();
    float tot = w2[0] + w2[1];
    float denom = fmaxf(sqrtf(tot), 1e-12f);
    h[(size_t)i * 128 + d] = v / denom;
}

// Final 128->32 GEMM with NS-way partial merge, LDS-staged. 4 rows per block.
template<int NS>
__global__ void k_gemm_final(const float* __restrict__ X, size_t xstride,
                             const float* __restrict__ W,
                             const float* __restrict__ b1, const float* __restrict__ b2,
                             float* __restrict__ out) {
    __shared__ float xr[4][128];
    int i0 = blockIdx.x * 4;
    for (int t = threadIdx.x; t < 512; t += 128) {
        int r = t >> 7, k = t & 127;
        float v = X[(size_t)(i0 + r) * 128 + k];
        #pragma unroll
        for (int s = 1; s < NS; ++s)
            v = fmaxf(v, X[(size_t)s * xstride + (size_t)(i0 + r) * 128 + k]);
        xr[r][k] = v;
    }
    __syncthreads();
    int il = threadIdx.x >> 5, j = threadIdx.x & 31;
    float acc = 0.0f;
    #pragma unroll 8
    for (int k = 0; k < 128; ++k) acc = fmaf(xr[il][k], W[k * 32 + j], acc);
    out[(size_t)(i0 + il) * 32 + j] = acc + b1[j] + b2[j];
}

extern "C" void kernel_launch(void* const* d_in, const int* in_sizes, int n_in,
                              void* d_out, int out_size, void* d_ws, size_t ws_size,
                              hipStream_t stream) {
    const float* inputs = (const float*)d_in[1];
    const float* feat   = (const float*)d_in[2];
    const float* u      = (const float*)d_in[3];
    const int*   src    = (const int*)d_in[4];
    const int*   dst    = (const int*)d_in[5];
    const float* gc0W = (const float*)d_in[6],  *gc0b = (const float*)d_in[7];
    const float* gc1W = (const float*)d_in[8],  *gc1b = (const float*)d_in[9];
    const float* p0W  = (const float*)d_in[10], *p0b  = (const float*)d_in[11];
    const float* l0W  = (const float*)d_in[12], *l0b  = (const float*)d_in[13];
    const float* b0   = (const float*)d_in[14];
    const float* p1W  = (const float*)d_in[15], *p1b  = (const float*)d_in[16];
    const float* l1W  = (const float*)d_in[17], *l1b  = (const float*)d_in[18];
    const float* b1   = (const float*)d_in[19];
    const float* p2W  = (const float*)d_in[20], *p2b  = (const float*)d_in[21];
    const float* l2W  = (const float*)d_in[22], *l2b  = (const float*)d_in[23];
    const float* b2   = (const float*)d_in[24];
    float* out = (float*)d_out;

    const size_t MB = 1048576;
    char* w = (char*)d_ws;
    int*      cnt_src  = (int*)(w + 0);            // 16 KB
    int*      cnt_dst  = (int*)(w + 16384);        // 16 KB
    float*    on       = (float*)(w + 32768);      // 16 KB
    float*    inn      = (float*)(w + 49152);      // 16 KB
    unsigned* smax_key = (unsigned*)(w + 65536);   // pad to 128 KB
    char*     big      = w + 131072;
    float*    tmp      = (float*)(big);            // 2 MB
    float*    agg      = (float*)(big + 2 * MB);   // 2 MB
    float*    hbuf     = (float*)(big + 4 * MB);   // 2 MB
    unsigned* mb       = (unsigned*)(big + 6 * MB);// 2 MB
    float*    z        = (float*)(big + 8 * MB);   // 4 MB
    float*    pm       = (float*)(big + 12 * MB);  // 32 MB (8 split partials)
    float*    hs       = (float*)(big + 44 * MB);  // 2 MB
    float*    Sbuf     = (float*)(big + 46 * MB);  // 64 MB
    bool use_sstore = ws_size >= 131072 + 110 * MB;

    hipMemsetAsync(w, 0, 131072, stream);
    k_count<<<EE / 256, 256, 0, stream>>>(src, dst, cnt_src, cnt_dst);
    k_norm<<<NN / 256, 256, 0, stream>>>(cnt_src, cnt_dst, on, inn);

    // --- GCN layer 0 ---
    k_gemm_scale<256, 128><<<NN, 128, 0, stream>>>(inputs, gc0W, on, tmp);
    hipMemsetAsync(agg, 0, (size_t)NN * 128 * 4, stream);
    k_scatter<<<EE, 128, 0, stream>>>(tmp, src, dst, agg);
    k_gcn_out<<<NN * 128 / 256, 256, 0, stream>>>(agg, inn, gc0b, hbuf, 1);

    // --- GCN layer 1 ---
    k_gemm_scale<128, 128><<<NN, 128, 0, stream>>>(hbuf, gc1W, on, tmp);
    hipMemsetAsync(agg, 0, (size_t)NN * 128 * 4, stream);
    k_scatter<<<EE, 128, 0, stream>>>(tmp, src, dst, agg);
    k_gcn_out<<<NN * 128 / 256, 256, 0, stream>>>(agg, inn, gc1b, hbuf, 0);

    // --- decode: S max + mask bits ---
    dim3 tg(64, 64);
    if (use_sstore) {
        k_stile_store<<<tg, 256, 0, stream>>>(hbuf, Sbuf, smax_key);
        k_bitemit<<<tg, 256, 0, stream>>>(Sbuf, u, smax_key, mb);
    } else {
        k_stile<0><<<tg, 256, 0, stream>>>(hbuf, nullptr, smax_key, nullptr);
        k_stile<1><<<tg, 256, 0, stream>>>(hbuf, u, smax_key, mb);
    }

    // --- GraphSAGE layer 0 (256 -> 128) ---
    k_gemm_mrg<256, 256, 1><<<NN, 256, 0, stream>>>(feat, 0, p0W, p0b, nullptr, z, 1);
    k_mmax256<32, 8><<<(NN / 32) * 8, 256, 0, stream>>>(mb, z, pm);
    k_gemm_mrg<256, 128, 8><<<NN, 128, 0, stream>>>(pm, (size_t)NN * 256, l0W, l0b, b0, hs, 0);
    k_relu_l2norm<<<NN, 128, 0, stream>>>(hs);

    // --- GraphSAGE layer 1 (128 -> 128) ---
    k_gemm_mrg<128, 128, 1><<<NN, 128, 0, stream>>>(hs, 0, p1W, p1b, nullptr, z, 1);
    k_mmax128<16, 8><<<(NN / 16) * 8, 256, 0, stream>>>(mb, z, pm);
    k_gemm_mrg<128, 128, 8><<<NN, 128, 0, stream>>>(pm, (size_t)NN * 128, l1W, l1b, b1, tmp, 0);
    k_relu_l2norm<<<NN, 128, 0, stream>>>(tmp);

    // --- GraphSAGE layer 2 (128 -> 32) ---
    k_gemm_mrg<128, 128, 1><<<NN, 128, 0, stream>>>(tmp, 0, p2W, p2b, nullptr, z, 1);
    k_mmax128<16, 8><<<(NN / 16) * 8, 256, 0, stream>>>(mb, z, pm);
    k_gemm_final<8><<<NN / 4, 128, 0, stream>>>(pm, (size_t)NN * 128, l2W, l2b, b2, out);
}

// Round 9
// 814.179 us; speedup vs baseline: 6.2598x; 1.0982x over previous
//
#include <hip/hip_runtime.h>
#include <cstdint>
#include <cstddef>

#define NN 4096
#define EE 131072
#define TS 64

__device__ __forceinline__ unsigned fkey(float f) {
    unsigned u = __float_as_uint(f);
    return (u & 0x80000000u) ? ~u : (u | 0x80000000u);
}
__device__ __forceinline__ float funkey(unsigned k) {
    unsigned u = (k & 0x80000000u) ? (k & 0x7fffffffu) : ~k;
    return __uint_as_float(u);
}

__device__ __forceinline__ float4 max4(float4 a, float4 b) {
    return make_float4(fmaxf(a.x, b.x), fmaxf(a.y, b.y), fmaxf(a.z, b.z), fmaxf(a.w, b.w));
}
// fmax3 fusion: fmaxf(fmaxf(a,b),c) -> v_max3_f32
__device__ __forceinline__ float4 max3_4(float4 a, float4 b, float4 c) {
    return make_float4(fmaxf(fmaxf(a.x, b.x), c.x), fmaxf(fmaxf(a.y, b.y), c.y),
                       fmaxf(fmaxf(a.z, b.z), c.z), fmaxf(fmaxf(a.w, b.w), c.w));
}
// sign-extended 1-bit field extract (vector: v_bfe_i32)
__device__ __forceinline__ unsigned bit_sext(unsigned w, unsigned off) {
#if __has_builtin(__builtin_amdgcn_sbfe)
    return (unsigned)__builtin_amdgcn_sbfe((int)w, off, 1u);
#else
    return (unsigned)(-(int)((w >> off) & 1u));
#endif
}
// scalar-friendly sext-bit (uniform input -> s_lshl/s_ashr or s_bfe_i32)
__device__ __forceinline__ unsigned bit_sext_s(unsigned w, int off) {
    return (unsigned)(((int)(w << (31 - off))) >> 31);
}
__device__ __forceinline__ float4 and4(unsigned m, float4 v) {
    return make_float4(__uint_as_float(m & __float_as_uint(v.x)),
                       __uint_as_float(m & __float_as_uint(v.y)),
                       __uint_as_float(m & __float_as_uint(v.z)),
                       __uint_as_float(m & __float_as_uint(v.w)));
}

__global__ void k_count(const int* __restrict__ src, const int* __restrict__ dst,
                        int* __restrict__ cs, int* __restrict__ cd) {
    int e = blockIdx.x * 256 + threadIdx.x;
    if (e < EE) {
        atomicAdd(&cs[src[e]], 1);
        atomicAdd(&cd[dst[e]], 1);
    }
}

__global__ void k_norm(const int* __restrict__ cs, const int* __restrict__ cd,
                       float* __restrict__ on, float* __restrict__ inn) {
    int i = blockIdx.x * 256 + threadIdx.x;
    if (i < NN) {
        int a = cs[i] > 1 ? cs[i] : 1;
        int b = cd[i] > 1 ? cd[i] : 1;
        on[i]  = 1.0f / sqrtf((float)a);
        inn[i] = 1.0f / sqrtf((float)b);
    }
}

template<int K, int ND>
__global__ void k_gemm_scale(const float* __restrict__ X, const float* __restrict__ W,
                             const float* __restrict__ scale, float* __restrict__ out) {
    __shared__ float xr[K];
    int i = blockIdx.x;
    for (int k = threadIdx.x; k < K; k += ND) xr[k] = X[(size_t)i * K + k];
    __syncthreads();
    int j = threadIdx.x;
    float acc = 0.0f;
    #pragma unroll 8
    for (int k = 0; k < K; ++k) acc = fmaf(xr[k], W[k * ND + j], acc);
    out[(size_t)i * ND + j] = acc * scale[i];
}

// out[i][j] = (max over NS split-partials of X)[i][:] @ W + b1 (+b2) (opt relu).
template<int K, int ND, int NS>
__global__ void k_gemm_mrg(const float* __restrict__ X, size_t xstride,
                           const float* __restrict__ W,
                           const float* __restrict__ b1, const float* __restrict__ b2,
                           float* __restrict__ out, int do_relu) {
    __shared__ float xr[K];
    int i = blockIdx.x;
    for (int k = threadIdx.x; k < K; k += ND) {
        float v = X[(size_t)i * K + k];
        #pragma unroll
        for (int s = 1; s < NS; ++s)
            v = fmaxf(v, X[(size_t)s * xstride + (size_t)i * K + k]);
        xr[k] = v;
    }
    __syncthreads();
    int j = threadIdx.x;
    float acc = 0.0f;
    #pragma unroll 8
    for (int k = 0; k < K; ++k) acc = fmaf(xr[k], W[k * ND + j], acc);
    acc += b1[j];
    if (b2) acc += b2[j];
    if (do_relu) acc = fmaxf(acc, 0.0f);
    out[(size_t)i * ND + j] = acc;
}

__global__ void k_scatter(const float* __restrict__ t, const int* __restrict__ src,
                          const int* __restrict__ dst, float* __restrict__ agg) {
    int e = blockIdx.x;
    int j = threadIdx.x;   // 128 threads
    int s = src[e], d = dst[e];
    atomicAdd(&agg[(size_t)d * 128 + j], t[(size_t)s * 128 + j]);
}

__global__ void k_gcn_out(const float* __restrict__ agg, const float* __restrict__ inn,
                          const float* __restrict__ b, float* __restrict__ out, int do_relu) {
    int idx = blockIdx.x * 256 + threadIdx.x;
    int i = idx >> 7, j = idx & 127;
    float v = agg[idx] * inn[i] + b[j];
    if (do_relu) v = fmaxf(v, 0.0f);
    out[idx] = v;
}

// ---- S = h h^T 64x64 tile; MODE 0: max-only; MODE 1: recompute + bit-emit ----
template<int MODE>
__global__ __launch_bounds__(256, 4) void k_stile(const float* __restrict__ h,
                                                  const float* __restrict__ u,
                                                  unsigned* __restrict__ smax_key,
                                                  unsigned* __restrict__ mb) {
    int ti = blockIdx.y, tj = blockIdx.x;
    if (tj < ti) return;
    __shared__ float Ah[TS][68];
    __shared__ float Bh[TS][68];
    int tid = threadIdx.x;
    int tx = tid & 15, ty = tid >> 4;
    const float* ha = h + (size_t)ti * TS * 128;
    const float* hb = h + (size_t)tj * TS * 128;

    float acc[4][4];
    #pragma unroll
    for (int r = 0; r < 4; ++r)
        #pragma unroll
        for (int c = 0; c < 4; ++c) acc[r][c] = 0.0f;

    for (int half = 0; half < 2; ++half) {
        __syncthreads();
        #pragma unroll
        for (int t = 0; t < 4; ++t) {
            int f = tid + t * 256;
            int row = f >> 4, kk = f & 15;
            *(float4*)&Ah[row][kk * 4] = *(const float4*)(ha + (size_t)row * 128 + half * 64 + kk * 4);
            *(float4*)&Bh[row][kk * 4] = *(const float4*)(hb + (size_t)row * 128 + half * 64 + kk * 4);
        }
        __syncthreads();
        #pragma unroll 2
        for (int k4 = 0; k4 < 16; ++k4) {
            float4 a[4], b[4];
            #pragma unroll
            for (int r = 0; r < 4; ++r) a[r] = *(const float4*)&Ah[ty + 16 * r][k4 * 4];
            #pragma unroll
            for (int c = 0; c < 4; ++c) b[c] = *(const float4*)&Bh[tx + 16 * c][k4 * 4];
            #pragma unroll
            for (int r = 0; r < 4; ++r)
                #pragma unroll
                for (int c = 0; c < 4; ++c) {
                    acc[r][c] = fmaf(a[r].x, b[c].x, acc[r][c]);
                    acc[r][c] = fmaf(a[r].y, b[c].y, acc[r][c]);
                    acc[r][c] = fmaf(a[r].z, b[c].z, acc[r][c]);
                    acc[r][c] = fmaf(a[r].w, b[c].w, acc[r][c]);
                }
        }
    }

    if constexpr (MODE == 0) {
        float m = -3.4e38f;
        #pragma unroll
        for (int r = 0; r < 4; ++r)
            #pragma unroll
            for (int c = 0; c < 4; ++c) m = fmaxf(m, acc[r][c]);
        #pragma unroll
        for (int o = 1; o < 64; o <<= 1) m = fmaxf(m, __shfl_xor(m, o, 64));
        __shared__ float wm[4];
        if ((tid & 63) == 0) wm[tid >> 6] = m;
        __syncthreads();
        if (tid == 0) {
            float mm = fmaxf(fmaxf(wm[0], wm[1]), fmaxf(wm[2], wm[3]));
            atomicMax(smax_key, fkey(mm));
        }
    } else {
        float smax = funkey(*smax_key);
        float epmax = 1.0f / (1.0f + expf(-smax));
        __shared__ unsigned lm[TS][2];
        __shared__ unsigned lmT[TS][2];
        if (tid < 128) { lm[tid >> 1][tid & 1] = 0u; lmT[tid >> 1][tid & 1] = 0u; }
        __syncthreads();
        #pragma unroll
        for (int r = 0; r < 4; ++r) {
            #pragma unroll
            for (int c = 0; c < 4; ++c) {
                int li = ty + 16 * r, lj = tx + 16 * c;
                int gi = ti * TS + li, gj = tj * TS + lj;
                bool bit = false;
                if (gi < gj) {
                    float ep = 1.0f / (1.0f + expf(-acc[r][c]));
                    float P = ep / epmax;
                    float Pc = fminf(fmaxf(P, 1e-6f), 1.0f - 1e-6f);
                    float uu = u[(size_t)gi * NN + gj];
                    float ucv = fminf(fmaxf(uu, 1e-6f), 1.0f - 1e-6f);
                    bit = Pc > (1.0f - ucv);
                } else if (gi == gj) {
                    bit = true;
                }
                if (bit) {
                    atomicOr(&lm[li][lj >> 5], 1u << (lj & 31));
                    atomicOr(&lmT[lj][li >> 5], 1u << (li & 31));
                }
            }
        }
        __syncthreads();
        if (tid < 128) {
            int r = tid >> 1, wq = tid & 1;
            unsigned word = lm[r][wq];
            if (ti == tj) word |= lmT[r][wq];
            mb[(size_t)(ti * TS + r) * 128 + tj * 2 + wq] = word;
        } else if (ti != tj) {
            int r = (tid - 128) >> 1, wq = tid & 1;
            mb[(size_t)(tj * TS + r) * 128 + ti * 2 + wq] = lmT[r][wq];
        }
    }
}

// Pass 1 (S-store path): compute tile, store S to ws, fold into global max.
__global__ __launch_bounds__(256, 4) void k_stile_store(const float* __restrict__ h,
                                                        float* __restrict__ S,
                                                        unsigned* __restrict__ smax_key) {
    int ti = blockIdx.y, tj = blockIdx.x;
    if (tj < ti) return;
    __shared__ float Ah[TS][68];
    __shared__ float Bh[TS][68];
    int tid = threadIdx.x;
    int tx = tid & 15, ty = tid >> 4;
    const float* ha = h + (size_t)ti * TS * 128;
    const float* hb = h + (size_t)tj * TS * 128;

    float acc[4][4];
    #pragma unroll
    for (int r = 0; r < 4; ++r)
        #pragma unroll
        for (int c = 0; c < 4; ++c) acc[r][c] = 0.0f;

    for (int half = 0; half < 2; ++half) {
        __syncthreads();
        #pragma unroll
        for (int t = 0; t < 4; ++t) {
            int f = tid + t * 256;
            int row = f >> 4, kk = f & 15;
            *(float4*)&Ah[row][kk * 4] = *(const float4*)(ha + (size_t)row * 128 + half * 64 + kk * 4);
            *(float4*)&Bh[row][kk * 4] = *(const float4*)(hb + (size_t)row * 128 + half * 64 + kk * 4);
        }
        __syncthreads();
        #pragma unroll 2
        for (int k4 = 0; k4 < 16; ++k4) {
            float4 a[4], b[4];
            #pragma unroll
            for (int r = 0; r < 4; ++r) a[r] = *(const float4*)&Ah[ty + 16 * r][k4 * 4];
            #pragma unroll
            for (int c = 0; c < 4; ++c) b[c] = *(const float4*)&Bh[tx + 16 * c][k4 * 4];
            #pragma unroll
            for (int r = 0; r < 4; ++r)
                #pragma unroll
                for (int c = 0; c < 4; ++c) {
                    acc[r][c] = fmaf(a[r].x, b[c].x, acc[r][c]);
                    acc[r][c] = fmaf(a[r].y, b[c].y, acc[r][c]);
                    acc[r][c] = fmaf(a[r].z, b[c].z, acc[r][c]);
                    acc[r][c] = fmaf(a[r].w, b[c].w, acc[r][c]);
                }
        }
    }

    float* sp = S + (size_t)(ti * 64 + tj) * 4096;
    #pragma unroll
    for (int r = 0; r < 4; ++r)
        #pragma unroll
        for (int c = 0; c < 4; ++c)
            sp[(ty + 16 * r) * 64 + tx + 16 * c] = acc[r][c];

    float m = -3.4e38f;
    #pragma unroll
    for (int r = 0; r < 4; ++r)
        #pragma unroll
        for (int c = 0; c < 4; ++c) m = fmaxf(m, acc[r][c]);
    #pragma unroll
    for (int o = 1; o < 64; o <<= 1) m = fmaxf(m, __shfl_xor(m, o, 64));
    __shared__ float wm[4];
    if ((tid & 63) == 0) wm[tid >> 6] = m;
    __syncthreads();
    if (tid == 0)
        atomicMax(smax_key, fkey(fmaxf(fmaxf(wm[0], wm[1]), fmaxf(wm[2], wm[3]))));
}

// Pass 2 (S-store path): read stored S, emit mask bits.
__global__ __launch_bounds__(256, 4) void k_bitemit(const float* __restrict__ S,
                                                    const float* __restrict__ u,
                                                    const unsigned* __restrict__ smax_key,
                                                    unsigned* __restrict__ mb) {
    int ti = blockIdx.y, tj = blockIdx.x;
    if (tj < ti) return;
    int tid = threadIdx.x;
    int tx = tid & 15, ty = tid >> 4;
    float smax = funkey(*smax_key);
    float epmax = 1.0f / (1.0f + expf(-smax));
    __shared__ unsigned lm[TS][2];
    __shared__ unsigned lmT[TS][2];
    if (tid < 128) { lm[tid >> 1][tid & 1] = 0u; lmT[tid >> 1][tid & 1] = 0u; }
    __syncthreads();
    const float* sp = S + (size_t)(ti * 64 + tj) * 4096;
    #pragma unroll
    for (int r = 0; r < 4; ++r) {
        #pragma unroll
        for (int c = 0; c < 4; ++c) {
            int li = ty + 16 * r, lj = tx + 16 * c;
            int gi = ti * TS + li, gj = tj * TS + lj;
            bool bit = false;
            if (gi < gj) {
                float ep = 1.0f / (1.0f + expf(-sp[li * 64 + lj]));
                float P = ep / epmax;
                float Pc = fminf(fmaxf(P, 1e-6f), 1.0f - 1e-6f);
                float uu = u[(size_t)gi * NN + gj];
                float ucv = fminf(fmaxf(uu, 1e-6f), 1.0f - 1e-6f);
                bit = Pc > (1.0f - ucv);
            } else if (gi == gj) {
                bit = true;
            }
            if (bit) {
                atomicOr(&lm[li][lj >> 5], 1u << (lj & 31));
                atomicOr(&lmT[lj][li >> 5], 1u << (li & 31));
            }
        }
    }
    __syncthreads();
    if (tid < 128) {
        int r = tid >> 1, wq = tid & 1;
        unsigned word = lm[r][wq];
        if (ti == tj) word |= lmT[r][wq];
        mb[(size_t)(ti * TS + r) * 128 + tj * 2 + wq] = word;
    } else if (ti != tj) {
        int r = (tid - 128) >> 1, wq = tid & 1;
        mb[(size_t)(tj * TS + r) * 128 + ti * 2 + wq] = lmT[r][wq];
    }
}

// Masked max, D=256. Mask word is wave-uniform -> SGPR (readfirstlane); bit
// expands via SCALAR shift-sext (s_bfe/s_lshl+s_ashr, scalar pipe), applied
// with v_and(sgpr,v) + v_max3 pairing: 6 VALU per (row,j), 0 VALU mask cost.
// RPG=16 rows/thread amortize each z load 16x (1.05 GB total L2 traffic).
template<int RT, int JS>
__global__ __launch_bounds__(256, 4) void k_mmax256(const unsigned* __restrict__ mb,
                                                    const float* __restrict__ z,
                                                    float* __restrict__ part) {
    constexpr int JPS = NN / JS;   // 512
    constexpr int WPS = JPS / 32;  // 16
    constexpr int RPG = RT / 4;    // 16 rows per thread (4 waves/block)
    constexpr int NRB = NN / RT;   // 64
    int rowblk = blockIdx.x % NRB, js = blockIdx.x / NRB;
    int i0 = rowblk * RT;

    __shared__ unsigned msk[RT][WPS + 1];
    for (int t = threadIdx.x; t < RT * WPS; t += 256)
        msk[t / WPS][t % WPS] = mb[(size_t)(i0 + t / WPS) * 128 + js * WPS + t % WPS];
    __syncthreads();

    int d4 = threadIdx.x & 63;
    int g = threadIdx.x >> 6;
    const float4* zbase = (const float4*)z + (size_t)js * JPS * 64 + d4;

    float4 acc[RPG];
    #pragma unroll
    for (int r = 0; r < RPG; ++r) acc[r] = make_float4(0.f, 0.f, 0.f, 0.f);

    for (int wq = 0; wq < WPS; ++wq) {
        unsigned m[RPG];
        #pragma unroll
        for (int r = 0; r < RPG; ++r)
            m[r] = (unsigned)__builtin_amdgcn_readfirstlane((int)msk[g * RPG + r][wq]);
        const float4* zp = zbase + (size_t)(wq * 32) * 64;
        for (int j4 = 0; j4 < 32; j4 += 4) {    // not unrolled: keep body in I-cache
            float4 z0 = zp[0 * 64];
            float4 z1 = zp[1 * 64];
            float4 z2 = zp[2 * 64];
            float4 z3 = zp[3 * 64];
            #pragma unroll
            for (int r = 0; r < RPG; ++r) {
                unsigned s0 = bit_sext_s(m[r], j4 + 0);
                unsigned s1 = bit_sext_s(m[r], j4 + 1);
                unsigned s2 = bit_sext_s(m[r], j4 + 2);
                unsigned s3 = bit_sext_s(m[r], j4 + 3);
                acc[r] = max3_4(acc[r], and4(s0, z0), and4(s1, z1));
                acc[r] = max3_4(acc[r], and4(s2, z2), and4(s3, z3));
            }
            zp += 4 * 64;
        }
    }

    float4* po = (float4*)(part + (size_t)js * NN * 256);
    #pragma unroll
    for (int r = 0; r < RPG; ++r)
        po[(size_t)(i0 + g * RPG + r) * 64 + d4] = acc[r];
}

// Masked max, D=128. Wave covers 2 j's (jpar = lane>>5); per-lane v_bfe mask +
// and4 + max3 pairing across j-steps: 3.5 VALU per (row,j). RPG=16 row-reuse.
template<int RT, int JS>
__global__ __launch_bounds__(256, 4) void k_mmax128(const unsigned* __restrict__ mb,
                                                    const float* __restrict__ z,
                                                    float* __restrict__ part) {
    constexpr int JPS = NN / JS;   // 512
    constexpr int WPS = JPS / 32;  // 16
    constexpr int RPG = RT / 4;    // 16
    constexpr int NRB = NN / RT;   // 64
    int rowblk = blockIdx.x % NRB, js = blockIdx.x / NRB;
    int i0 = rowblk * RT;

    __shared__ unsigned msk[RT][WPS + 1];
    for (int t = threadIdx.x; t < RT * WPS; t += 256)
        msk[t / WPS][t % WPS] = mb[(size_t)(i0 + t / WPS) * 128 + js * WPS + t % WPS];
    __syncthreads();

    int lane = threadIdx.x & 63;
    int g = threadIdx.x >> 6;
    unsigned jpar = lane >> 5;
    int d4 = lane & 31;
    const float4* zbase = (const float4*)z + (size_t)js * JPS * 32 + d4;

    float4 acc[RPG];
    #pragma unroll
    for (int r = 0; r < RPG; ++r) acc[r] = make_float4(0.f, 0.f, 0.f, 0.f);

    for (int wq = 0; wq < WPS; ++wq) {
        unsigned m[RPG];
        #pragma unroll
        for (int r = 0; r < RPG; ++r) m[r] = msk[g * RPG + r][wq];
        const float4* zp = zbase + (size_t)(wq * 32) * 32;
        for (int j4 = 0; j4 < 32; j4 += 4) {
            float4 za = zp[(size_t)jpar * 32];
            float4 zb = zp[(size_t)(2 + jpar) * 32];
            unsigned oa = j4 + jpar, ob = j4 + 2 + jpar;
            #pragma unroll
            for (int r = 0; r < RPG; ++r) {
                unsigned sa = bit_sext(m[r], oa);
                unsigned sb = bit_sext(m[r], ob);
                acc[r] = max3_4(acc[r], and4(sa, za), and4(sb, zb));
            }
            zp += 4 * 32;
        }
    }

    // merge the two j-halves of the wave
    #pragma unroll
    for (int r = 0; r < RPG; ++r) {
        acc[r].x = fmaxf(acc[r].x, __shfl_xor(acc[r].x, 32, 64));
        acc[r].y = fmaxf(acc[r].y, __shfl_xor(acc[r].y, 32, 64));
        acc[r].z = fmaxf(acc[r].z, __shfl_xor(acc[r].z, 32, 64));
        acc[r].w = fmaxf(acc[r].w, __shfl_xor(acc[r].w, 32, 64));
    }
    if (!jpar) {
        float4* po = (float4*)(part + (size_t)js * NN * 128);
        #pragma unroll
        for (int r = 0; r < RPG; ++r)
            po[(size_t)(i0 + g * RPG + r) * 32 + d4] = acc[r];
    }
}

__global__ void k_relu_l2norm(float* __restrict__ h) {
    int i = blockIdx.x, d = threadIdx.x;
    float v = fmaxf(h[(size_t)i * 128 + d], 0.0f);
    float ss = v * v;
    #pragma unroll
    for (int o = 1; o < 64; o <<= 1) ss += __shfl_xor(ss, o, 64);
    __shared__ float w2[2];
    if ((d & 63) == 0) w2[d >> 6] = ss;
    __syncthreads();
    float tot = w2[0] + w2[1];
    float denom = fmaxf(sqrtf(tot), 1e-12f);
    h[(size_t)i * 128 + d] = v / denom;
}

// Final 128->32 GEMM with NS-way partial merge, LDS-staged. 4 rows per block.
template<int NS>
__global__ void k_gemm_final(const float* __restrict__ X, size_t xstride,
                             const float* __restrict__ W,
                             const float* __restrict__ b1, const float* __restrict__ b2,
                             float* __restrict__ out) {
    __shared__ float xr[4][128];
    int i0 = blockIdx.x * 4;
    for (int t = threadIdx.x; t < 512; t += 128) {
        int r = t >> 7, k = t & 127;
        float v = X[(size_t)(i0 + r) * 128 + k];
        #pragma unroll
        for (int s = 1; s < NS; ++s)
            v = fmaxf(v, X[(size_t)s * xstride + (size_t)(i0 + r) * 128 + k]);
        xr[r][k] = v;
    }
    __syncthreads();
    int il = threadIdx.x >> 5, j = threadIdx.x & 31;
    float acc = 0.0f;
    #pragma unroll 8
    for (int k = 0; k < 128; ++k) acc = fmaf(xr[il][k], W[k * 32 + j], acc);
    out[(size_t)(i0 + il) * 32 + j] = acc + b1[j] + b2[j];
}

extern "C" void kernel_launch(void* const* d_in, const int* in_sizes, int n_in,
                              void* d_out, int out_size, void* d_ws, size_t ws_size,
                              hipStream_t stream) {
    const float* inputs = (const float*)d_in[1];
    const float* feat   = (const float*)d_in[2];
    const float* u      = (const float*)d_in[3];
    const int*   src    = (const int*)d_in[4];
    const int*   dst    = (const int*)d_in[5];
    const float* gc0W = (const float*)d_in[6],  *gc0b = (const float*)d_in[7];
    const float* gc1W = (const float*)d_in[8],  *gc1b = (const float*)d_in[9];
    const float* p0W  = (const float*)d_in[10], *p0b  = (const float*)d_in[11];
    const float* l0W  = (const float*)d_in[12], *l0b  = (const float*)d_in[13];
    const float* b0   = (const float*)d_in[14];
    const float* p1W  = (const float*)d_in[15], *p1b  = (const float*)d_in[16];
    const float* l1W  = (const float*)d_in[17], *l1b  = (const float*)d_in[18];
    const float* b1   = (const float*)d_in[19];
    const float* p2W  = (const float*)d_in[20], *p2b  = (const float*)d_in[21];
    const float* l2W  = (const float*)d_in[22], *l2b  = (const float*)d_in[23];
    const float* b2   = (const float*)d_in[24];
    float* out = (float*)d_out;

    const size_t MB = 1048576;
    char* w = (char*)d_ws;
    int*      cnt_src  = (int*)(w + 0);            // 16 KB
    int*      cnt_dst  = (int*)(w + 16384);        // 16 KB
    float*    on       = (float*)(w + 32768);      // 16 KB
    float*    inn      = (float*)(w + 49152);      // 16 KB
    unsigned* smax_key = (unsigned*)(w + 65536);   // pad to 128 KB
    char*     big      = w + 131072;
    float*    tmp      = (float*)(big);            // 2 MB
    float*    agg      = (float*)(big + 2 * MB);   // 2 MB
    float*    hbuf     = (float*)(big + 4 * MB);   // 2 MB
    unsigned* mb       = (unsigned*)(big + 6 * MB);// 2 MB
    float*    z        = (float*)(big + 8 * MB);   // 4 MB
    float*    pm       = (float*)(big + 12 * MB);  // 32 MB (8 split partials)
    float*    hs       = (float*)(big + 44 * MB);  // 2 MB
    float*    Sbuf     = (float*)(big + 46 * MB);  // 64 MB
    bool use_sstore = ws_size >= 131072 + 110 * MB;

    hipMemsetAsync(w, 0, 131072, stream);
    k_count<<<EE / 256, 256, 0, stream>>>(src, dst, cnt_src, cnt_dst);
    k_norm<<<NN / 256, 256, 0, stream>>>(cnt_src, cnt_dst, on, inn);

    // --- GCN layer 0 ---
    k_gemm_scale<256, 128><<<NN, 128, 0, stream>>>(inputs, gc0W, on, tmp);
    hipMemsetAsync(agg, 0, (size_t)NN * 128 * 4, stream);
    k_scatter<<<EE, 128, 0, stream>>>(tmp, src, dst, agg);
    k_gcn_out<<<NN * 128 / 256, 256, 0, stream>>>(agg, inn, gc0b, hbuf, 1);

    // --- GCN layer 1 ---
    k_gemm_scale<128, 128><<<NN, 128, 0, stream>>>(hbuf, gc1W, on, tmp);
    hipMemsetAsync(agg, 0, (size_t)NN * 128 * 4, stream);
    k_scatter<<<EE, 128, 0, stream>>>(tmp, src, dst, agg);
    k_gcn_out<<<NN * 128 / 256, 256, 0, stream>>>(agg, inn, gc1b, hbuf, 0);

    // --- decode: S max + mask bits ---
    dim3 tg(64, 64);
    if (use_sstore) {
        k_stile_store<<<tg, 256, 0, stream>>>(hbuf, Sbuf, smax_key);
        k_bitemit<<<tg, 256, 0, stream>>>(Sbuf, u, smax_key, mb);
    } else {
        k_stile<0><<<tg, 256, 0, stream>>>(hbuf, nullptr, smax_key, nullptr);
        k_stile<1><<<tg, 256, 0, stream>>>(hbuf, u, smax_key, mb);
    }

    // --- GraphSAGE layer 0 (256 -> 128) ---
    k_gemm_mrg<256, 256, 1><<<NN, 256, 0, stream>>>(feat, 0, p0W, p0b, nullptr, z, 1);
    k_mmax256<64, 8><<<(NN / 64) * 8, 256, 0, stream>>>(mb, z, pm);
    k_gemm_mrg<256, 128, 8><<<NN, 128, 0, stream>>>(pm, (size_t)NN * 256, l0W, l0b, b0, hs, 0);
    k_relu_l2norm<<<NN, 128, 0, stream>>>(hs);

    // --- GraphSAGE layer 1 (128 -> 128) ---
    k_gemm_mrg<128, 128, 1><<<NN, 128, 0, stream>>>(hs, 0, p1W, p1b, nullptr, z, 1);
    k_mmax128<64, 8><<<(NN / 64) * 8, 256, 0, stream>>>(mb, z, pm);
    k_gemm_mrg<128, 128, 8><<<NN, 128, 0, stream>>>(pm, (size_t)NN * 128, l1W, l1b, b1, tmp, 0);
    k_relu_l2norm<<<NN, 128, 0, stream>>>(tmp);

    // --- GraphSAGE layer 2 (128 -> 32) ---
    k_gemm_mrg<128, 128, 1><<<NN, 128, 0, stream>>>(tmp, 0, p2W, p2b, nullptr, z, 1);
    k_mmax128<64, 8><<<(NN / 64) * 8, 256, 0, stream>>>(mb, z, pm);
    k_gemm_final<8><<<NN / 4, 128, 0, stream>>>(pm, (size_t)NN * 128, l2W, l2b, b2, out);
}